// Round 1
// baseline (423.977 us; speedup 1.0000x reference)
//
#include <hip/hip_runtime.h>
#include <hip/hip_bf16.h>
#include <math.h>

// Problem constants
#define NTOK 2048
#define CDIM 1024
#define NHEAD 16
#define HDIM 64
// frame id = token >> 8 (8 frames of 256 tokens)

// ---------------------------------------------------------------------------
// GEMM: C[M x N] = A[M x K] @ B[N x K]^T + bias[N]   (f32, vector ALU)
// BM=BN=128, BK=16, 256 threads, 8x8 micro-tile per thread (split 4+4)
// ---------------------------------------------------------------------------
template <int M, int N, int K>
__global__ __launch_bounds__(256) void gemm_nt_bias(const float* __restrict__ A,
                                                    const float* __restrict__ B,
                                                    const float* __restrict__ bias,
                                                    float* __restrict__ C) {
    __shared__ float As[16][132];  // [k][m], pad 132 (16B-aligned rows, bank-spread)
    __shared__ float Bs[16][132];  // [k][n]
    const int tid = threadIdx.x;
    const int tx = tid & 15;
    const int ty = tid >> 4;
    const int m0 = blockIdx.y * 128;
    const int n0 = blockIdx.x * 128;
    const int lr = tid >> 2;          // 0..63
    const int lc = (tid & 3) << 2;    // 0,4,8,12

    float acc[8][8];
#pragma unroll
    for (int i = 0; i < 8; ++i)
#pragma unroll
        for (int j = 0; j < 8; ++j) acc[i][j] = 0.f;

    for (int k0 = 0; k0 < K; k0 += 16) {
        float4 a0 = *(const float4*)&A[(size_t)(m0 + lr) * K + k0 + lc];
        float4 a1 = *(const float4*)&A[(size_t)(m0 + 64 + lr) * K + k0 + lc];
        float4 b0 = *(const float4*)&B[(size_t)(n0 + lr) * K + k0 + lc];
        float4 b1 = *(const float4*)&B[(size_t)(n0 + 64 + lr) * K + k0 + lc];
        __syncthreads();  // previous iteration's compute done before overwrite
        As[lc + 0][lr] = a0.x; As[lc + 1][lr] = a0.y; As[lc + 2][lr] = a0.z; As[lc + 3][lr] = a0.w;
        As[lc + 0][64 + lr] = a1.x; As[lc + 1][64 + lr] = a1.y; As[lc + 2][64 + lr] = a1.z; As[lc + 3][64 + lr] = a1.w;
        Bs[lc + 0][lr] = b0.x; Bs[lc + 1][lr] = b0.y; Bs[lc + 2][lr] = b0.z; Bs[lc + 3][lr] = b0.w;
        Bs[lc + 0][64 + lr] = b1.x; Bs[lc + 1][64 + lr] = b1.y; Bs[lc + 2][64 + lr] = b1.z; Bs[lc + 3][64 + lr] = b1.w;
        __syncthreads();
#pragma unroll
        for (int k = 0; k < 16; ++k) {
            float4 av0 = *(const float4*)&As[k][ty * 4];
            float4 av1 = *(const float4*)&As[k][64 + ty * 4];
            float4 bv0 = *(const float4*)&Bs[k][tx * 4];
            float4 bv1 = *(const float4*)&Bs[k][64 + tx * 4];
            float a[8] = {av0.x, av0.y, av0.z, av0.w, av1.x, av1.y, av1.z, av1.w};
            float b[8] = {bv0.x, bv0.y, bv0.z, bv0.w, bv1.x, bv1.y, bv1.z, bv1.w};
#pragma unroll
            for (int i = 0; i < 8; ++i)
#pragma unroll
                for (int j = 0; j < 8; ++j) acc[i][j] = fmaf(a[i], b[j], acc[i][j]);
        }
    }

    float4 bia0 = *(const float4*)&bias[n0 + tx * 4];
    float4 bia1 = *(const float4*)&bias[n0 + 64 + tx * 4];
    float bb[8] = {bia0.x, bia0.y, bia0.z, bia0.w, bia1.x, bia1.y, bia1.z, bia1.w};
#pragma unroll
    for (int i = 0; i < 8; ++i) {
        int r = m0 + ((i < 4) ? (ty * 4 + i) : (64 + ty * 4 + i - 4));
        float4 s0 = make_float4(acc[i][0] + bb[0], acc[i][1] + bb[1], acc[i][2] + bb[2], acc[i][3] + bb[3]);
        float4 s1 = make_float4(acc[i][4] + bb[4], acc[i][5] + bb[5], acc[i][6] + bb[6], acc[i][7] + bb[7]);
        *(float4*)&C[(size_t)r * N + n0 + tx * 4] = s0;
        *(float4*)&C[(size_t)r * N + n0 + 64 + tx * 4] = s1;
    }
}

// ---------------------------------------------------------------------------
// Sparse flash attention (f32).
// grid = (NHEAD, NTOK/64). Block 256 threads, 64 queries/block.
// Tile-level skip: a 64x64 (q,k) tile has uniform frame pair; skip if !adj.
// ---------------------------------------------------------------------------
__global__ __launch_bounds__(256) void attn_kernel(const float* __restrict__ qkv,
                                                   const float* __restrict__ frame_bias,
                                                   const int* __restrict__ adj,
                                                   const int* __restrict__ is_hub,
                                                   float* __restrict__ att) {
    __shared__ float Qs[64][68];  // [d][m], pre-scaled by 1/8
    __shared__ float Ks[64][68];  // [d][n]
    __shared__ float Vs[64][68];  // [n][d]
    __shared__ float Ps[64][68];  // [n][m]

    const int h = blockIdx.x;
    const int q0 = blockIdx.y * 64;
    const int tid = threadIdx.x;
    const int tx = tid & 15;
    const int ty = tid >> 4;
    const int fi = q0 >> 8;
    const float scale = 0.125f;  // D^-0.5, D=64

    // Stage Q (scaled), transposed [d][m]
    {
        const int d = (tid & 15) * 4;
        const int mb = tid >> 4;
#pragma unroll
        for (int i = 0; i < 4; ++i) {
            const int m = mb + i * 16;
            float4 qv = *(const float4*)&qkv[(size_t)(q0 + m) * 3072 + h * 64 + d];
            Qs[d + 0][m] = qv.x * scale;
            Qs[d + 1][m] = qv.y * scale;
            Qs[d + 2][m] = qv.z * scale;
            Qs[d + 3][m] = qv.w * scale;
        }
    }

    int hq[4];
#pragma unroll
    for (int i = 0; i < 4; ++i) hq[i] = is_hub[q0 + ty * 4 + i];

    float m_i[4], l_i[4], o[4][4];
#pragma unroll
    for (int i = 0; i < 4; ++i) {
        m_i[i] = -INFINITY;
        l_i[i] = 0.f;
#pragma unroll
        for (int j = 0; j < 4; ++j) o[i][j] = 0.f;
    }

    for (int n0 = 0; n0 < NTOK; n0 += 64) {
        const int fj = n0 >> 8;
        if (!adj[fi * 8 + fj]) continue;  // uniform across block
        const bool same = (fi == fj);
        const float biasv = frame_bias[fi * 8 + fj];

        __syncthreads();  // previous tile's PV reads done before restaging
        {
            const int d = (tid & 15) * 4;
            const int nb = tid >> 4;
#pragma unroll
            for (int i = 0; i < 4; ++i) {
                const int n = nb + i * 16;
                float4 kv = *(const float4*)&qkv[(size_t)(n0 + n) * 3072 + 1024 + h * 64 + d];
                Ks[d + 0][n] = kv.x; Ks[d + 1][n] = kv.y; Ks[d + 2][n] = kv.z; Ks[d + 3][n] = kv.w;
                float4 vv = *(const float4*)&qkv[(size_t)(n0 + n) * 3072 + 2048 + h * 64 + d];
                *(float4*)&Vs[n][d] = vv;
            }
        }
        __syncthreads();

        // S = (Q*scale) . K^T
        float s[4][4];
#pragma unroll
        for (int i = 0; i < 4; ++i)
#pragma unroll
            for (int j = 0; j < 4; ++j) s[i][j] = 0.f;
        for (int d = 0; d < 64; ++d) {
            float4 qv = *(const float4*)&Qs[d][ty * 4];
            float4 kv = *(const float4*)&Ks[d][tx * 4];
            float qa[4] = {qv.x, qv.y, qv.z, qv.w};
            float ka[4] = {kv.x, kv.y, kv.z, kv.w};
#pragma unroll
            for (int i = 0; i < 4; ++i)
#pragma unroll
                for (int j = 0; j < 4; ++j) s[i][j] = fmaf(qa[i], ka[j], s[i][j]);
        }

        // mask + bias
        int hk[4];
#pragma unroll
        for (int j = 0; j < 4; ++j) hk[j] = is_hub[n0 + tx * 4 + j];
        float rmax[4];
#pragma unroll
        for (int i = 0; i < 4; ++i) rmax[i] = -INFINITY;
#pragma unroll
        for (int i = 0; i < 4; ++i)
#pragma unroll
            for (int j = 0; j < 4; ++j) {
                const bool allowed = same || ((hq[i] == 0) && (hk[j] == 0));
                const float se = allowed ? (s[i][j] + biasv) : -INFINITY;
                s[i][j] = se;
                rmax[i] = fmaxf(rmax[i], se);
            }
        // row reduce across the 16 lanes sharing ty
#pragma unroll
        for (int off = 1; off < 16; off <<= 1)
#pragma unroll
            for (int i = 0; i < 4; ++i) rmax[i] = fmaxf(rmax[i], __shfl_xor(rmax[i], off));

        float alpha[4];
#pragma unroll
        for (int i = 0; i < 4; ++i) {
            const float mn = fmaxf(m_i[i], rmax[i]);
            alpha[i] = (mn == -INFINITY) ? 1.f : __expf(m_i[i] - mn);
            m_i[i] = mn;
        }
        float p[4][4], rsum[4];
#pragma unroll
        for (int i = 0; i < 4; ++i) rsum[i] = 0.f;
#pragma unroll
        for (int i = 0; i < 4; ++i)
#pragma unroll
            for (int j = 0; j < 4; ++j) {
                const float pv = (s[i][j] == -INFINITY) ? 0.f : __expf(s[i][j] - m_i[i]);
                p[i][j] = pv;
                rsum[i] += pv;
            }
#pragma unroll
        for (int off = 1; off < 16; off <<= 1)
#pragma unroll
            for (int i = 0; i < 4; ++i) rsum[i] += __shfl_xor(rsum[i], off);
#pragma unroll
        for (int i = 0; i < 4; ++i) {
            l_i[i] = l_i[i] * alpha[i] + rsum[i];
#pragma unroll
            for (int j = 0; j < 4; ++j) o[i][j] *= alpha[i];
        }

        // P -> LDS (transposed [n][m]), then O += P @ V
#pragma unroll
        for (int i = 0; i < 4; ++i)
#pragma unroll
            for (int j = 0; j < 4; ++j) Ps[tx * 4 + j][ty * 4 + i] = p[i][j];
        __syncthreads();
        for (int n = 0; n < 64; ++n) {
            float4 pv = *(const float4*)&Ps[n][ty * 4];
            float4 vv = *(const float4*)&Vs[n][tx * 4];
            float pa[4] = {pv.x, pv.y, pv.z, pv.w};
            float va[4] = {vv.x, vv.y, vv.z, vv.w};
#pragma unroll
            for (int i = 0; i < 4; ++i)
#pragma unroll
                for (int j = 0; j < 4; ++j) o[i][j] = fmaf(pa[i], va[j], o[i][j]);
        }
    }

    // epilogue: normalize and write att[(token), h*64+d]
#pragma unroll
    for (int i = 0; i < 4; ++i) {
        const float inv = 1.f / l_i[i];
        float4 st = make_float4(o[i][0] * inv, o[i][1] * inv, o[i][2] * inv, o[i][3] * inv);
        *(float4*)&att[(size_t)(q0 + ty * 4 + i) * CDIM + h * 64 + tx * 4] = st;
    }
}

// ---------------------------------------------------------------------------
extern "C" void kernel_launch(void* const* d_in, const int* in_sizes, int n_in,
                              void* d_out, int out_size, void* d_ws, size_t ws_size,
                              hipStream_t stream) {
    const float* x          = (const float*)d_in[0];
    const float* Wqkv       = (const float*)d_in[1];
    const float* bqkv       = (const float*)d_in[2];
    const float* Wproj      = (const float*)d_in[3];
    const float* bproj      = (const float*)d_in[4];
    const float* frame_bias = (const float*)d_in[5];
    const int*   adj        = (const int*)d_in[6];
    // d_in[7] = frame_ids (unused: fi = token >> 8 by construction)
    const int*   is_hub     = (const int*)d_in[8];
    float* out = (float*)d_out;

    float* qkv = (float*)d_ws;                       // 2048*3072 f32 = 25.2 MB
    float* att = qkv + (size_t)NTOK * 3 * CDIM;      // 2048*1024 f32 = 8.4 MB

    // 1) QKV projection
    gemm_nt_bias<NTOK, 3 * CDIM, CDIM>
        <<<dim3((3 * CDIM) / 128, NTOK / 128), 256, 0, stream>>>(x, Wqkv, bqkv, qkv);
    // 2) sparse attention
    attn_kernel<<<dim3(NHEAD, NTOK / 64), 256, 0, stream>>>(qkv, frame_bias, adj, is_hub, att);
    // 3) output projection
    gemm_nt_bias<NTOK, CDIM, CDIM>
        <<<dim3(CDIM / 128, NTOK / 128), 256, 0, stream>>>(att, Wproj, bproj, out);
}

// Round 2
// 224.934 us; speedup vs baseline: 1.8849x; 1.8849x over previous
//
#include <hip/hip_runtime.h>
#include <hip/hip_bf16.h>
#include <math.h>

// Problem constants
#define NTOK 2048
#define CDIM 1024
#define NHEAD 16
#define HDIM 64
// frame id = token >> 8 (8 frames of 256 tokens)

typedef __attribute__((ext_vector_type(8))) short bf16x8;
typedef __attribute__((ext_vector_type(4))) float f32x4;
typedef unsigned short ushort_t;

// ---------------------------------------------------------------------------
// f32 -> bf16 hi/lo split (round-to-nearest-even), 4 elems/thread
// ---------------------------------------------------------------------------
__device__ inline unsigned short bf16_rn(float f) {
    unsigned int u = __float_as_uint(f);
    u += 0x7FFFu + ((u >> 16) & 1u);
    return (unsigned short)(u >> 16);
}

__global__ __launch_bounds__(256) void split_bf16(const float* __restrict__ in,
                                                  unsigned short* __restrict__ hi,
                                                  unsigned short* __restrict__ lo,
                                                  int n4) {
    int i = blockIdx.x * 256 + threadIdx.x;
    if (i >= n4) return;
    float4 v = ((const float4*)in)[i];
    float a[4] = {v.x, v.y, v.z, v.w};
    ushort4 h, l;
    unsigned short hs[4], ls[4];
#pragma unroll
    for (int j = 0; j < 4; ++j) {
        unsigned short hb = bf16_rn(a[j]);
        float hf = __uint_as_float((unsigned int)hb << 16);
        hs[j] = hb;
        ls[j] = bf16_rn(a[j] - hf);
    }
    h.x = hs[0]; h.y = hs[1]; h.z = hs[2]; h.w = hs[3];
    l.x = ls[0]; l.y = ls[1]; l.z = ls[2]; l.w = ls[3];
    ((ushort4*)hi)[i] = h;
    ((ushort4*)lo)[i] = l;
}

// ---------------------------------------------------------------------------
// MFMA GEMM with hi/lo split inputs:
// C[M x N] = (Ah+Al)[M x K] @ (Bh+Bl)[N x K]^T + bias[N]  (drop lo*lo term)
// 128x128 tile, BK=32, 4 waves (2x2 of 64x64), mfma_f32_16x16x32_bf16.
// Staging via global_load_lds (16B), linear LDS, m97 2-barrier structure.
// ---------------------------------------------------------------------------
__device__ inline void gload16(const void* g, void* l) {
    __builtin_amdgcn_global_load_lds((const __attribute__((address_space(1))) void*)g,
                                     (__attribute__((address_space(3))) void*)l,
                                     16, 0, 0);
}

template <int M, int N, int K>
__global__ __launch_bounds__(256) void gemm_mfma_split(const unsigned short* __restrict__ Ah,
                                                       const unsigned short* __restrict__ Al,
                                                       const unsigned short* __restrict__ Bh,
                                                       const unsigned short* __restrict__ Bl,
                                                       const float* __restrict__ bias,
                                                       float* __restrict__ C) {
    // 128 rows x 32 cols bf16 per array, linear (row*32 + col)
    __shared__ unsigned short sAh[128 * 32];
    __shared__ unsigned short sAl[128 * 32];
    __shared__ unsigned short sBh[128 * 32];
    __shared__ unsigned short sBl[128 * 32];

    const int tid = threadIdx.x;
    const int lane = tid & 63;
    const int w = tid >> 6;
    const int m0 = blockIdx.y * 128;
    const int n0 = blockIdx.x * 128;
    const int wave_m = (w >> 1) * 64;
    const int wave_n = (w & 1) * 64;
    const int lr = lane & 15;
    const int kg = lane >> 4;

    // staging coords: wave w stages rows [w*32, w*32+32) of each 128x32 tile
    const int srow0 = w * 32 + (lane >> 2);   // + j*16
    const int scol = (lane & 3) * 8;          // bf16 elem offset in row
    const int ldsbase = w * 1024;             // + j*512 (elements)

    f32x4 acc[4][4];
#pragma unroll
    for (int i = 0; i < 4; ++i)
#pragma unroll
        for (int j = 0; j < 4; ++j) acc[i][j] = {0.f, 0.f, 0.f, 0.f};

    for (int k0 = 0; k0 < K; k0 += 32) {
        __syncthreads();  // previous iter's frag reads complete before overwrite
#pragma unroll
        for (int j = 0; j < 2; ++j) {
            const int row = srow0 + j * 16;
            const size_t ga = (size_t)(m0 + row) * K + k0 + scol;
            const size_t gb = (size_t)(n0 + row) * K + k0 + scol;
            gload16(Ah + ga, sAh + ldsbase + j * 512);
            gload16(Al + ga, sAl + ldsbase + j * 512);
            gload16(Bh + gb, sBh + ldsbase + j * 512);
            gload16(Bl + gb, sBl + ldsbase + j * 512);
        }
        __syncthreads();  // compiler drains vmcnt(0) before barrier

        bf16x8 ah[4], al[4], bh[4], bl[4];
#pragma unroll
        for (int f = 0; f < 4; ++f) {
            const int ra = (wave_m + f * 16 + lr) * 32 + kg * 8;
            const int rb = (wave_n + f * 16 + lr) * 32 + kg * 8;
            ah[f] = *(const bf16x8*)&sAh[ra];
            al[f] = *(const bf16x8*)&sAl[ra];
            bh[f] = *(const bf16x8*)&sBh[rb];
            bl[f] = *(const bf16x8*)&sBl[rb];
        }
#pragma unroll
        for (int fm = 0; fm < 4; ++fm)
#pragma unroll
            for (int fn = 0; fn < 4; ++fn) {
                acc[fm][fn] = __builtin_amdgcn_mfma_f32_16x16x32_bf16(ah[fm], bh[fn], acc[fm][fn], 0, 0, 0);
                acc[fm][fn] = __builtin_amdgcn_mfma_f32_16x16x32_bf16(ah[fm], bl[fn], acc[fm][fn], 0, 0, 0);
                acc[fm][fn] = __builtin_amdgcn_mfma_f32_16x16x32_bf16(al[fm], bh[fn], acc[fm][fn], 0, 0, 0);
            }
    }

    // epilogue: C/D layout col=lane&15, row=(lane>>4)*4+reg  [m89-verified]
    float bv[4];
#pragma unroll
    for (int fn = 0; fn < 4; ++fn) bv[fn] = bias[n0 + wave_n + fn * 16 + lr];
#pragma unroll
    for (int fm = 0; fm < 4; ++fm) {
        const int row0 = m0 + wave_m + fm * 16 + kg * 4;
#pragma unroll
        for (int fn = 0; fn < 4; ++fn) {
            const int col = n0 + wave_n + fn * 16 + lr;
#pragma unroll
            for (int r = 0; r < 4; ++r)
                C[(size_t)(row0 + r) * N + col] = acc[fm][fn][r] + bv[fn];
        }
    }
}

// ---------------------------------------------------------------------------
// Sparse flash attention (f32) — unchanged from round 1 (passed).
// ---------------------------------------------------------------------------
__global__ __launch_bounds__(256) void attn_kernel(const float* __restrict__ qkv,
                                                   const float* __restrict__ frame_bias,
                                                   const int* __restrict__ adj,
                                                   const int* __restrict__ is_hub,
                                                   float* __restrict__ att) {
    __shared__ float Qs[64][68];  // [d][m], pre-scaled by 1/8
    __shared__ float Ks[64][68];  // [d][n]
    __shared__ float Vs[64][68];  // [n][d]
    __shared__ float Ps[64][68];  // [n][m]

    const int h = blockIdx.x;
    const int q0 = blockIdx.y * 64;
    const int tid = threadIdx.x;
    const int tx = tid & 15;
    const int ty = tid >> 4;
    const int fi = q0 >> 8;
    const float scale = 0.125f;

    {
        const int d = (tid & 15) * 4;
        const int mb = tid >> 4;
#pragma unroll
        for (int i = 0; i < 4; ++i) {
            const int m = mb + i * 16;
            float4 qv = *(const float4*)&qkv[(size_t)(q0 + m) * 3072 + h * 64 + d];
            Qs[d + 0][m] = qv.x * scale;
            Qs[d + 1][m] = qv.y * scale;
            Qs[d + 2][m] = qv.z * scale;
            Qs[d + 3][m] = qv.w * scale;
        }
    }

    int hq[4];
#pragma unroll
    for (int i = 0; i < 4; ++i) hq[i] = is_hub[q0 + ty * 4 + i];

    float m_i[4], l_i[4], o[4][4];
#pragma unroll
    for (int i = 0; i < 4; ++i) {
        m_i[i] = -INFINITY;
        l_i[i] = 0.f;
#pragma unroll
        for (int j = 0; j < 4; ++j) o[i][j] = 0.f;
    }

    for (int n0 = 0; n0 < NTOK; n0 += 64) {
        const int fj = n0 >> 8;
        if (!adj[fi * 8 + fj]) continue;
        const bool same = (fi == fj);
        const float biasv = frame_bias[fi * 8 + fj];

        __syncthreads();
        {
            const int d = (tid & 15) * 4;
            const int nb = tid >> 4;
#pragma unroll
            for (int i = 0; i < 4; ++i) {
                const int n = nb + i * 16;
                float4 kv = *(const float4*)&qkv[(size_t)(n0 + n) * 3072 + 1024 + h * 64 + d];
                Ks[d + 0][n] = kv.x; Ks[d + 1][n] = kv.y; Ks[d + 2][n] = kv.z; Ks[d + 3][n] = kv.w;
                float4 vv = *(const float4*)&qkv[(size_t)(n0 + n) * 3072 + 2048 + h * 64 + d];
                *(float4*)&Vs[n][d] = vv;
            }
        }
        __syncthreads();

        float s[4][4];
#pragma unroll
        for (int i = 0; i < 4; ++i)
#pragma unroll
            for (int j = 0; j < 4; ++j) s[i][j] = 0.f;
        for (int d = 0; d < 64; ++d) {
            float4 qv = *(const float4*)&Qs[d][ty * 4];
            float4 kv = *(const float4*)&Ks[d][tx * 4];
            float qa[4] = {qv.x, qv.y, qv.z, qv.w};
            float ka[4] = {kv.x, kv.y, kv.z, kv.w};
#pragma unroll
            for (int i = 0; i < 4; ++i)
#pragma unroll
                for (int j = 0; j < 4; ++j) s[i][j] = fmaf(qa[i], ka[j], s[i][j]);
        }

        int hk[4];
#pragma unroll
        for (int j = 0; j < 4; ++j) hk[j] = is_hub[n0 + tx * 4 + j];
        float rmax[4];
#pragma unroll
        for (int i = 0; i < 4; ++i) rmax[i] = -INFINITY;
#pragma unroll
        for (int i = 0; i < 4; ++i)
#pragma unroll
            for (int j = 0; j < 4; ++j) {
                const bool allowed = same || ((hq[i] == 0) && (hk[j] == 0));
                const float se = allowed ? (s[i][j] + biasv) : -INFINITY;
                s[i][j] = se;
                rmax[i] = fmaxf(rmax[i], se);
            }
#pragma unroll
        for (int off = 1; off < 16; off <<= 1)
#pragma unroll
            for (int i = 0; i < 4; ++i) rmax[i] = fmaxf(rmax[i], __shfl_xor(rmax[i], off));

        float alpha[4];
#pragma unroll
        for (int i = 0; i < 4; ++i) {
            const float mn = fmaxf(m_i[i], rmax[i]);
            alpha[i] = (mn == -INFINITY) ? 1.f : __expf(m_i[i] - mn);
            m_i[i] = mn;
        }
        float p[4][4], rsum[4];
#pragma unroll
        for (int i = 0; i < 4; ++i) rsum[i] = 0.f;
#pragma unroll
        for (int i = 0; i < 4; ++i)
#pragma unroll
            for (int j = 0; j < 4; ++j) {
                const float pv = (s[i][j] == -INFINITY) ? 0.f : __expf(s[i][j] - m_i[i]);
                p[i][j] = pv;
                rsum[i] += pv;
            }
#pragma unroll
        for (int off = 1; off < 16; off <<= 1)
#pragma unroll
            for (int i = 0; i < 4; ++i) rsum[i] += __shfl_xor(rsum[i], off);
#pragma unroll
        for (int i = 0; i < 4; ++i) {
            l_i[i] = l_i[i] * alpha[i] + rsum[i];
#pragma unroll
            for (int j = 0; j < 4; ++j) o[i][j] *= alpha[i];
        }

#pragma unroll
        for (int i = 0; i < 4; ++i)
#pragma unroll
            for (int j = 0; j < 4; ++j) Ps[tx * 4 + j][ty * 4 + i] = p[i][j];
        __syncthreads();
        for (int n = 0; n < 64; ++n) {
            float4 pv = *(const float4*)&Ps[n][ty * 4];
            float4 vv = *(const float4*)&Vs[n][tx * 4];
            float pa[4] = {pv.x, pv.y, pv.z, pv.w};
            float va[4] = {vv.x, vv.y, vv.z, vv.w};
#pragma unroll
            for (int i = 0; i < 4; ++i)
#pragma unroll
                for (int j = 0; j < 4; ++j) o[i][j] = fmaf(pa[i], va[j], o[i][j]);
        }
    }

#pragma unroll
    for (int i = 0; i < 4; ++i) {
        const float inv = 1.f / l_i[i];
        float4 st = make_float4(o[i][0] * inv, o[i][1] * inv, o[i][2] * inv, o[i][3] * inv);
        *(float4*)&att[(size_t)(q0 + ty * 4 + i) * CDIM + h * 64 + tx * 4] = st;
    }
}

// ---------------------------------------------------------------------------
extern "C" void kernel_launch(void* const* d_in, const int* in_sizes, int n_in,
                              void* d_out, int out_size, void* d_ws, size_t ws_size,
                              hipStream_t stream) {
    const float* x          = (const float*)d_in[0];
    const float* Wqkv       = (const float*)d_in[1];
    const float* bqkv       = (const float*)d_in[2];
    const float* Wproj      = (const float*)d_in[3];
    const float* bproj      = (const float*)d_in[4];
    const float* frame_bias = (const float*)d_in[5];
    const int*   adj        = (const int*)d_in[6];
    const int*   is_hub     = (const int*)d_in[8];
    float* out = (float*)d_out;

    char* ws = (char*)d_ws;
    size_t off = 0;
    float* qkv = (float*)(ws + off); off += (size_t)NTOK * 3 * CDIM * 4;   // 25.2 MB
    float* att = (float*)(ws + off); off += (size_t)NTOK * CDIM * 4;       // 8.4 MB
    unsigned short* xh  = (unsigned short*)(ws + off); off += (size_t)NTOK * CDIM * 2;
    unsigned short* xl  = (unsigned short*)(ws + off); off += (size_t)NTOK * CDIM * 2;
    unsigned short* wqh = (unsigned short*)(ws + off); off += (size_t)3 * CDIM * CDIM * 2;
    unsigned short* wql = (unsigned short*)(ws + off); off += (size_t)3 * CDIM * CDIM * 2;
    unsigned short* wph = (unsigned short*)(ws + off); off += (size_t)CDIM * CDIM * 2;
    unsigned short* wpl = (unsigned short*)(ws + off); off += (size_t)CDIM * CDIM * 2;
    unsigned short* ath = (unsigned short*)(ws + off); off += (size_t)NTOK * CDIM * 2;
    unsigned short* atl = (unsigned short*)(ws + off); off += (size_t)NTOK * CDIM * 2;

    // split inputs to bf16 hi/lo
    split_bf16<<<(NTOK * CDIM / 4) / 256, 256, 0, stream>>>(x, xh, xl, NTOK * CDIM / 4);
    split_bf16<<<(3 * CDIM * CDIM / 4) / 256, 256, 0, stream>>>(Wqkv, wqh, wql, 3 * CDIM * CDIM / 4);
    split_bf16<<<(CDIM * CDIM / 4) / 256, 256, 0, stream>>>(Wproj, wph, wpl, CDIM * CDIM / 4);

    // 1) QKV projection (MFMA split)
    gemm_mfma_split<NTOK, 3 * CDIM, CDIM>
        <<<dim3((3 * CDIM) / 128, NTOK / 128), 256, 0, stream>>>(xh, xl, wqh, wql, bqkv, qkv);
    // 2) sparse attention (f32)
    attn_kernel<<<dim3(NHEAD, NTOK / 64), 256, 0, stream>>>(qkv, frame_bias, adj, is_hub, att);
    // 3) split attention output, then output projection (MFMA split)
    split_bf16<<<(NTOK * CDIM / 4) / 256, 256, 0, stream>>>(att, ath, atl, NTOK * CDIM / 4);
    gemm_mfma_split<NTOK, CDIM, CDIM>
        <<<dim3(CDIM / 128, NTOK / 128), 256, 0, stream>>>(ath, atl, wph, wpl, bproj, out);
}

// Round 3
// 148.838 us; speedup vs baseline: 2.8486x; 1.5113x over previous
//
#include <hip/hip_runtime.h>
#include <hip/hip_bf16.h>
#include <math.h>

// Problem constants
#define NTOK 2048
#define CDIM 1024
#define NHEAD 16
#define HDIM 64
// frame id = token >> 8 (8 frames of 256 tokens)

typedef __attribute__((ext_vector_type(8))) short bf16x8;
typedef __attribute__((ext_vector_type(4))) float f32x4;
typedef __attribute__((ext_vector_type(4))) unsigned int u32x4;

// ---------------------------------------------------------------------------
// f32 -> bf16 helpers (round-to-nearest-even) and hi/lo split
// ---------------------------------------------------------------------------
__device__ inline unsigned short bf16_rn(float f) {
    unsigned int u = __float_as_uint(f);
    u += 0x7FFFu + ((u >> 16) & 1u);
    return (unsigned short)(u >> 16);
}

__device__ inline void split4(float4 v, ushort4& h, ushort4& l) {
    float a[4] = {v.x, v.y, v.z, v.w};
    unsigned short hs[4], ls[4];
#pragma unroll
    for (int j = 0; j < 4; ++j) {
        hs[j] = bf16_rn(a[j]);
        float hf = __uint_as_float((unsigned int)hs[j] << 16);
        ls[j] = bf16_rn(a[j] - hf);
    }
    h.x = hs[0]; h.y = hs[1]; h.z = hs[2]; h.w = hs[3];
    l.x = ls[0]; l.y = ls[1]; l.z = ls[2]; l.w = ls[3];
}

__global__ __launch_bounds__(256) void split_bf16(const float* __restrict__ in,
                                                  unsigned short* __restrict__ hi,
                                                  unsigned short* __restrict__ lo,
                                                  int n4) {
    int i = blockIdx.x * 256 + threadIdx.x;
    if (i >= n4) return;
    float4 v = ((const float4*)in)[i];
    ushort4 h, l;
    split4(v, h, l);
    ((ushort4*)hi)[i] = h;
    ((ushort4*)lo)[i] = l;
}

// ---------------------------------------------------------------------------
// MFMA GEMM with hi/lo split inputs (m97 structure) — unchanged from round 2.
// ---------------------------------------------------------------------------
__device__ inline void gload16(const void* g, void* l) {
    __builtin_amdgcn_global_load_lds((const __attribute__((address_space(1))) void*)g,
                                     (__attribute__((address_space(3))) void*)l,
                                     16, 0, 0);
}

template <int M, int N, int K>
__global__ __launch_bounds__(256) void gemm_mfma_split(const unsigned short* __restrict__ Ah,
                                                       const unsigned short* __restrict__ Al,
                                                       const unsigned short* __restrict__ Bh,
                                                       const unsigned short* __restrict__ Bl,
                                                       const float* __restrict__ bias,
                                                       float* __restrict__ C) {
    __shared__ unsigned short sAh[128 * 32];
    __shared__ unsigned short sAl[128 * 32];
    __shared__ unsigned short sBh[128 * 32];
    __shared__ unsigned short sBl[128 * 32];

    const int tid = threadIdx.x;
    const int lane = tid & 63;
    const int w = tid >> 6;
    const int m0 = blockIdx.y * 128;
    const int n0 = blockIdx.x * 128;
    const int wave_m = (w >> 1) * 64;
    const int wave_n = (w & 1) * 64;
    const int lr = lane & 15;
    const int kg = lane >> 4;

    const int srow0 = w * 32 + (lane >> 2);
    const int scol = (lane & 3) * 8;
    const int ldsbase = w * 1024;

    f32x4 acc[4][4];
#pragma unroll
    for (int i = 0; i < 4; ++i)
#pragma unroll
        for (int j = 0; j < 4; ++j) acc[i][j] = {0.f, 0.f, 0.f, 0.f};

    for (int k0 = 0; k0 < K; k0 += 32) {
        __syncthreads();
#pragma unroll
        for (int j = 0; j < 2; ++j) {
            const int row = srow0 + j * 16;
            const size_t ga = (size_t)(m0 + row) * K + k0 + scol;
            const size_t gb = (size_t)(n0 + row) * K + k0 + scol;
            gload16(Ah + ga, sAh + ldsbase + j * 512);
            gload16(Al + ga, sAl + ldsbase + j * 512);
            gload16(Bh + gb, sBh + ldsbase + j * 512);
            gload16(Bl + gb, sBl + ldsbase + j * 512);
        }
        __syncthreads();

        bf16x8 ah[4], al[4], bh[4], bl[4];
#pragma unroll
        for (int f = 0; f < 4; ++f) {
            const int ra = (wave_m + f * 16 + lr) * 32 + kg * 8;
            const int rb = (wave_n + f * 16 + lr) * 32 + kg * 8;
            ah[f] = *(const bf16x8*)&sAh[ra];
            al[f] = *(const bf16x8*)&sAl[ra];
            bh[f] = *(const bf16x8*)&sBh[rb];
            bl[f] = *(const bf16x8*)&sBl[rb];
        }
#pragma unroll
        for (int fm = 0; fm < 4; ++fm)
#pragma unroll
            for (int fn = 0; fn < 4; ++fn) {
                acc[fm][fn] = __builtin_amdgcn_mfma_f32_16x16x32_bf16(ah[fm], bh[fn], acc[fm][fn], 0, 0, 0);
                acc[fm][fn] = __builtin_amdgcn_mfma_f32_16x16x32_bf16(ah[fm], bl[fn], acc[fm][fn], 0, 0, 0);
                acc[fm][fn] = __builtin_amdgcn_mfma_f32_16x16x32_bf16(al[fm], bh[fn], acc[fm][fn], 0, 0, 0);
            }
    }

    float bv[4];
#pragma unroll
    for (int fn = 0; fn < 4; ++fn) bv[fn] = bias[n0 + wave_n + fn * 16 + lr];
#pragma unroll
    for (int fm = 0; fm < 4; ++fm) {
        const int row0 = m0 + wave_m + fm * 16 + kg * 4;
#pragma unroll
        for (int fn = 0; fn < 4; ++fn) {
            const int col = n0 + wave_n + fn * 16 + lr;
#pragma unroll
            for (int r = 0; r < 4; ++r)
                C[(size_t)(row0 + r) * N + col] = acc[fm][fn][r] + bv[fn];
        }
    }
}

// ---------------------------------------------------------------------------
// MFMA sparse flash attention.
// grid (16 heads, 32 q-blocks of 64). 4 waves, each owns 16 q rows.
// S^T = mfma(K, Q) per 64-kv tile (hi/lo split, 3 terms); softmax in-register
// (lane holds 16 scores of its own q row); PV via permuted-k-slot
// O^T = mfma(V^T, P^T) — P fragments are the softmax registers directly.
// ---------------------------------------------------------------------------
__global__ __launch_bounds__(256) void attn_mfma(const float* __restrict__ qkv,
                                                 const float* __restrict__ frame_bias,
                                                 const int* __restrict__ adj,
                                                 const int* __restrict__ is_hub,
                                                 unsigned short* __restrict__ ath,
                                                 unsigned short* __restrict__ atl) {
    __shared__ unsigned short sKh[64 * 72];  // K hi, row-major [k][d], XOR-swizzled
    __shared__ unsigned short sKl[64 * 72];  // K lo
    __shared__ unsigned short sVt[64 * 68];  // V^T [d][k], plain bf16

    const int h = blockIdx.x;
    const int q0 = blockIdx.y * 64;
    const int tid = threadIdx.x;
    const int lane = tid & 63;
    const int wq = tid >> 6;
    const int lr = lane & 15;
    const int kg = lane >> 4;
    const int fi = q0 >> 8;

    // staging coords: thread -> (row, 16 consecutive d starting at sdb)
    const int srow = tid >> 2;
    const int sdb = (tid & 3) * 16;

    // ---- stage Q (scaled by 1/8) as hi/lo into sKh/sKl, read fragments ----
#pragma unroll
    for (int i = 0; i < 4; ++i) {
        const int d0 = sdb + i * 4;
        float4 v = *(const float4*)&qkv[(size_t)(q0 + srow) * 3072 + h * 64 + d0];
        v.x *= 0.125f; v.y *= 0.125f; v.z *= 0.125f; v.w *= 0.125f;
        ushort4 hv, lv;
        split4(v, hv, lv);
        const int csw = d0 ^ ((srow & 3) << 3);
        *(ushort4*)&sKh[srow * 72 + csw] = hv;
        *(ushort4*)&sKl[srow * 72 + csw] = lv;
    }
    __syncthreads();
    const int qrow = wq * 16 + lr;  // this lane's q row (block-local)
    bf16x8 qh[2], ql[2];
#pragma unroll
    for (int dc = 0; dc < 2; ++dc) {
        const int coff = (dc * 32 + kg * 8) ^ ((qrow & 3) << 3);
        qh[dc] = *(const bf16x8*)&sKh[qrow * 72 + coff];
        ql[dc] = *(const bf16x8*)&sKl[qrow * 72 + coff];
    }
    const bool hq = is_hub[q0 + qrow] != 0;

    float m_i = -INFINITY, l_i = 0.f;
    f32x4 oacc[4];
#pragma unroll
    for (int fd = 0; fd < 4; ++fd) oacc[fd] = {0.f, 0.f, 0.f, 0.f};

    for (int n0 = 0; n0 < NTOK; n0 += 64) {
        const int fj = n0 >> 8;
        if (!adj[fi * 8 + fj]) continue;  // block-uniform tile skip
        const bool same = (fi == fj);
        const float biasv = frame_bias[fi * 8 + fj];
        const unsigned long long hubmask = __ballot(is_hub[n0 + lane] != 0);

        __syncthreads();  // previous tile's LDS reads done
        // ---- stage K (hi/lo, row-major swizzled) and V^T (bf16) ----
#pragma unroll
        for (int i = 0; i < 4; ++i) {
            const int d0 = sdb + i * 4;
            float4 kv = *(const float4*)&qkv[(size_t)(n0 + srow) * 3072 + 1024 + h * 64 + d0];
            ushort4 hv, lv;
            split4(kv, hv, lv);
            const int csw = d0 ^ ((srow & 3) << 3);
            *(ushort4*)&sKh[srow * 72 + csw] = hv;
            *(ushort4*)&sKl[srow * 72 + csw] = lv;
            float4 vv = *(const float4*)&qkv[(size_t)(n0 + srow) * 3072 + 2048 + h * 64 + d0];
            sVt[(d0 + 0) * 68 + srow] = bf16_rn(vv.x);
            sVt[(d0 + 1) * 68 + srow] = bf16_rn(vv.y);
            sVt[(d0 + 2) * 68 + srow] = bf16_rn(vv.z);
            sVt[(d0 + 3) * 68 + srow] = bf16_rn(vv.w);
        }
        __syncthreads();

        // ---- S^T[k][q] = K . Q^T  (hi/lo: Kh*Qh + Kl*Qh + Kh*Ql) ----
        f32x4 sacc[4];
#pragma unroll
        for (int fk = 0; fk < 4; ++fk) sacc[fk] = {0.f, 0.f, 0.f, 0.f};
#pragma unroll
        for (int fk = 0; fk < 4; ++fk) {
            const int r = fk * 16 + lr;
#pragma unroll
            for (int dc = 0; dc < 2; ++dc) {
                const int coff = (dc * 32 + kg * 8) ^ ((r & 3) << 3);
                bf16x8 kh = *(const bf16x8*)&sKh[r * 72 + coff];
                bf16x8 kl = *(const bf16x8*)&sKl[r * 72 + coff];
                sacc[fk] = __builtin_amdgcn_mfma_f32_16x16x32_bf16(kh, qh[dc], sacc[fk], 0, 0, 0);
                sacc[fk] = __builtin_amdgcn_mfma_f32_16x16x32_bf16(kl, qh[dc], sacc[fk], 0, 0, 0);
                sacc[fk] = __builtin_amdgcn_mfma_f32_16x16x32_bf16(kh, ql[dc], sacc[fk], 0, 0, 0);
            }
        }

        // ---- mask + bias; lane holds 16 scores of q row `qrow`,
        //      at k = fk*16 + kg*4 + r ----
        float sv[4][4];
        float rmax = -INFINITY;
#pragma unroll
        for (int fk = 0; fk < 4; ++fk)
#pragma unroll
            for (int r = 0; r < 4; ++r) {
                float val = sacc[fk][r] + biasv;
                if (!same) {
                    const int k = fk * 16 + kg * 4 + r;
                    const bool hk = (hubmask >> k) & 1ull;
                    if (hq || hk) val = -INFINITY;
                }
                sv[fk][r] = val;
                rmax = fmaxf(rmax, val);
            }
        // row-reduce across the 4 lanes sharing this q (l, l^16, l^32, l^48)
        rmax = fmaxf(rmax, __shfl_xor(rmax, 16));
        rmax = fmaxf(rmax, __shfl_xor(rmax, 32));

        const float mn = fmaxf(m_i, rmax);
        const float alpha = (mn == -INFINITY) ? 1.f : __expf(m_i - mn);
        m_i = mn;

        float p[4][4];
        float psum = 0.f;
#pragma unroll
        for (int fk = 0; fk < 4; ++fk)
#pragma unroll
            for (int r = 0; r < 4; ++r) {
                const float pv = (sv[fk][r] == -INFINITY) ? 0.f : __expf(sv[fk][r] - mn);
                p[fk][r] = pv;
                psum += pv;
            }
        psum += __shfl_xor(psum, 16);
        psum += __shfl_xor(psum, 32);
        l_i = l_i * alpha + psum;
#pragma unroll
        for (int fd = 0; fd < 4; ++fd) {
            oacc[fd][0] *= alpha; oacc[fd][1] *= alpha;
            oacc[fd][2] *= alpha; oacc[fd][3] *= alpha;
        }

        // ---- pack P to bf16 (k slots permuted to match V^T reads) ----
        unsigned int pc[4][2];
#pragma unroll
        for (int fk = 0; fk < 4; ++fk)
#pragma unroll
            for (int rp = 0; rp < 2; ++rp)
                pc[fk][rp] = (unsigned int)bf16_rn(p[fk][2 * rp]) |
                             ((unsigned int)bf16_rn(p[fk][2 * rp + 1]) << 16);

        // ---- O^T += V^T . P^T  (k-slot s of chunk c <-> k=(2c+(s&7)/4)*16+(s>>3)*4+(s&3)) ----
#pragma unroll
        for (int c = 0; c < 2; ++c) {
            u32x4 pw = {pc[2 * c][0], pc[2 * c][1], pc[2 * c + 1][0], pc[2 * c + 1][1]};
            bf16x8 pb = __builtin_bit_cast(bf16x8, pw);
#pragma unroll
            for (int fd = 0; fd < 4; ++fd) {
                const int vrow = fd * 16 + lr;
                ushort4 v0 = *(const ushort4*)&sVt[vrow * 68 + c * 32 + kg * 4];
                ushort4 v1 = *(const ushort4*)&sVt[vrow * 68 + c * 32 + 16 + kg * 4];
                bf16x8 va;
                va[0] = (short)v0.x; va[1] = (short)v0.y; va[2] = (short)v0.z; va[3] = (short)v0.w;
                va[4] = (short)v1.x; va[5] = (short)v1.y; va[6] = (short)v1.z; va[7] = (short)v1.w;
                oacc[fd] = __builtin_amdgcn_mfma_f32_16x16x32_bf16(va, pb, oacc[fd], 0, 0, 0);
            }
        }
    }

    // ---- epilogue: O^T[d][q] -> att hi/lo bf16, [token][h*64+d] ----
    const float inv = 1.f / l_i;
#pragma unroll
    for (int fd = 0; fd < 4; ++fd)
#pragma unroll
        for (int r = 0; r < 4; ++r) {
            const float o = oacc[fd][r] * inv;
            const unsigned short hb = bf16_rn(o);
            const float hf = __uint_as_float((unsigned int)hb << 16);
            const unsigned short lb = bf16_rn(o - hf);
            const size_t idx = (size_t)(q0 + qrow) * CDIM + h * 64 + fd * 16 + kg * 4 + r;
            ath[idx] = hb;
            atl[idx] = lb;
        }
}

// ---------------------------------------------------------------------------
extern "C" void kernel_launch(void* const* d_in, const int* in_sizes, int n_in,
                              void* d_out, int out_size, void* d_ws, size_t ws_size,
                              hipStream_t stream) {
    const float* x          = (const float*)d_in[0];
    const float* Wqkv       = (const float*)d_in[1];
    const float* bqkv       = (const float*)d_in[2];
    const float* Wproj      = (const float*)d_in[3];
    const float* bproj      = (const float*)d_in[4];
    const float* frame_bias = (const float*)d_in[5];
    const int*   adj        = (const int*)d_in[6];
    const int*   is_hub     = (const int*)d_in[8];
    float* out = (float*)d_out;

    char* ws = (char*)d_ws;
    size_t off = 0;
    float* qkv = (float*)(ws + off); off += (size_t)NTOK * 3 * CDIM * 4;   // 25.2 MB
    unsigned short* xh  = (unsigned short*)(ws + off); off += (size_t)NTOK * CDIM * 2;
    unsigned short* xl  = (unsigned short*)(ws + off); off += (size_t)NTOK * CDIM * 2;
    unsigned short* wqh = (unsigned short*)(ws + off); off += (size_t)3 * CDIM * CDIM * 2;
    unsigned short* wql = (unsigned short*)(ws + off); off += (size_t)3 * CDIM * CDIM * 2;
    unsigned short* wph = (unsigned short*)(ws + off); off += (size_t)CDIM * CDIM * 2;
    unsigned short* wpl = (unsigned short*)(ws + off); off += (size_t)CDIM * CDIM * 2;
    unsigned short* ath = (unsigned short*)(ws + off); off += (size_t)NTOK * CDIM * 2;
    unsigned short* atl = (unsigned short*)(ws + off); off += (size_t)NTOK * CDIM * 2;

    // split inputs to bf16 hi/lo
    split_bf16<<<(NTOK * CDIM / 4) / 256, 256, 0, stream>>>(x, xh, xl, NTOK * CDIM / 4);
    split_bf16<<<(3 * CDIM * CDIM / 4) / 256, 256, 0, stream>>>(Wqkv, wqh, wql, 3 * CDIM * CDIM / 4);
    split_bf16<<<(CDIM * CDIM / 4) / 256, 256, 0, stream>>>(Wproj, wph, wpl, CDIM * CDIM / 4);

    // 1) QKV projection (MFMA split)
    gemm_mfma_split<NTOK, 3 * CDIM, CDIM>
        <<<dim3((3 * CDIM) / 128, NTOK / 128), 256, 0, stream>>>(xh, xl, wqh, wql, bqkv, qkv);
    // 2) sparse attention (MFMA), writes hi/lo bf16 directly
    attn_mfma<<<dim3(NHEAD, NTOK / 64), 256, 0, stream>>>(qkv, frame_bias, adj, is_hub, ath, atl);
    // 3) output projection (MFMA split)
    gemm_mfma_split<NTOK, CDIM, CDIM>
        <<<dim3(CDIM / 128, NTOK / 128), 256, 0, stream>>>(ath, atl, wph, wpl, bproj, out);
}

// Round 4
// 127.871 us; speedup vs baseline: 3.3157x; 1.1640x over previous
//
#include <hip/hip_runtime.h>
#include <hip/hip_bf16.h>
#include <math.h>

// Problem constants
#define NTOK 2048
#define CDIM 1024
#define NHEAD 16
#define HDIM 64
// frame id = token >> 8 (8 frames of 256 tokens)

typedef __attribute__((ext_vector_type(8))) short bf16x8;
typedef __attribute__((ext_vector_type(4))) float f32x4;
typedef __attribute__((ext_vector_type(4))) unsigned int u32x4;

// ---------------------------------------------------------------------------
// f32 -> bf16 helpers (round-to-nearest-even) and hi/lo split
// ---------------------------------------------------------------------------
__device__ inline unsigned short bf16_rn(float f) {
    unsigned int u = __float_as_uint(f);
    u += 0x7FFFu + ((u >> 16) & 1u);
    return (unsigned short)(u >> 16);
}

__device__ inline void split4(float4 v, ushort4& h, ushort4& l) {
    float a[4] = {v.x, v.y, v.z, v.w};
    unsigned short hs[4], ls[4];
#pragma unroll
    for (int j = 0; j < 4; ++j) {
        hs[j] = bf16_rn(a[j]);
        float hf = __uint_as_float((unsigned int)hs[j] << 16);
        ls[j] = bf16_rn(a[j] - hf);
    }
    h.x = hs[0]; h.y = hs[1]; h.z = hs[2]; h.w = hs[3];
    l.x = ls[0]; l.y = ls[1]; l.z = ls[2]; l.w = ls[3];
}

// One dispatch splitting all three f32 arrays into bf16 hi/lo.
__global__ __launch_bounds__(256) void split3(const float* __restrict__ s0, unsigned short* __restrict__ h0,
                                              unsigned short* __restrict__ l0, int nb0,
                                              const float* __restrict__ s1, unsigned short* __restrict__ h1,
                                              unsigned short* __restrict__ l1, int nb1,
                                              const float* __restrict__ s2, unsigned short* __restrict__ h2,
                                              unsigned short* __restrict__ l2) {
    int b = blockIdx.x;
    const float* s;
    unsigned short *hh, *ll;
    if (b < nb0) { s = s0; hh = h0; ll = l0; }
    else if (b < nb0 + nb1) { s = s1; hh = h1; ll = l1; b -= nb0; }
    else { s = s2; hh = h2; ll = l2; b -= nb0 + nb1; }
    const int i = b * 256 + threadIdx.x;
    float4 v = ((const float4*)s)[i];
    ushort4 h, l;
    split4(v, h, l);
    ((ushort4*)hh)[i] = h;
    ((ushort4*)ll)[i] = l;
}

// ---------------------------------------------------------------------------
// MFMA GEMM, hi/lo split inputs, double-buffered (T3 minimal 2-phase):
// C[M x N] = (Ah+Al) @ (Bh+Bl)^T + bias  (lo*lo dropped)
// BM x BN tile (BM,BN in {64,128}), BK=32, 4 waves (2x2), 16x16x32 MFMA.
// Staging via global_load_lds width-16, linear LDS; next tile issued BEFORE
// current tile's ds_read+MFMA; single __syncthreads (vmcnt drain) per K-step.
// ---------------------------------------------------------------------------
__device__ inline void gload16(const void* g, void* l) {
    __builtin_amdgcn_global_load_lds((const __attribute__((address_space(1))) void*)g,
                                     (__attribute__((address_space(3))) void*)l,
                                     16, 0, 0);
}

template <int BM, int BN, int M, int N, int K>
__global__ __launch_bounds__(256) void gemm_mfma_split(const unsigned short* __restrict__ Ah,
                                                       const unsigned short* __restrict__ Al,
                                                       const unsigned short* __restrict__ Bh,
                                                       const unsigned short* __restrict__ Bl,
                                                       const float* __restrict__ bias,
                                                       float* __restrict__ C) {
    constexpr int FM = BM / 32;            // 16-row fragments per wave (M)
    constexpr int FN = BN / 32;
    constexpr int ASZ = BM * 32;           // elems per A array per buffer
    constexpr int BSZ = BN * 32;
    constexpr int BUF = 2 * (ASZ + BSZ);   // Ah,Al,Bh,Bl per buffer
    __shared__ unsigned short lds[2 * BUF];

    const int tid = threadIdx.x;
    const int lane = tid & 63;
    const int w = tid >> 6;
    const int m0 = blockIdx.y * BM;
    const int n0 = blockIdx.x * BN;
    const int wave_m = (w >> 1) * (BM / 2);
    const int wave_n = (w & 1) * (BN / 2);
    const int lr = lane & 15;
    const int kg = lane >> 4;
    const int srow = tid >> 2;             // staging row
    const int scol = (tid & 3) * 8;        // staging col (bf16 elems)

    f32x4 acc[FM][FN];
#pragma unroll
    for (int i = 0; i < FM; ++i)
#pragma unroll
        for (int j = 0; j < FN; ++j) acc[i][j] = {0.f, 0.f, 0.f, 0.f};

    auto stage = [&](int buf, int k0) {
        unsigned short* bb = lds + buf * BUF;
#pragma unroll
        for (int j = 0; j < BM / 64; ++j) {
            const int row = srow + j * 64;
            const size_t ga = (size_t)(m0 + row) * K + k0 + scol;
            gload16(Ah + ga, bb + row * 32 + scol);
            gload16(Al + ga, bb + ASZ + row * 32 + scol);
        }
#pragma unroll
        for (int j = 0; j < BN / 64; ++j) {
            const int row = srow + j * 64;
            const size_t gb = (size_t)(n0 + row) * K + k0 + scol;
            gload16(Bh + gb, bb + 2 * ASZ + row * 32 + scol);
            gload16(Bl + gb, bb + 2 * ASZ + BSZ + row * 32 + scol);
        }
    };

    stage(0, 0);
    __syncthreads();  // prologue: buf0 ready

    constexpr int NT = K / 32;
    for (int t = 0; t < NT; ++t) {
        const int cur = t & 1;
        if (t + 1 < NT) stage(cur ^ 1, (t + 1) * 32);  // issue next tile first

        const unsigned short* bb = lds + cur * BUF;
        bf16x8 ah[FM], al[FM], bh[FN], bl[FN];
#pragma unroll
        for (int f = 0; f < FM; ++f) {
            const int ra = (wave_m + f * 16 + lr) * 32 + kg * 8;
            ah[f] = *(const bf16x8*)&bb[ra];
            al[f] = *(const bf16x8*)&bb[ASZ + ra];
        }
#pragma unroll
        for (int f = 0; f < FN; ++f) {
            const int rb = (wave_n + f * 16 + lr) * 32 + kg * 8;
            bh[f] = *(const bf16x8*)&bb[2 * ASZ + rb];
            bl[f] = *(const bf16x8*)&bb[2 * ASZ + BSZ + rb];
        }
#pragma unroll
        for (int fm = 0; fm < FM; ++fm)
#pragma unroll
            for (int fn = 0; fn < FN; ++fn) {
                acc[fm][fn] = __builtin_amdgcn_mfma_f32_16x16x32_bf16(ah[fm], bh[fn], acc[fm][fn], 0, 0, 0);
                acc[fm][fn] = __builtin_amdgcn_mfma_f32_16x16x32_bf16(ah[fm], bl[fn], acc[fm][fn], 0, 0, 0);
                acc[fm][fn] = __builtin_amdgcn_mfma_f32_16x16x32_bf16(al[fm], bh[fn], acc[fm][fn], 0, 0, 0);
            }
        if (t + 1 < NT) __syncthreads();  // buf^1 staged + all reads of it done
    }

    // epilogue: C/D layout col=lane&15, row=(lane>>4)*4+reg  [m89-verified]
    float bv[FN];
#pragma unroll
    for (int fn = 0; fn < FN; ++fn) bv[fn] = bias[n0 + wave_n + fn * 16 + lr];
#pragma unroll
    for (int fm = 0; fm < FM; ++fm) {
        const int row0 = m0 + wave_m + fm * 16 + kg * 4;
#pragma unroll
        for (int fn = 0; fn < FN; ++fn) {
            const int col = n0 + wave_n + fn * 16 + lr;
#pragma unroll
            for (int r = 0; r < 4; ++r)
                C[(size_t)(row0 + r) * N + col] = acc[fm][fn][r] + bv[fn];
        }
    }
}

// ---------------------------------------------------------------------------
// MFMA sparse flash attention — unchanged from round 3 (passed).
// ---------------------------------------------------------------------------
__global__ __launch_bounds__(256) void attn_mfma(const float* __restrict__ qkv,
                                                 const float* __restrict__ frame_bias,
                                                 const int* __restrict__ adj,
                                                 const int* __restrict__ is_hub,
                                                 unsigned short* __restrict__ ath,
                                                 unsigned short* __restrict__ atl) {
    __shared__ unsigned short sKh[64 * 72];  // K hi, row-major [k][d], XOR-swizzled
    __shared__ unsigned short sKl[64 * 72];  // K lo
    __shared__ unsigned short sVt[64 * 68];  // V^T [d][k], plain bf16

    const int h = blockIdx.x;
    const int q0 = blockIdx.y * 64;
    const int tid = threadIdx.x;
    const int lane = tid & 63;
    const int wq = tid >> 6;
    const int lr = lane & 15;
    const int kg = lane >> 4;
    const int fi = q0 >> 8;

    const int srow = tid >> 2;
    const int sdb = (tid & 3) * 16;

#pragma unroll
    for (int i = 0; i < 4; ++i) {
        const int d0 = sdb + i * 4;
        float4 v = *(const float4*)&qkv[(size_t)(q0 + srow) * 3072 + h * 64 + d0];
        v.x *= 0.125f; v.y *= 0.125f; v.z *= 0.125f; v.w *= 0.125f;
        ushort4 hv, lv;
        split4(v, hv, lv);
        const int csw = d0 ^ ((srow & 3) << 3);
        *(ushort4*)&sKh[srow * 72 + csw] = hv;
        *(ushort4*)&sKl[srow * 72 + csw] = lv;
    }
    __syncthreads();
    const int qrow = wq * 16 + lr;
    bf16x8 qh[2], ql[2];
#pragma unroll
    for (int dc = 0; dc < 2; ++dc) {
        const int coff = (dc * 32 + kg * 8) ^ ((qrow & 3) << 3);
        qh[dc] = *(const bf16x8*)&sKh[qrow * 72 + coff];
        ql[dc] = *(const bf16x8*)&sKl[qrow * 72 + coff];
    }
    const bool hq = is_hub[q0 + qrow] != 0;

    float m_i = -INFINITY, l_i = 0.f;
    f32x4 oacc[4];
#pragma unroll
    for (int fd = 0; fd < 4; ++fd) oacc[fd] = {0.f, 0.f, 0.f, 0.f};

    for (int n0 = 0; n0 < NTOK; n0 += 64) {
        const int fj = n0 >> 8;
        if (!adj[fi * 8 + fj]) continue;
        const bool same = (fi == fj);
        const float biasv = frame_bias[fi * 8 + fj];
        const unsigned long long hubmask = __ballot(is_hub[n0 + lane] != 0);

        __syncthreads();
#pragma unroll
        for (int i = 0; i < 4; ++i) {
            const int d0 = sdb + i * 4;
            float4 kv = *(const float4*)&qkv[(size_t)(n0 + srow) * 3072 + 1024 + h * 64 + d0];
            ushort4 hv, lv;
            split4(kv, hv, lv);
            const int csw = d0 ^ ((srow & 3) << 3);
            *(ushort4*)&sKh[srow * 72 + csw] = hv;
            *(ushort4*)&sKl[srow * 72 + csw] = lv;
            float4 vv = *(const float4*)&qkv[(size_t)(n0 + srow) * 3072 + 2048 + h * 64 + d0];
            sVt[(d0 + 0) * 68 + srow] = bf16_rn(vv.x);
            sVt[(d0 + 1) * 68 + srow] = bf16_rn(vv.y);
            sVt[(d0 + 2) * 68 + srow] = bf16_rn(vv.z);
            sVt[(d0 + 3) * 68 + srow] = bf16_rn(vv.w);
        }
        __syncthreads();

        f32x4 sacc[4];
#pragma unroll
        for (int fk = 0; fk < 4; ++fk) sacc[fk] = {0.f, 0.f, 0.f, 0.f};
#pragma unroll
        for (int fk = 0; fk < 4; ++fk) {
            const int r = fk * 16 + lr;
#pragma unroll
            for (int dc = 0; dc < 2; ++dc) {
                const int coff = (dc * 32 + kg * 8) ^ ((r & 3) << 3);
                bf16x8 kh = *(const bf16x8*)&sKh[r * 72 + coff];
                bf16x8 kl = *(const bf16x8*)&sKl[r * 72 + coff];
                sacc[fk] = __builtin_amdgcn_mfma_f32_16x16x32_bf16(kh, qh[dc], sacc[fk], 0, 0, 0);
                sacc[fk] = __builtin_amdgcn_mfma_f32_16x16x32_bf16(kl, qh[dc], sacc[fk], 0, 0, 0);
                sacc[fk] = __builtin_amdgcn_mfma_f32_16x16x32_bf16(kh, ql[dc], sacc[fk], 0, 0, 0);
            }
        }

        float sv[4][4];
        float rmax = -INFINITY;
#pragma unroll
        for (int fk = 0; fk < 4; ++fk)
#pragma unroll
            for (int r = 0; r < 4; ++r) {
                float val = sacc[fk][r] + biasv;
                if (!same) {
                    const int k = fk * 16 + kg * 4 + r;
                    const bool hk = (hubmask >> k) & 1ull;
                    if (hq || hk) val = -INFINITY;
                }
                sv[fk][r] = val;
                rmax = fmaxf(rmax, val);
            }
        rmax = fmaxf(rmax, __shfl_xor(rmax, 16));
        rmax = fmaxf(rmax, __shfl_xor(rmax, 32));

        const float mn = fmaxf(m_i, rmax);
        const float alpha = (mn == -INFINITY) ? 1.f : __expf(m_i - mn);
        m_i = mn;

        float p[4][4];
        float psum = 0.f;
#pragma unroll
        for (int fk = 0; fk < 4; ++fk)
#pragma unroll
            for (int r = 0; r < 4; ++r) {
                const float pv = (sv[fk][r] == -INFINITY) ? 0.f : __expf(sv[fk][r] - mn);
                p[fk][r] = pv;
                psum += pv;
            }
        psum += __shfl_xor(psum, 16);
        psum += __shfl_xor(psum, 32);
        l_i = l_i * alpha + psum;
#pragma unroll
        for (int fd = 0; fd < 4; ++fd) {
            oacc[fd][0] *= alpha; oacc[fd][1] *= alpha;
            oacc[fd][2] *= alpha; oacc[fd][3] *= alpha;
        }

        unsigned int pc[4][2];
#pragma unroll
        for (int fk = 0; fk < 4; ++fk)
#pragma unroll
            for (int rp = 0; rp < 2; ++rp)
                pc[fk][rp] = (unsigned int)bf16_rn(p[fk][2 * rp]) |
                             ((unsigned int)bf16_rn(p[fk][2 * rp + 1]) << 16);

#pragma unroll
        for (int c = 0; c < 2; ++c) {
            u32x4 pw = {pc[2 * c][0], pc[2 * c][1], pc[2 * c + 1][0], pc[2 * c + 1][1]};
            bf16x8 pb = __builtin_bit_cast(bf16x8, pw);
#pragma unroll
            for (int fd = 0; fd < 4; ++fd) {
                const int vrow = fd * 16 + lr;
                ushort4 v0 = *(const ushort4*)&sVt[vrow * 68 + c * 32 + kg * 4];
                ushort4 v1 = *(const ushort4*)&sVt[vrow * 68 + c * 32 + 16 + kg * 4];
                bf16x8 va;
                va[0] = (short)v0.x; va[1] = (short)v0.y; va[2] = (short)v0.z; va[3] = (short)v0.w;
                va[4] = (short)v1.x; va[5] = (short)v1.y; va[6] = (short)v1.z; va[7] = (short)v1.w;
                oacc[fd] = __builtin_amdgcn_mfma_f32_16x16x32_bf16(va, pb, oacc[fd], 0, 0, 0);
            }
        }
    }

    const float inv = 1.f / l_i;
#pragma unroll
    for (int fd = 0; fd < 4; ++fd)
#pragma unroll
        for (int r = 0; r < 4; ++r) {
            const float o = oacc[fd][r] * inv;
            const unsigned short hb = bf16_rn(o);
            const float hf = __uint_as_float((unsigned int)hb << 16);
            const unsigned short lb = bf16_rn(o - hf);
            const size_t idx = (size_t)(q0 + qrow) * CDIM + h * 64 + fd * 16 + kg * 4 + r;
            ath[idx] = hb;
            atl[idx] = lb;
        }
}

// ---------------------------------------------------------------------------
extern "C" void kernel_launch(void* const* d_in, const int* in_sizes, int n_in,
                              void* d_out, int out_size, void* d_ws, size_t ws_size,
                              hipStream_t stream) {
    const float* x          = (const float*)d_in[0];
    const float* Wqkv       = (const float*)d_in[1];
    const float* bqkv       = (const float*)d_in[2];
    const float* Wproj      = (const float*)d_in[3];
    const float* bproj      = (const float*)d_in[4];
    const float* frame_bias = (const float*)d_in[5];
    const int*   adj        = (const int*)d_in[6];
    const int*   is_hub     = (const int*)d_in[8];
    float* out = (float*)d_out;

    char* ws = (char*)d_ws;
    size_t off = 0;
    float* qkv = (float*)(ws + off); off += (size_t)NTOK * 3 * CDIM * 4;
    unsigned short* xh  = (unsigned short*)(ws + off); off += (size_t)NTOK * CDIM * 2;
    unsigned short* xl  = (unsigned short*)(ws + off); off += (size_t)NTOK * CDIM * 2;
    unsigned short* wqh = (unsigned short*)(ws + off); off += (size_t)3 * CDIM * CDIM * 2;
    unsigned short* wql = (unsigned short*)(ws + off); off += (size_t)3 * CDIM * CDIM * 2;
    unsigned short* wph = (unsigned short*)(ws + off); off += (size_t)CDIM * CDIM * 2;
    unsigned short* wpl = (unsigned short*)(ws + off); off += (size_t)CDIM * CDIM * 2;
    unsigned short* ath = (unsigned short*)(ws + off); off += (size_t)NTOK * CDIM * 2;
    unsigned short* atl = (unsigned short*)(ws + off); off += (size_t)NTOK * CDIM * 2;

    // split x, Wqkv, Wproj in one dispatch
    const int nb_x = (NTOK * CDIM / 4) / 256;          // 2048
    const int nb_wq = (3 * CDIM * CDIM / 4) / 256;     // 3072
    const int nb_wp = (CDIM * CDIM / 4) / 256;         // 1024
    split3<<<nb_x + nb_wq + nb_wp, 256, 0, stream>>>(x, xh, xl, nb_x,
                                                     Wqkv, wqh, wql, nb_wq,
                                                     Wproj, wph, wpl);

    // 1) QKV projection (128x128 tiles, dbuf)
    gemm_mfma_split<128, 128, NTOK, 3 * CDIM, CDIM>
        <<<dim3((3 * CDIM) / 128, NTOK / 128), 256, 0, stream>>>(xh, xl, wqh, wql, bqkv, qkv);
    // 2) sparse attention (MFMA), writes hi/lo bf16 directly
    attn_mfma<<<dim3(NHEAD, NTOK / 64), 256, 0, stream>>>(qkv, frame_bias, adj, is_hub, ath, atl);
    // 3) output projection (64x128 tiles -> 256 blocks, dbuf)
    gemm_mfma_split<64, 128, NTOK, CDIM, CDIM>
        <<<dim3(CDIM / 128, NTOK / 64), 256, 0, stream>>>(ath, atl, wph, wpl, bproj, out);
}

// Round 5
// 122.482 us; speedup vs baseline: 3.4615x; 1.0440x over previous
//
#include <hip/hip_runtime.h>
#include <hip/hip_bf16.h>
#include <math.h>

// Problem constants
#define NTOK 2048
#define CDIM 1024
#define NHEAD 16
#define HDIM 64
// frame id = token >> 8 (8 frames of 256 tokens)

typedef __attribute__((ext_vector_type(8))) short bf16x8;
typedef __attribute__((ext_vector_type(4))) short bf16x4;
typedef __attribute__((ext_vector_type(4))) float f32x4;
typedef __attribute__((ext_vector_type(4))) unsigned int u32x4;

// ---------------------------------------------------------------------------
// helpers
// ---------------------------------------------------------------------------
__device__ inline unsigned short bf16_rn(float f) {
    unsigned int u = __float_as_uint(f);
    u += 0x7FFFu + ((u >> 16) & 1u);
    return (unsigned short)(u >> 16);
}

__device__ inline void split4(float4 v, ushort4& h, ushort4& l) {
    float a[4] = {v.x, v.y, v.z, v.w};
    unsigned short hs[4], ls[4];
#pragma unroll
    for (int j = 0; j < 4; ++j) {
        hs[j] = bf16_rn(a[j]);
        float hf = __uint_as_float((unsigned int)hs[j] << 16);
        ls[j] = bf16_rn(a[j] - hf);
    }
    h.x = hs[0]; h.y = hs[1]; h.z = hs[2]; h.w = hs[3];
    l.x = ls[0]; l.y = ls[1]; l.z = ls[2]; l.w = ls[3];
}

template <int N> __device__ inline void waitcnt_vm() {
    if constexpr (N == 0) asm volatile("s_waitcnt vmcnt(0)" ::: "memory");
    else if constexpr (N == 6) asm volatile("s_waitcnt vmcnt(6)" ::: "memory");
    else if constexpr (N == 8) asm volatile("s_waitcnt vmcnt(8)" ::: "memory");
}

__device__ inline void gload16(const void* g, void* l) {
    __builtin_amdgcn_global_load_lds((const __attribute__((address_space(1))) void*)g,
                                     (__attribute__((address_space(3))) void*)l,
                                     16, 0, 0);
}

// One dispatch splitting the three f32 inputs into bf16 hi/lo.
__global__ __launch_bounds__(256) void split3(const float* __restrict__ s0, unsigned short* __restrict__ h0,
                                              unsigned short* __restrict__ l0, int nb0,
                                              const float* __restrict__ s1, unsigned short* __restrict__ h1,
                                              unsigned short* __restrict__ l1, int nb1,
                                              const float* __restrict__ s2, unsigned short* __restrict__ h2,
                                              unsigned short* __restrict__ l2) {
    int b = blockIdx.x;
    const float* s;
    unsigned short *hh, *ll;
    if (b < nb0) { s = s0; hh = h0; ll = l0; }
    else if (b < nb0 + nb1) { s = s1; hh = h1; ll = l1; b -= nb0; }
    else { s = s2; hh = h2; ll = l2; b -= nb0 + nb1; }
    const int i = b * 256 + threadIdx.x;
    float4 v = ((const float4*)s)[i];
    ushort4 h, l;
    split4(v, h, l);
    ((ushort4*)hh)[i] = h;
    ((ushort4*)ll)[i] = l;
}

// ---------------------------------------------------------------------------
// MFMA GEMM, hi/lo split inputs, counted-vmcnt double buffer (T3+T4 minimum).
// MODE 0 (PROJ): C = f32 out + bias.
// MODE 1 (QKV): epilogue writes attention-ready bf16 buffers:
//   qhg/qlg[h][tok][d ^ ((tok&7)<<3)]  (pre-scaled by 0.125)
//   khg/klg[h][tok][d ^ ((tok&7)<<3)]
//   vtg[h][d][tok ^ ((d&7)<<3)]        (V transposed, plain bf16)
// ---------------------------------------------------------------------------
template <int BM, int BN, int M, int N, int K, int MODE>
__global__ __launch_bounds__(256) void gemm_mfma_split(const unsigned short* __restrict__ Ah,
                                                       const unsigned short* __restrict__ Al,
                                                       const unsigned short* __restrict__ Bh,
                                                       const unsigned short* __restrict__ Bl,
                                                       const float* __restrict__ bias,
                                                       float* __restrict__ C,
                                                       unsigned short* __restrict__ qhg,
                                                       unsigned short* __restrict__ qlg,
                                                       unsigned short* __restrict__ khg,
                                                       unsigned short* __restrict__ klg,
                                                       unsigned short* __restrict__ vtg) {
    constexpr int FM = BM / 32;
    constexpr int FN = BN / 32;
    constexpr int ASZ = BM * 32;
    constexpr int BSZ = BN * 32;
    constexpr int BUF = 2 * (ASZ + BSZ);
    __shared__ unsigned short lds[2 * BUF];

    const int tid = threadIdx.x;
    const int lane = tid & 63;
    const int w = tid >> 6;
    const int m0 = blockIdx.y * BM;
    const int n0 = blockIdx.x * BN;
    const int wave_m = (w >> 1) * (BM / 2);
    const int wave_n = (w & 1) * (BN / 2);
    const int lr = lane & 15;
    const int kg = lane >> 4;
    const int srow = tid >> 2;
    const int scol = (tid & 3) * 8;

    f32x4 acc[FM][FN];
#pragma unroll
    for (int i = 0; i < FM; ++i)
#pragma unroll
        for (int j = 0; j < FN; ++j) acc[i][j] = {0.f, 0.f, 0.f, 0.f};

    auto stage = [&](int buf, int k0) {
        unsigned short* bb = lds + buf * BUF;
#pragma unroll
        for (int j = 0; j < BM / 64; ++j) {
            const int row = srow + j * 64;
            const size_t ga = (size_t)(m0 + row) * K + k0 + scol;
            gload16(Ah + ga, bb + row * 32 + scol);
            gload16(Al + ga, bb + ASZ + row * 32 + scol);
        }
#pragma unroll
        for (int j = 0; j < BN / 64; ++j) {
            const int row = srow + j * 64;
            const size_t gb = (size_t)(n0 + row) * K + k0 + scol;
            gload16(Bh + gb, bb + 2 * ASZ + row * 32 + scol);
            gload16(Bl + gb, bb + 2 * ASZ + BSZ + row * 32 + scol);
        }
    };

    stage(0, 0);
    constexpr int NL = 2 * (BM / 64) + 2 * (BN / 64);
    constexpr int NT = K / 32;
    for (int t = 0; t < NT; ++t) {
        const int cur = t & 1;
        if (t + 1 < NT) {
            stage(cur ^ 1, (t + 1) * 32);
            waitcnt_vm<NL>();   // own current-tile loads complete; next stays in flight
        } else {
            waitcnt_vm<0>();
        }
        __builtin_amdgcn_s_barrier();  // everyone's current tile is in LDS

        const unsigned short* bb = lds + cur * BUF;
        bf16x8 ah[FM], al[FM], bh[FN], bl[FN];
#pragma unroll
        for (int f = 0; f < FM; ++f) {
            const int ra = (wave_m + f * 16 + lr) * 32 + kg * 8;
            ah[f] = *(const bf16x8*)&bb[ra];
            al[f] = *(const bf16x8*)&bb[ASZ + ra];
        }
#pragma unroll
        for (int f = 0; f < FN; ++f) {
            const int rb = (wave_n + f * 16 + lr) * 32 + kg * 8;
            bh[f] = *(const bf16x8*)&bb[2 * ASZ + rb];
            bl[f] = *(const bf16x8*)&bb[2 * ASZ + BSZ + rb];
        }
#pragma unroll
        for (int fm = 0; fm < FM; ++fm)
#pragma unroll
            for (int fn = 0; fn < FN; ++fn) {
                acc[fm][fn] = __builtin_amdgcn_mfma_f32_16x16x32_bf16(ah[fm], bh[fn], acc[fm][fn], 0, 0, 0);
                acc[fm][fn] = __builtin_amdgcn_mfma_f32_16x16x32_bf16(ah[fm], bl[fn], acc[fm][fn], 0, 0, 0);
                acc[fm][fn] = __builtin_amdgcn_mfma_f32_16x16x32_bf16(al[fm], bh[fn], acc[fm][fn], 0, 0, 0);
            }
        asm volatile("" ::: "memory");
        __builtin_amdgcn_s_barrier();  // reads done; next iter may overwrite this buf
    }

    // epilogue: C/D layout col=lane&15, row=(lane>>4)*4+reg  [m89-verified]
    if constexpr (MODE == 0) {
        float bv[FN];
#pragma unroll
        for (int fn = 0; fn < FN; ++fn) bv[fn] = bias[n0 + wave_n + fn * 16 + lr];
#pragma unroll
        for (int fm = 0; fm < FM; ++fm) {
            const int row0 = m0 + wave_m + fm * 16 + kg * 4;
#pragma unroll
            for (int fn = 0; fn < FN; ++fn) {
                const int col = n0 + wave_n + fn * 16 + lr;
#pragma unroll
                for (int r = 0; r < 4; ++r)
                    C[(size_t)(row0 + r) * N + col] = acc[fm][fn][r] + bv[fn];
            }
        }
    } else {
        const int reg = n0 >> 10;  // 0=q, 1=k, 2=v (uniform per block)
#pragma unroll
        for (int fn = 0; fn < FN; ++fn) {
            const int col = n0 + wave_n + fn * 16 + lr;
            const int head = (col >> 6) & 15;
            const int d = col & 63;
            const float bv = bias[col];
#pragma unroll
            for (int fm = 0; fm < FM; ++fm) {
                const int row0 = m0 + wave_m + fm * 16 + kg * 4;
                if (reg == 2) {
                    ushort4 pk;
                    pk.x = bf16_rn(acc[fm][fn][0] + bv);
                    pk.y = bf16_rn(acc[fm][fn][1] + bv);
                    pk.z = bf16_rn(acc[fm][fn][2] + bv);
                    pk.w = bf16_rn(acc[fm][fn][3] + bv);
                    const size_t idx = (size_t)(head * 64 + d) * 2048 + (size_t)(row0 ^ ((d & 7) << 3));
                    *(ushort4*)&vtg[idx] = pk;
                } else {
                    const float sc = (reg == 0) ? 0.125f : 1.0f;
                    unsigned short* hp = (reg == 0) ? qhg : khg;
                    unsigned short* lp = (reg == 0) ? qlg : klg;
#pragma unroll
                    for (int r = 0; r < 4; ++r) {
                        const int tok = row0 + r;
                        const float val = (acc[fm][fn][r] + bv) * sc;
                        const unsigned short hb = bf16_rn(val);
                        const unsigned short lb = bf16_rn(val - __uint_as_float((unsigned int)hb << 16));
                        const size_t idx = ((size_t)head * 2048 + tok) * 64 + (d ^ ((tok & 7) << 3));
                        hp[idx] = hb;
                        lp[idx] = lb;
                    }
                }
            }
        }
    }
}

// ---------------------------------------------------------------------------
// MFMA sparse flash attention, pre-converted bf16 inputs, counted-vmcnt dbuf.
// 1-D grid 512, XCD-decoded so each XCD owns 2 heads. 4 waves x 16 q rows.
// ---------------------------------------------------------------------------
__global__ __launch_bounds__(256) void attn_mfma(const unsigned short* __restrict__ qhg,
                                                 const unsigned short* __restrict__ qlg,
                                                 const unsigned short* __restrict__ khg,
                                                 const unsigned short* __restrict__ klg,
                                                 const unsigned short* __restrict__ vtg,
                                                 const float* __restrict__ frame_bias,
                                                 const int* __restrict__ adj,
                                                 const int* __restrict__ is_hub,
                                                 unsigned short* __restrict__ ath,
                                                 unsigned short* __restrict__ atl) {
    __shared__ unsigned short sBuf[2][3][64 * 64];  // [buf][{kh,kl,vt}]
    __shared__ int sList[32];
    __shared__ float sFB[8];
    __shared__ unsigned long long sHub[32];
    __shared__ int sNT;

    // XCD decode: bid%8 = XCD gets heads {2r, 2r+1}
    const int bid = blockIdx.x;
    const int r8 = bid & 7, tt = bid >> 3;
    const int qb = tt & 31, hb = tt >> 5;
    const int h = r8 * 2 + hb;
    const int q0 = qb * 64;

    const int tid = threadIdx.x;
    const int lane = tid & 63;
    const int wq = tid >> 6;
    const int lr = lane & 15;
    const int kg = lane >> 4;
    const int fi = q0 >> 8;

    // ---- Q fragments straight from global (pre-swizzled layout) ----
    const int qrow = wq * 16 + lr;          // block-local q row
    const int qg = q0 + qrow;               // global token
    const unsigned short* qbh = qhg + ((size_t)h * 2048 + qg) * 64;
    const unsigned short* qbl = qlg + ((size_t)h * 2048 + qg) * 64;
    const int Xq = (qg & 7) << 3;
    bf16x8 qh[2], ql[2];
#pragma unroll
    for (int dc = 0; dc < 2; ++dc) {
        const int off = (dc * 32 + kg * 8) ^ Xq;
        qh[dc] = *(const bf16x8*)&qbh[off];
        ql[dc] = *(const bf16x8*)&qbl[off];
    }
    const bool hq = is_hub[qg] != 0;

    // ---- prologue tables: allowed-tile list, bias row, hub masks ----
#pragma unroll 1
    for (int t2 = 0; t2 < 32; ++t2) {
        unsigned long long mb = __ballot(is_hub[t2 * 64 + lane] != 0);
        if (tid == 0) sHub[t2] = mb;
    }
    if (tid < 8) sFB[tid] = frame_bias[fi * 8 + tid];
    if (tid == 0) {
        int c = 0;
#pragma unroll 1
        for (int t2 = 0; t2 < 32; ++t2)
            if (adj[fi * 8 + (t2 >> 2)]) sList[c++] = t2;
        sNT = c;
    }
    __syncthreads();
    const int nt = sNT;

    // staging: thread -> chunks tid and tid+256 of each 64x64 u16 tile
    const int crow = tid >> 3;
    const int ccol = (tid & 7) * 8;
    const unsigned short* kbase = khg + (size_t)h * 2048 * 64;
    const unsigned short* lbase = klg + (size_t)h * 2048 * 64;
    const unsigned short* vbase = vtg + (size_t)h * 64 * 2048;

    auto stage = [&](int buf, int n0) {
        unsigned short* b0 = &sBuf[buf][0][0];
        unsigned short* b1 = &sBuf[buf][1][0];
        unsigned short* b2 = &sBuf[buf][2][0];
        const int dst = tid * 8;
        gload16(kbase + (size_t)(n0 + crow) * 64 + ccol, b0 + dst);
        gload16(kbase + (size_t)(n0 + crow + 32) * 64 + ccol, b0 + dst + 2048);
        gload16(lbase + (size_t)(n0 + crow) * 64 + ccol, b1 + dst);
        gload16(lbase + (size_t)(n0 + crow + 32) * 64 + ccol, b1 + dst + 2048);
        gload16(vbase + (size_t)crow * 2048 + n0 + ccol, b2 + dst);
        gload16(vbase + (size_t)(crow + 32) * 2048 + n0 + ccol, b2 + dst + 2048);
    };

    float m_i = -INFINITY, l_i = 0.f;
    f32x4 oacc[4];
#pragma unroll
    for (int fd = 0; fd < 4; ++fd) oacc[fd] = {0.f, 0.f, 0.f, 0.f};

    stage(0, sList[0] * 64);
#pragma unroll 1
    for (int i = 0; i < nt; ++i) {
        const int cur = i & 1;
        const int tile = sList[i];
        if (i + 1 < nt) {
            stage(cur ^ 1, sList[i + 1] * 64);
            waitcnt_vm<6>();
        } else {
            waitcnt_vm<0>();
        }
        __builtin_amdgcn_s_barrier();

        const int fj = tile >> 2;
        const bool same = (fj == fi);
        const float biasv = sFB[fj];
        const unsigned long long hubmask = sHub[tile];
        const unsigned short* sKh = &sBuf[cur][0][0];
        const unsigned short* sKl = &sBuf[cur][1][0];
        const unsigned short* sVt = &sBuf[cur][2][0];

        // ---- S^T = K . Q^T (hi/lo) ----
        f32x4 sacc[4];
#pragma unroll
        for (int fk = 0; fk < 4; ++fk) sacc[fk] = {0.f, 0.f, 0.f, 0.f};
#pragma unroll
        for (int fk = 0; fk < 4; ++fk) {
            const int r = fk * 16 + lr;
            const int Xk = (r & 7) << 3;
            const int rb = r * 64;
#pragma unroll
            for (int dc = 0; dc < 2; ++dc) {
                const int off = rb + ((dc * 32 + kg * 8) ^ Xk);
                bf16x8 khf = *(const bf16x8*)&sKh[off];
                bf16x8 klf = *(const bf16x8*)&sKl[off];
                sacc[fk] = __builtin_amdgcn_mfma_f32_16x16x32_bf16(khf, qh[dc], sacc[fk], 0, 0, 0);
                sacc[fk] = __builtin_amdgcn_mfma_f32_16x16x32_bf16(klf, qh[dc], sacc[fk], 0, 0, 0);
                sacc[fk] = __builtin_amdgcn_mfma_f32_16x16x32_bf16(khf, ql[dc], sacc[fk], 0, 0, 0);
            }
        }

        // ---- mask + bias + online softmax (lane owns 16 scores of its q) ----
        float sv[4][4];
        float rmax = -INFINITY;
#pragma unroll
        for (int fk = 0; fk < 4; ++fk)
#pragma unroll
            for (int r = 0; r < 4; ++r) {
                float val = sacc[fk][r] + biasv;
                if (!same) {
                    const int k = fk * 16 + kg * 4 + r;
                    const bool hk = (hubmask >> k) & 1ull;
                    if (hq || hk) val = -INFINITY;
                }
                sv[fk][r] = val;
                rmax = fmaxf(rmax, val);
            }
        rmax = fmaxf(rmax, __shfl_xor(rmax, 16));
        rmax = fmaxf(rmax, __shfl_xor(rmax, 32));

        const float mn = fmaxf(m_i, rmax);
        const float alpha = (mn == -INFINITY) ? 1.f : __expf(m_i - mn);
        m_i = mn;

        float p[4][4];
        float psum = 0.f;
#pragma unroll
        for (int fk = 0; fk < 4; ++fk)
#pragma unroll
            for (int r = 0; r < 4; ++r) {
                const float pv = (sv[fk][r] == -INFINITY) ? 0.f : __expf(sv[fk][r] - mn);
                p[fk][r] = pv;
                psum += pv;
            }
        psum += __shfl_xor(psum, 16);
        psum += __shfl_xor(psum, 32);
        l_i = l_i * alpha + psum;
#pragma unroll
        for (int fd = 0; fd < 4; ++fd) {
            oacc[fd][0] *= alpha; oacc[fd][1] *= alpha;
            oacc[fd][2] *= alpha; oacc[fd][3] *= alpha;
        }

        // ---- pack P, O^T += V^T . P^T (k-slot permuted) ----
        unsigned int pc[4][2];
#pragma unroll
        for (int fk = 0; fk < 4; ++fk)
#pragma unroll
            for (int rp = 0; rp < 2; ++rp)
                pc[fk][rp] = (unsigned int)bf16_rn(p[fk][2 * rp]) |
                             ((unsigned int)bf16_rn(p[fk][2 * rp + 1]) << 16);
#pragma unroll
        for (int c = 0; c < 2; ++c) {
            u32x4 pw = {pc[2 * c][0], pc[2 * c][1], pc[2 * c + 1][0], pc[2 * c + 1][1]};
            bf16x8 pb = __builtin_bit_cast(bf16x8, pw);
#pragma unroll
            for (int fd = 0; fd < 4; ++fd) {
                const int vrow = fd * 16 + lr;
                const int Xv = (vrow & 7) << 3;
                const int vb = vrow * 64;
                bf16x4 v0 = *(const bf16x4*)&sVt[vb + ((c * 32 + kg * 4) ^ Xv)];
                bf16x4 v1 = *(const bf16x4*)&sVt[vb + ((c * 32 + 16 + kg * 4) ^ Xv)];
                bf16x8 va = __builtin_shufflevector(v0, v1, 0, 1, 2, 3, 4, 5, 6, 7);
                oacc[fd] = __builtin_amdgcn_mfma_f32_16x16x32_bf16(va, pb, oacc[fd], 0, 0, 0);
            }
        }
        asm volatile("" ::: "memory");
        __builtin_amdgcn_s_barrier();
    }

    // ---- epilogue: O^T -> att hi/lo bf16 ----
    const float inv = 1.f / l_i;
#pragma unroll
    for (int fd = 0; fd < 4; ++fd) {
        ushort4 h4, l4;
        unsigned short hs[4], ls[4];
#pragma unroll
        for (int r = 0; r < 4; ++r) {
            const float o = oacc[fd][r] * inv;
            hs[r] = bf16_rn(o);
            ls[r] = bf16_rn(o - __uint_as_float((unsigned int)hs[r] << 16));
        }
        h4.x = hs[0]; h4.y = hs[1]; h4.z = hs[2]; h4.w = hs[3];
        l4.x = ls[0]; l4.y = ls[1]; l4.z = ls[2]; l4.w = ls[3];
        const size_t idx = (size_t)qg * CDIM + h * 64 + fd * 16 + kg * 4;
        *(ushort4*)&ath[idx] = h4;
        *(ushort4*)&atl[idx] = l4;
    }
}

// ---------------------------------------------------------------------------
extern "C" void kernel_launch(void* const* d_in, const int* in_sizes, int n_in,
                              void* d_out, int out_size, void* d_ws, size_t ws_size,
                              hipStream_t stream) {
    const float* x          = (const float*)d_in[0];
    const float* Wqkv       = (const float*)d_in[1];
    const float* bqkv       = (const float*)d_in[2];
    const float* Wproj      = (const float*)d_in[3];
    const float* bproj      = (const float*)d_in[4];
    const float* frame_bias = (const float*)d_in[5];
    const int*   adj        = (const int*)d_in[6];
    const int*   is_hub     = (const int*)d_in[8];
    float* out = (float*)d_out;

    char* ws = (char*)d_ws;
    size_t off = 0;
    auto alloc_us = [&](size_t n) { unsigned short* p = (unsigned short*)(ws + off); off += n * 2; return p; };
    unsigned short* qhg = alloc_us((size_t)NHEAD * NTOK * HDIM);
    unsigned short* qlg = alloc_us((size_t)NHEAD * NTOK * HDIM);
    unsigned short* khg = alloc_us((size_t)NHEAD * NTOK * HDIM);
    unsigned short* klg = alloc_us((size_t)NHEAD * NTOK * HDIM);
    unsigned short* vtg = alloc_us((size_t)NHEAD * HDIM * NTOK);
    unsigned short* xh  = alloc_us((size_t)NTOK * CDIM);
    unsigned short* xl  = alloc_us((size_t)NTOK * CDIM);
    unsigned short* wqh = alloc_us((size_t)3 * CDIM * CDIM);
    unsigned short* wql = alloc_us((size_t)3 * CDIM * CDIM);
    unsigned short* wph = alloc_us((size_t)CDIM * CDIM);
    unsigned short* wpl = alloc_us((size_t)CDIM * CDIM);
    unsigned short* ath = alloc_us((size_t)NTOK * CDIM);
    unsigned short* atl = alloc_us((size_t)NTOK * CDIM);

    const int nb_x = (NTOK * CDIM / 4) / 256;
    const int nb_wq = (3 * CDIM * CDIM / 4) / 256;
    const int nb_wp = (CDIM * CDIM / 4) / 256;
    split3<<<nb_x + nb_wq + nb_wp, 256, 0, stream>>>(x, xh, xl, nb_x,
                                                     Wqkv, wqh, wql, nb_wq,
                                                     Wproj, wph, wpl);

    // 1) QKV projection; epilogue emits attention-ready bf16 q/k/v buffers
    gemm_mfma_split<128, 128, NTOK, 3 * CDIM, CDIM, 1>
        <<<dim3((3 * CDIM) / 128, NTOK / 128), 256, 0, stream>>>(
            xh, xl, wqh, wql, bqkv, nullptr, qhg, qlg, khg, klg, vtg);
    // 2) sparse attention
    attn_mfma<<<512, 256, 0, stream>>>(qhg, qlg, khg, klg, vtg,
                                       frame_bias, adj, is_hub, ath, atl);
    // 3) output projection
    gemm_mfma_split<64, 128, NTOK, CDIM, CDIM, 0>
        <<<dim3(CDIM / 128, NTOK / 64), 256, 0, stream>>>(
            ath, atl, wph, wpl, bproj, out, nullptr, nullptr, nullptr, nullptr, nullptr);
}

// Round 6
// 114.066 us; speedup vs baseline: 3.7169x; 1.0738x over previous
//
#include <hip/hip_runtime.h>
#include <hip/hip_bf16.h>
#include <math.h>

// Problem constants
#define NTOK 2048
#define CDIM 1024
#define NHEAD 16
#define HDIM 64
// frame id = token >> 8 (8 frames of 256 tokens)

typedef __attribute__((ext_vector_type(8))) short bf16x8;
typedef __attribute__((ext_vector_type(4))) short bf16x4;
typedef __attribute__((ext_vector_type(4))) float f32x4;
typedef __attribute__((ext_vector_type(4))) unsigned int u32x4;

// ---------------------------------------------------------------------------
// helpers
// ---------------------------------------------------------------------------
__device__ inline unsigned short bf16_rn(float f) {
    unsigned int u = __float_as_uint(f);
    u += 0x7FFFu + ((u >> 16) & 1u);
    return (unsigned short)(u >> 16);
}

__device__ inline void split4(float4 v, ushort4& h, ushort4& l) {
    float a[4] = {v.x, v.y, v.z, v.w};
    unsigned short hs[4], ls[4];
#pragma unroll
    for (int j = 0; j < 4; ++j) {
        hs[j] = bf16_rn(a[j]);
        float hf = __uint_as_float((unsigned int)hs[j] << 16);
        ls[j] = bf16_rn(a[j] - hf);
    }
    h.x = hs[0]; h.y = hs[1]; h.z = hs[2]; h.w = hs[3];
    l.x = ls[0]; l.y = ls[1]; l.z = ls[2]; l.w = ls[3];
}

template <int N> __device__ inline void waitcnt_vm() {
    if constexpr (N == 0) asm volatile("s_waitcnt vmcnt(0)" ::: "memory");
    else if constexpr (N == 3) asm volatile("s_waitcnt vmcnt(3)" ::: "memory");
    else if constexpr (N == 5) asm volatile("s_waitcnt vmcnt(5)" ::: "memory");
    else if constexpr (N == 6) asm volatile("s_waitcnt vmcnt(6)" ::: "memory");
    else if constexpr (N == 8) asm volatile("s_waitcnt vmcnt(8)" ::: "memory");
}

__device__ inline void gload16(const void* g, void* l) {
    __builtin_amdgcn_global_load_lds((const __attribute__((address_space(1))) void*)g,
                                     (__attribute__((address_space(3))) void*)l,
                                     16, 0, 0);
}

// One dispatch splitting the three f32 inputs into bf16 hi/lo.
__global__ __launch_bounds__(256) void split3(const float* __restrict__ s0, unsigned short* __restrict__ h0,
                                              unsigned short* __restrict__ l0, int nb0,
                                              const float* __restrict__ s1, unsigned short* __restrict__ h1,
                                              unsigned short* __restrict__ l1, int nb1,
                                              const float* __restrict__ s2, unsigned short* __restrict__ h2,
                                              unsigned short* __restrict__ l2) {
    int b = blockIdx.x;
    const float* s;
    unsigned short *hh, *ll;
    if (b < nb0) { s = s0; hh = h0; ll = l0; }
    else if (b < nb0 + nb1) { s = s1; hh = h1; ll = l1; b -= nb0; }
    else { s = s2; hh = h2; ll = l2; b -= nb0 + nb1; }
    const int i = b * 256 + threadIdx.x;
    float4 v = ((const float4*)s)[i];
    ushort4 h, l;
    split4(v, h, l);
    ((ushort4*)hh)[i] = h;
    ((ushort4*)ll)[i] = l;
}

// ---------------------------------------------------------------------------
// MFMA GEMM, counted-vmcnt double buffer.
// MODE 1 (QKV): A split hi/lo, B split hi/lo, 3 terms; epilogue writes
//   attention-ready bf16 buffers (q/k hi+lo swizzled, V^T swizzled).
// MODE 2 (PROJ): A single bf16, B split hi/lo, 2 terms; f32 out + bias.
// ---------------------------------------------------------------------------
template <int BM, int BN, int M, int N, int K, int MODE>
__global__ __launch_bounds__(256) void gemm_mfma(const unsigned short* __restrict__ Ah,
                                                 const unsigned short* __restrict__ Al,
                                                 const unsigned short* __restrict__ Bh,
                                                 const unsigned short* __restrict__ Bl,
                                                 const float* __restrict__ bias,
                                                 float* __restrict__ C,
                                                 unsigned short* __restrict__ qhg,
                                                 unsigned short* __restrict__ qlg,
                                                 unsigned short* __restrict__ khg,
                                                 unsigned short* __restrict__ klg,
                                                 unsigned short* __restrict__ vtg) {
    constexpr bool ASPLIT = (MODE == 1);
    constexpr int NA = ASPLIT ? 2 : 1;
    constexpr int FM = BM / 32;
    constexpr int FN = BN / 32;
    constexpr int ASZ = BM * 32;
    constexpr int BSZ = BN * 32;
    constexpr int BUF = NA * ASZ + 2 * BSZ;
    __shared__ unsigned short lds[2 * BUF];

    const int tid = threadIdx.x;
    const int lane = tid & 63;
    const int w = tid >> 6;
    const int m0 = blockIdx.y * BM;
    const int n0 = blockIdx.x * BN;
    const int wave_m = (w >> 1) * (BM / 2);
    const int wave_n = (w & 1) * (BN / 2);
    const int lr = lane & 15;
    const int kg = lane >> 4;
    const int srow = tid >> 2;
    const int scol = (tid & 3) * 8;

    // hoist the 64-bit row*K products out of the K-loop
    const size_t aRow = (size_t)(m0 + srow) * K + scol;
    const size_t bRow = (size_t)(n0 + srow) * K + scol;

    f32x4 acc[FM][FN];
#pragma unroll
    for (int i = 0; i < FM; ++i)
#pragma unroll
        for (int j = 0; j < FN; ++j) acc[i][j] = {0.f, 0.f, 0.f, 0.f};

    auto stage = [&](int buf, int k0) {
        unsigned short* bb = lds + buf * BUF;
#pragma unroll
        for (int j = 0; j < BM / 64; ++j) {
            const size_t ga = aRow + (size_t)j * 64 * K + k0;
            const int ldst = (srow + j * 64) * 32 + scol;
            gload16(Ah + ga, bb + ldst);
            if constexpr (ASPLIT) gload16(Al + ga, bb + ASZ + ldst);
        }
#pragma unroll
        for (int j = 0; j < BN / 64; ++j) {
            const size_t gb = bRow + (size_t)j * 64 * K + k0;
            const int ldst = (srow + j * 64) * 32 + scol;
            gload16(Bh + gb, bb + NA * ASZ + ldst);
            gload16(Bl + gb, bb + NA * ASZ + BSZ + ldst);
        }
    };

    stage(0, 0);
    constexpr int NL = NA * (BM / 64) + 2 * (BN / 64);
    constexpr int NT = K / 32;
    for (int t = 0; t < NT; ++t) {
        const int cur = t & 1;
        if (t + 1 < NT) {
            stage(cur ^ 1, (t + 1) * 32);
            waitcnt_vm<NL>();   // current tile's loads done; next stays in flight
        } else {
            waitcnt_vm<0>();
        }
        __builtin_amdgcn_s_barrier();

        const unsigned short* bb = lds + cur * BUF;
        bf16x8 ah[FM], al[FM], bh[FN], bl[FN];
#pragma unroll
        for (int f = 0; f < FM; ++f) {
            const int ra = (wave_m + f * 16 + lr) * 32 + kg * 8;
            ah[f] = *(const bf16x8*)&bb[ra];
            if constexpr (ASPLIT) al[f] = *(const bf16x8*)&bb[ASZ + ra];
        }
#pragma unroll
        for (int f = 0; f < FN; ++f) {
            const int rb = (wave_n + f * 16 + lr) * 32 + kg * 8;
            bh[f] = *(const bf16x8*)&bb[NA * ASZ + rb];
            bl[f] = *(const bf16x8*)&bb[NA * ASZ + BSZ + rb];
        }
#pragma unroll
        for (int fm = 0; fm < FM; ++fm)
#pragma unroll
            for (int fn = 0; fn < FN; ++fn) {
                acc[fm][fn] = __builtin_amdgcn_mfma_f32_16x16x32_bf16(ah[fm], bh[fn], acc[fm][fn], 0, 0, 0);
                acc[fm][fn] = __builtin_amdgcn_mfma_f32_16x16x32_bf16(ah[fm], bl[fn], acc[fm][fn], 0, 0, 0);
                if constexpr (ASPLIT)
                    acc[fm][fn] = __builtin_amdgcn_mfma_f32_16x16x32_bf16(al[fm], bh[fn], acc[fm][fn], 0, 0, 0);
            }
        asm volatile("" ::: "memory");
        __builtin_amdgcn_s_barrier();
    }

    // epilogue: C/D layout col=lane&15, row=(lane>>4)*4+reg  [m89-verified]
    if constexpr (MODE == 2) {
        float bv[FN];
#pragma unroll
        for (int fn = 0; fn < FN; ++fn) bv[fn] = bias[n0 + wave_n + fn * 16 + lr];
#pragma unroll
        for (int fm = 0; fm < FM; ++fm) {
            const int row0 = m0 + wave_m + fm * 16 + kg * 4;
#pragma unroll
            for (int fn = 0; fn < FN; ++fn) {
                const int col = n0 + wave_n + fn * 16 + lr;
#pragma unroll
                for (int r = 0; r < 4; ++r)
                    C[(size_t)(row0 + r) * N + col] = acc[fm][fn][r] + bv[fn];
            }
        }
    } else {
        const int reg = n0 >> 10;  // 0=q, 1=k, 2=v (uniform per block)
#pragma unroll
        for (int fn = 0; fn < FN; ++fn) {
            const int col = n0 + wave_n + fn * 16 + lr;
            const int head = (col >> 6) & 15;
            const int d = col & 63;
            const float bv = bias[col];
#pragma unroll
            for (int fm = 0; fm < FM; ++fm) {
                const int row0 = m0 + wave_m + fm * 16 + kg * 4;
                if (reg == 2) {
                    ushort4 pk;
                    pk.x = bf16_rn(acc[fm][fn][0] + bv);
                    pk.y = bf16_rn(acc[fm][fn][1] + bv);
                    pk.z = bf16_rn(acc[fm][fn][2] + bv);
                    pk.w = bf16_rn(acc[fm][fn][3] + bv);
                    const size_t idx = (size_t)(head * 64 + d) * 2048 + (size_t)(row0 ^ ((d & 7) << 3));
                    *(ushort4*)&vtg[idx] = pk;
                } else {
                    const float sc = (reg == 0) ? 0.125f : 1.0f;
                    unsigned short* hp = (reg == 0) ? qhg : khg;
                    unsigned short* lp = (reg == 0) ? qlg : klg;
#pragma unroll
                    for (int r = 0; r < 4; ++r) {
                        const int tok = row0 + r;
                        const float val = (acc[fm][fn][r] + bv) * sc;
                        const unsigned short hb = bf16_rn(val);
                        const unsigned short lb = bf16_rn(val - __uint_as_float((unsigned int)hb << 16));
                        const size_t idx = ((size_t)head * 2048 + tok) * 64 + (d ^ ((tok & 7) << 3));
                        hp[idx] = hb;
                        lp[idx] = lb;
                    }
                }
            }
        }
    }
}

// ---------------------------------------------------------------------------
// MFMA sparse flash attention. QBLK=128 (8 waves x 16 q rows), 256 blocks,
// XCD-decoded (2 heads per XCD). K/V staged once per 128 queries,
// counted-vmcnt(3) double buffer. Output: plain bf16 att.
// ---------------------------------------------------------------------------
__global__ __launch_bounds__(512) void attn_mfma(const unsigned short* __restrict__ qhg,
                                                 const unsigned short* __restrict__ qlg,
                                                 const unsigned short* __restrict__ khg,
                                                 const unsigned short* __restrict__ klg,
                                                 const unsigned short* __restrict__ vtg,
                                                 const float* __restrict__ frame_bias,
                                                 const int* __restrict__ adj,
                                                 const int* __restrict__ is_hub,
                                                 unsigned short* __restrict__ ath) {
    __shared__ unsigned short sBuf[2][3][64 * 64];  // [buf][{kh,kl,vt}]
    __shared__ int sList[32];
    __shared__ float sFB[8];
    __shared__ unsigned long long sHub[32];
    __shared__ int sNT;

    // XCD decode: bid%8 = XCD, each XCD owns heads {2r, 2r+1}
    const int bid = blockIdx.x;
    const int r8 = bid & 7, tt = bid >> 3;
    const int qb = tt & 15, hb = tt >> 4;
    const int h = r8 * 2 + hb;
    const int q0 = qb * 128;

    const int tid = threadIdx.x;
    const int lane = tid & 63;
    const int wq = tid >> 6;       // 0..7
    const int lr = lane & 15;
    const int kg = lane >> 4;
    const int fi = q0 >> 8;        // 128-q block never straddles a frame

    // ---- Q fragments straight from global (pre-swizzled layout) ----
    const int qrow = wq * 16 + lr;          // block-local q row (0..127)
    const int qg = q0 + qrow;               // global token
    const unsigned short* qbh = qhg + ((size_t)h * 2048 + qg) * 64;
    const unsigned short* qbl = qlg + ((size_t)h * 2048 + qg) * 64;
    const int Xq = (qg & 7) << 3;
    bf16x8 qh[2], ql[2];
#pragma unroll
    for (int dc = 0; dc < 2; ++dc) {
        const int off = (dc * 32 + kg * 8) ^ Xq;
        qh[dc] = *(const bf16x8*)&qbh[off];
        ql[dc] = *(const bf16x8*)&qbl[off];
    }
    const bool hq = is_hub[qg] != 0;

    // ---- prologue tables (hub masks parallel across waves) ----
#pragma unroll
    for (int i = 0; i < 4; ++i) {
        const int t2 = wq * 4 + i;
        unsigned long long mb = __ballot(is_hub[t2 * 64 + lane] != 0);
        if (lane == 0) sHub[t2] = mb;
    }
    if (tid < 8) sFB[tid] = frame_bias[fi * 8 + tid];
    if (tid == 0) {
        int c = 0;
#pragma unroll 1
        for (int t2 = 0; t2 < 32; ++t2)
            if (adj[fi * 8 + (t2 >> 2)]) sList[c++] = t2;
        sNT = c;
    }
    __syncthreads();
    const int nt = sNT;

    // staging: 512 threads x 16B = one 64x64 u16 tile per array
    const int crow = tid >> 3;          // 0..63
    const int ccol = (tid & 7) * 8;
    const unsigned short* kbase = khg + (size_t)h * 2048 * 64;
    const unsigned short* lbase = klg + (size_t)h * 2048 * 64;
    const unsigned short* vbase = vtg + (size_t)h * 64 * 2048;

    auto stage = [&](int buf, int n0s) {
        const int dst = tid * 8;
        gload16(kbase + (size_t)(n0s + crow) * 64 + ccol, &sBuf[buf][0][dst]);
        gload16(lbase + (size_t)(n0s + crow) * 64 + ccol, &sBuf[buf][1][dst]);
        gload16(vbase + (size_t)crow * 2048 + n0s + ccol, &sBuf[buf][2][dst]);
    };

    float m_i = -INFINITY, l_i = 0.f;
    f32x4 oacc[4];
#pragma unroll
    for (int fd = 0; fd < 4; ++fd) oacc[fd] = {0.f, 0.f, 0.f, 0.f};

    stage(0, sList[0] * 64);
#pragma unroll 1
    for (int i = 0; i < nt; ++i) {
        const int cur = i & 1;
        const int tile = sList[i];
        if (i + 1 < nt) {
            stage(cur ^ 1, sList[i + 1] * 64);
            waitcnt_vm<3>();
        } else {
            waitcnt_vm<0>();
        }
        __builtin_amdgcn_s_barrier();

        const int fj = tile >> 2;
        const bool same = (fj == fi);
        const float biasv = sFB[fj];
        const unsigned long long hubmask = sHub[tile];
        const unsigned short* sKh = &sBuf[cur][0][0];
        const unsigned short* sKl = &sBuf[cur][1][0];
        const unsigned short* sVt = &sBuf[cur][2][0];

        // ---- S^T = K . Q^T (hi/lo) ----
        f32x4 sacc[4];
#pragma unroll
        for (int fk = 0; fk < 4; ++fk) sacc[fk] = {0.f, 0.f, 0.f, 0.f};
#pragma unroll
        for (int fk = 0; fk < 4; ++fk) {
            const int r = fk * 16 + lr;
            const int Xk = (r & 7) << 3;
            const int rb = r * 64;
#pragma unroll
            for (int dc = 0; dc < 2; ++dc) {
                const int off = rb + ((dc * 32 + kg * 8) ^ Xk);
                bf16x8 khf = *(const bf16x8*)&sKh[off];
                bf16x8 klf = *(const bf16x8*)&sKl[off];
                sacc[fk] = __builtin_amdgcn_mfma_f32_16x16x32_bf16(khf, qh[dc], sacc[fk], 0, 0, 0);
                sacc[fk] = __builtin_amdgcn_mfma_f32_16x16x32_bf16(klf, qh[dc], sacc[fk], 0, 0, 0);
                sacc[fk] = __builtin_amdgcn_mfma_f32_16x16x32_bf16(khf, ql[dc], sacc[fk], 0, 0, 0);
            }
        }

        // ---- mask + bias + online softmax (lane owns 16 scores of its q) ----
        float sv[4][4];
        float rmax = -INFINITY;
#pragma unroll
        for (int fk = 0; fk < 4; ++fk)
#pragma unroll
            for (int r = 0; r < 4; ++r) {
                float val = sacc[fk][r] + biasv;
                if (!same) {
                    const int k = fk * 16 + kg * 4 + r;
                    const bool hk = (hubmask >> k) & 1ull;
                    if (hq || hk) val = -INFINITY;
                }
                sv[fk][r] = val;
                rmax = fmaxf(rmax, val);
            }
        rmax = fmaxf(rmax, __shfl_xor(rmax, 16));
        rmax = fmaxf(rmax, __shfl_xor(rmax, 32));

        const float mn = fmaxf(m_i, rmax);
        const float alpha = (mn == -INFINITY) ? 1.f : __expf(m_i - mn);
        m_i = mn;

        float p[4][4];
        float psum = 0.f;
#pragma unroll
        for (int fk = 0; fk < 4; ++fk)
#pragma unroll
            for (int r = 0; r < 4; ++r) {
                const float pv = (sv[fk][r] == -INFINITY) ? 0.f : __expf(sv[fk][r] - mn);
                p[fk][r] = pv;
                psum += pv;
            }
        psum += __shfl_xor(psum, 16);
        psum += __shfl_xor(psum, 32);
        l_i = l_i * alpha + psum;
#pragma unroll
        for (int fd = 0; fd < 4; ++fd) {
            oacc[fd][0] *= alpha; oacc[fd][1] *= alpha;
            oacc[fd][2] *= alpha; oacc[fd][3] *= alpha;
        }

        // ---- pack P, O^T += V^T . P^T (k-slot permuted) ----
        unsigned int pc[4][2];
#pragma unroll
        for (int fk = 0; fk < 4; ++fk)
#pragma unroll
            for (int rp = 0; rp < 2; ++rp)
                pc[fk][rp] = (unsigned int)bf16_rn(p[fk][2 * rp]) |
                             ((unsigned int)bf16_rn(p[fk][2 * rp + 1]) << 16);
#pragma unroll
        for (int c = 0; c < 2; ++c) {
            u32x4 pw = {pc[2 * c][0], pc[2 * c][1], pc[2 * c + 1][0], pc[2 * c + 1][1]};
            bf16x8 pb = __builtin_bit_cast(bf16x8, pw);
#pragma unroll
            for (int fd = 0; fd < 4; ++fd) {
                const int vrow = fd * 16 + lr;
                const int Xv = (vrow & 7) << 3;
                const int vb = vrow * 64;
                bf16x4 v0 = *(const bf16x4*)&sVt[vb + ((c * 32 + kg * 4) ^ Xv)];
                bf16x4 v1 = *(const bf16x4*)&sVt[vb + ((c * 32 + 16 + kg * 4) ^ Xv)];
                bf16x8 va = __builtin_shufflevector(v0, v1, 0, 1, 2, 3, 4, 5, 6, 7);
                oacc[fd] = __builtin_amdgcn_mfma_f32_16x16x32_bf16(va, pb, oacc[fd], 0, 0, 0);
            }
        }
        asm volatile("" ::: "memory");
        __builtin_amdgcn_s_barrier();
    }

    // ---- epilogue: O^T -> att bf16 (plain; proj uses 2-term split) ----
    const float inv = 1.f / l_i;
#pragma unroll
    for (int fd = 0; fd < 4; ++fd) {
        ushort4 h4;
        h4.x = bf16_rn(oacc[fd][0] * inv);
        h4.y = bf16_rn(oacc[fd][1] * inv);
        h4.z = bf16_rn(oacc[fd][2] * inv);
        h4.w = bf16_rn(oacc[fd][3] * inv);
        const size_t idx = (size_t)qg * CDIM + h * 64 + fd * 16 + kg * 4;
        *(ushort4*)&ath[idx] = h4;
    }
}

// ---------------------------------------------------------------------------
extern "C" void kernel_launch(void* const* d_in, const int* in_sizes, int n_in,
                              void* d_out, int out_size, void* d_ws, size_t ws_size,
                              hipStream_t stream) {
    const float* x          = (const float*)d_in[0];
    const float* Wqkv       = (const float*)d_in[1];
    const float* bqkv       = (const float*)d_in[2];
    const float* Wproj      = (const float*)d_in[3];
    const float* bproj      = (const float*)d_in[4];
    const float* frame_bias = (const float*)d_in[5];
    const int*   adj        = (const int*)d_in[6];
    const int*   is_hub     = (const int*)d_in[8];
    float* out = (float*)d_out;

    char* ws = (char*)d_ws;
    size_t off = 0;
    auto alloc_us = [&](size_t n) { unsigned short* p = (unsigned short*)(ws + off); off += n * 2; return p; };
    unsigned short* qhg = alloc_us((size_t)NHEAD * NTOK * HDIM);
    unsigned short* qlg = alloc_us((size_t)NHEAD * NTOK * HDIM);
    unsigned short* khg = alloc_us((size_t)NHEAD * NTOK * HDIM);
    unsigned short* klg = alloc_us((size_t)NHEAD * NTOK * HDIM);
    unsigned short* vtg = alloc_us((size_t)NHEAD * HDIM * NTOK);
    unsigned short* xh  = alloc_us((size_t)NTOK * CDIM);
    unsigned short* xl  = alloc_us((size_t)NTOK * CDIM);
    unsigned short* wqh = alloc_us((size_t)3 * CDIM * CDIM);
    unsigned short* wql = alloc_us((size_t)3 * CDIM * CDIM);
    unsigned short* wph = alloc_us((size_t)CDIM * CDIM);
    unsigned short* wpl = alloc_us((size_t)CDIM * CDIM);
    unsigned short* ath = alloc_us((size_t)NTOK * CDIM);

    const int nb_x = (NTOK * CDIM / 4) / 256;
    const int nb_wq = (3 * CDIM * CDIM / 4) / 256;
    const int nb_wp = (CDIM * CDIM / 4) / 256;
    split3<<<nb_x + nb_wq + nb_wp, 256, 0, stream>>>(x, xh, xl, nb_x,
                                                     Wqkv, wqh, wql, nb_wq,
                                                     Wproj, wph, wpl);

    // 1) QKV projection; epilogue emits attention-ready bf16 q/k/v buffers
    gemm_mfma<128, 128, NTOK, 3 * CDIM, CDIM, 1>
        <<<dim3((3 * CDIM) / 128, NTOK / 128), 256, 0, stream>>>(
            xh, xl, wqh, wql, bqkv, nullptr, qhg, qlg, khg, klg, vtg);
    // 2) sparse attention (QBLK=128, 8 waves), writes plain bf16 att
    attn_mfma<<<256, 512, 0, stream>>>(qhg, qlg, khg, klg, vtg,
                                       frame_bias, adj, is_hub, ath);
    // 3) output projection (2-term: ath x (wph+wpl))
    gemm_mfma<64, 128, NTOK, CDIM, CDIM, 2>
        <<<dim3(CDIM / 128, NTOK / 64), 256, 0, stream>>>(
            ath, nullptr, wph, wpl, bproj, out, nullptr, nullptr, nullptr, nullptr, nullptr);
}

// Round 7
// 100.851 us; speedup vs baseline: 4.2040x; 1.1310x over previous
//
#include <hip/hip_runtime.h>
#include <hip/hip_bf16.h>
#include <math.h>

// Problem constants
#define NTOK 2048
#define CDIM 1024
#define NHEAD 16
#define HDIM 64
// frame id = token >> 8 (8 frames of 256 tokens)

typedef __attribute__((ext_vector_type(8))) short bf16x8;
typedef __attribute__((ext_vector_type(4))) short bf16x4;
typedef __attribute__((ext_vector_type(4))) float f32x4;
typedef __attribute__((ext_vector_type(4))) unsigned int u32x4;

// ---------------------------------------------------------------------------
// helpers
// ---------------------------------------------------------------------------
__device__ inline unsigned short bf16_rn(float f) {
    unsigned int u = __float_as_uint(f);
    u += 0x7FFFu + ((u >> 16) & 1u);
    return (unsigned short)(u >> 16);
}

__device__ inline void split4(float4 v, ushort4& h, ushort4& l) {
    float a[4] = {v.x, v.y, v.z, v.w};
    unsigned short hs[4], ls[4];
#pragma unroll
    for (int j = 0; j < 4; ++j) {
        hs[j] = bf16_rn(a[j]);
        float hf = __uint_as_float((unsigned int)hs[j] << 16);
        ls[j] = bf16_rn(a[j] - hf);
    }
    h.x = hs[0]; h.y = hs[1]; h.z = hs[2]; h.w = hs[3];
    l.x = ls[0]; l.y = ls[1]; l.z = ls[2]; l.w = ls[3];
}

template <int N> __device__ inline void waitcnt_vm() {
    if constexpr (N == 0) asm volatile("s_waitcnt vmcnt(0)" ::: "memory");
    else if constexpr (N == 3) asm volatile("s_waitcnt vmcnt(3)" ::: "memory");
    else if constexpr (N == 4) asm volatile("s_waitcnt vmcnt(4)" ::: "memory");
    else if constexpr (N == 6) asm volatile("s_waitcnt vmcnt(6)" ::: "memory");
}

__device__ inline void gload16(const void* g, void* l) {
    __builtin_amdgcn_global_load_lds((const __attribute__((address_space(1))) void*)g,
                                     (__attribute__((address_space(3))) void*)l,
                                     16, 0, 0);
}

// One dispatch: x -> hi/lo split; Wqkv, Wproj -> plain bf16 (hi only).
__global__ __launch_bounds__(256) void split3(const float* __restrict__ s0, unsigned short* __restrict__ h0,
                                              unsigned short* __restrict__ l0, int nb0,
                                              const float* __restrict__ s1, unsigned short* __restrict__ h1,
                                              int nb1,
                                              const float* __restrict__ s2, unsigned short* __restrict__ h2) {
    int b = blockIdx.x;
    const float* s;
    unsigned short *hh, *ll = nullptr;
    if (b < nb0) { s = s0; hh = h0; ll = l0; }
    else if (b < nb0 + nb1) { s = s1; hh = h1; b -= nb0; }
    else { s = s2; hh = h2; b -= nb0 + nb1; }
    const int i = b * 256 + threadIdx.x;
    float4 v = ((const float4*)s)[i];
    ushort4 h, l;
    split4(v, h, l);
    ((ushort4*)hh)[i] = h;
    if (ll) ((ushort4*)ll)[i] = l;
}

// ---------------------------------------------------------------------------
// MFMA GEMM, counted-vmcnt double buffer. BM=64, BN=128, 4 waves (32x64 each).
// MODE 1 (QKV): (Ah+Al) @ Bh^T, 2 terms; epilogue writes attention-ready
//   bf16 buffers (q/k hi+lo swizzled, V^T swizzled).
// MODE 2 (PROJ): Ah @ Bh^T, 1 term; f32 out + bias.
// ---------------------------------------------------------------------------
template <int BM, int BN, int M, int N, int K, int MODE>
__global__ __launch_bounds__(256) void gemm_mfma(const unsigned short* __restrict__ Ah,
                                                 const unsigned short* __restrict__ Al,
                                                 const unsigned short* __restrict__ Bh,
                                                 const float* __restrict__ bias,
                                                 float* __restrict__ C,
                                                 unsigned short* __restrict__ qhg,
                                                 unsigned short* __restrict__ qlg,
                                                 unsigned short* __restrict__ khg,
                                                 unsigned short* __restrict__ klg,
                                                 unsigned short* __restrict__ vtg) {
    constexpr bool ASPLIT = (MODE == 1);
    constexpr int NA = ASPLIT ? 2 : 1;
    constexpr int FM = BM / 32;
    constexpr int FN = BN / 32;
    constexpr int ASZ = BM * 32;
    constexpr int BSZ = BN * 32;
    constexpr int BUF = NA * ASZ + BSZ;
    __shared__ unsigned short lds[2 * BUF];

    const int tid = threadIdx.x;
    const int lane = tid & 63;
    const int w = tid >> 6;
    const int m0 = blockIdx.y * BM;
    const int n0 = blockIdx.x * BN;
    const int wave_m = (w >> 1) * (BM / 2);
    const int wave_n = (w & 1) * (BN / 2);
    const int lr = lane & 15;
    const int kg = lane >> 4;
    const int srow = tid >> 2;
    const int scol = (tid & 3) * 8;

    const size_t aRow = (size_t)(m0 + srow) * K + scol;
    const size_t bRow = (size_t)(n0 + srow) * K + scol;

    f32x4 acc[FM][FN];
#pragma unroll
    for (int i = 0; i < FM; ++i)
#pragma unroll
        for (int j = 0; j < FN; ++j) acc[i][j] = {0.f, 0.f, 0.f, 0.f};

    auto stage = [&](int buf, int k0) {
        unsigned short* bb = lds + buf * BUF;
#pragma unroll
        for (int j = 0; j < BM / 64; ++j) {
            const size_t ga = aRow + (size_t)j * 64 * K + k0;
            const int ldst = (srow + j * 64) * 32 + scol;
            gload16(Ah + ga, bb + ldst);
            if constexpr (ASPLIT) gload16(Al + ga, bb + ASZ + ldst);
        }
#pragma unroll
        for (int j = 0; j < BN / 64; ++j) {
            const size_t gb = bRow + (size_t)j * 64 * K + k0;
            const int ldst = (srow + j * 64) * 32 + scol;
            gload16(Bh + gb, bb + NA * ASZ + ldst);
        }
    };

    stage(0, 0);
    constexpr int NL = NA * (BM / 64) + (BN / 64);
    constexpr int NT = K / 32;
    for (int t = 0; t < NT; ++t) {
        const int cur = t & 1;
        if (t + 1 < NT) {
            stage(cur ^ 1, (t + 1) * 32);
            waitcnt_vm<NL>();   // current tile's loads done; next stays in flight
        } else {
            waitcnt_vm<0>();
        }
        __builtin_amdgcn_s_barrier();

        const unsigned short* bb = lds + cur * BUF;
        bf16x8 ah[FM], al[FM], bh[FN];
#pragma unroll
        for (int f = 0; f < FM; ++f) {
            const int ra = (wave_m + f * 16 + lr) * 32 + kg * 8;
            ah[f] = *(const bf16x8*)&bb[ra];
            if constexpr (ASPLIT) al[f] = *(const bf16x8*)&bb[ASZ + ra];
        }
#pragma unroll
        for (int f = 0; f < FN; ++f) {
            const int rb = (wave_n + f * 16 + lr) * 32 + kg * 8;
            bh[f] = *(const bf16x8*)&bb[NA * ASZ + rb];
        }
#pragma unroll
        for (int fm = 0; fm < FM; ++fm)
#pragma unroll
            for (int fn = 0; fn < FN; ++fn) {
                acc[fm][fn] = __builtin_amdgcn_mfma_f32_16x16x32_bf16(ah[fm], bh[fn], acc[fm][fn], 0, 0, 0);
                if constexpr (ASPLIT)
                    acc[fm][fn] = __builtin_amdgcn_mfma_f32_16x16x32_bf16(al[fm], bh[fn], acc[fm][fn], 0, 0, 0);
            }
        asm volatile("" ::: "memory");
        __builtin_amdgcn_s_barrier();
    }

    // epilogue: C/D layout col=lane&15, row=(lane>>4)*4+reg  [m89-verified]
    if constexpr (MODE == 2) {
        float bv[FN];
#pragma unroll
        for (int fn = 0; fn < FN; ++fn) bv[fn] = bias[n0 + wave_n + fn * 16 + lr];
#pragma unroll
        for (int fm = 0; fm < FM; ++fm) {
            const int row0 = m0 + wave_m + fm * 16 + kg * 4;
#pragma unroll
            for (int fn = 0; fn < FN; ++fn) {
                const int col = n0 + wave_n + fn * 16 + lr;
#pragma unroll
                for (int r = 0; r < 4; ++r)
                    C[(size_t)(row0 + r) * N + col] = acc[fm][fn][r] + bv[fn];
            }
        }
    } else {
        const int reg = n0 >> 10;  // 0=q, 1=k, 2=v (uniform per block)
#pragma unroll
        for (int fn = 0; fn < FN; ++fn) {
            const int col = n0 + wave_n + fn * 16 + lr;
            const int head = (col >> 6) & 15;
            const int d = col & 63;
            const float bv = bias[col];
#pragma unroll
            for (int fm = 0; fm < FM; ++fm) {
                const int row0 = m0 + wave_m + fm * 16 + kg * 4;
                if (reg == 2) {
                    ushort4 pk;
                    pk.x = bf16_rn(acc[fm][fn][0] + bv);
                    pk.y = bf16_rn(acc[fm][fn][1] + bv);
                    pk.z = bf16_rn(acc[fm][fn][2] + bv);
                    pk.w = bf16_rn(acc[fm][fn][3] + bv);
                    const size_t idx = (size_t)(head * 64 + d) * 2048 + (size_t)(row0 ^ ((d & 7) << 3));
                    *(ushort4*)&vtg[idx] = pk;
                } else {
                    const float sc = (reg == 0) ? 0.125f : 1.0f;
                    unsigned short* hp = (reg == 0) ? qhg : khg;
                    unsigned short* lp = (reg == 0) ? qlg : klg;
#pragma unroll
                    for (int r = 0; r < 4; ++r) {
                        const int tok = row0 + r;
                        const float val = (acc[fm][fn][r] + bv) * sc;
                        const unsigned short hb = bf16_rn(val);
                        const unsigned short lb = bf16_rn(val - __uint_as_float((unsigned int)hb << 16));
                        const size_t idx = ((size_t)head * 2048 + tok) * 64 + (d ^ ((tok & 7) << 3));
                        hp[idx] = hb;
                        lp[idx] = lb;
                    }
                }
            }
        }
    }
}

// ---------------------------------------------------------------------------
// MFMA sparse flash attention. QBLK=128 (8 waves x 16 q rows), 256 blocks,
// XCD-decoded (2 heads per XCD). K/V staged once per 128 queries,
// counted-vmcnt(3) double buffer. Output: plain bf16 att.
// ---------------------------------------------------------------------------
__global__ __launch_bounds__(512) void attn_mfma(const unsigned short* __restrict__ qhg,
                                                 const unsigned short* __restrict__ qlg,
                                                 const unsigned short* __restrict__ khg,
                                                 const unsigned short* __restrict__ klg,
                                                 const unsigned short* __restrict__ vtg,
                                                 const float* __restrict__ frame_bias,
                                                 const int* __restrict__ adj,
                                                 const int* __restrict__ is_hub,
                                                 unsigned short* __restrict__ ath) {
    __shared__ unsigned short sBuf[2][3][64 * 64];  // [buf][{kh,kl,vt}]
    __shared__ int sList[32];
    __shared__ float sFB[8];
    __shared__ unsigned long long sHub[32];
    __shared__ int sNT;

    // XCD decode: bid%8 = XCD, each XCD owns heads {2r, 2r+1}
    const int bid = blockIdx.x;
    const int r8 = bid & 7, tt = bid >> 3;
    const int qb = tt & 15, hb = tt >> 4;
    const int h = r8 * 2 + hb;
    const int q0 = qb * 128;

    const int tid = threadIdx.x;
    const int lane = tid & 63;
    const int wq = tid >> 6;       // 0..7
    const int lr = lane & 15;
    const int kg = lane >> 4;
    const int fi = q0 >> 8;        // 128-q block never straddles a frame

    // ---- Q fragments straight from global (pre-swizzled layout) ----
    const int qrow = wq * 16 + lr;          // block-local q row (0..127)
    const int qg = q0 + qrow;               // global token
    const unsigned short* qbh = qhg + ((size_t)h * 2048 + qg) * 64;
    const unsigned short* qbl = qlg + ((size_t)h * 2048 + qg) * 64;
    const int Xq = (qg & 7) << 3;
    bf16x8 qh[2], ql[2];
#pragma unroll
    for (int dc = 0; dc < 2; ++dc) {
        const int off = (dc * 32 + kg * 8) ^ Xq;
        qh[dc] = *(const bf16x8*)&qbh[off];
        ql[dc] = *(const bf16x8*)&qbl[off];
    }
    const bool hq = is_hub[qg] != 0;

    // ---- prologue tables ----
#pragma unroll
    for (int i = 0; i < 4; ++i) {
        const int t2 = wq * 4 + i;
        unsigned long long mb = __ballot(is_hub[t2 * 64 + lane] != 0);
        if (lane == 0) sHub[t2] = mb;
    }
    if (tid < 8) sFB[tid] = frame_bias[fi * 8 + tid];
    if (wq == 0) {
        // parallel adj read (32 lanes), list built from SGPR mask (no mem latency)
        const bool ok = (lane < 32) && (adj[fi * 8 + ((lane & 31) >> 2)] != 0);
        const unsigned long long am = __ballot(ok);
        if (lane == 0) {
            int c = 0;
#pragma unroll 1
            for (int t2 = 0; t2 < 32; ++t2)
                if ((am >> t2) & 1ull) sList[c++] = t2;
            sNT = c;
        }
    }
    __syncthreads();
    const int nt = sNT;

    // staging: 512 threads x 16B = one 64x64 u16 tile per array
    const int crow = tid >> 3;          // 0..63
    const int ccol = (tid & 7) * 8;
    const unsigned short* kbase = khg + (size_t)h * 2048 * 64;
    const unsigned short* lbase = klg + (size_t)h * 2048 * 64;
    const unsigned short* vbase = vtg + (size_t)h * 64 * 2048;

    auto stage = [&](int buf, int n0s) {
        const int dst = tid * 8;
        gload16(kbase + (size_t)(n0s + crow) * 64 + ccol, &sBuf[buf][0][dst]);
        gload16(lbase + (size_t)(n0s + crow) * 64 + ccol, &sBuf[buf][1][dst]);
        gload16(vbase + (size_t)crow * 2048 + n0s + ccol, &sBuf[buf][2][dst]);
    };

    float m_i = -INFINITY, l_i = 0.f;
    f32x4 oacc[4];
#pragma unroll
    for (int fd = 0; fd < 4; ++fd) oacc[fd] = {0.f, 0.f, 0.f, 0.f};

    stage(0, sList[0] * 64);
#pragma unroll 1
    for (int i = 0; i < nt; ++i) {
        const int cur = i & 1;
        const int tile = sList[i];
        if (i + 1 < nt) {
            stage(cur ^ 1, sList[i + 1] * 64);
            waitcnt_vm<3>();
        } else {
            waitcnt_vm<0>();
        }
        __builtin_amdgcn_s_barrier();

        const int fj = tile >> 2;
        const bool same = (fj == fi);
        const float biasv = sFB[fj];
        const unsigned long long hubmask = sHub[tile];
        const unsigned short* sKh = &sBuf[cur][0][0];
        const unsigned short* sKl = &sBuf[cur][1][0];
        const unsigned short* sVt = &sBuf[cur][2][0];

        // ---- S^T = K . Q^T (hi/lo) ----
        f32x4 sacc[4];
#pragma unroll
        for (int fk = 0; fk < 4; ++fk) sacc[fk] = {0.f, 0.f, 0.f, 0.f};
#pragma unroll
        for (int fk = 0; fk < 4; ++fk) {
            const int r = fk * 16 + lr;
            const int Xk = (r & 7) << 3;
            const int rb = r * 64;
#pragma unroll
            for (int dc = 0; dc < 2; ++dc) {
                const int off = rb + ((dc * 32 + kg * 8) ^ Xk);
                bf16x8 khf = *(const bf16x8*)&sKh[off];
                bf16x8 klf = *(const bf16x8*)&sKl[off];
                sacc[fk] = __builtin_amdgcn_mfma_f32_16x16x32_bf16(khf, qh[dc], sacc[fk], 0, 0, 0);
                sacc[fk] = __builtin_amdgcn_mfma_f32_16x16x32_bf16(klf, qh[dc], sacc[fk], 0, 0, 0);
                sacc[fk] = __builtin_amdgcn_mfma_f32_16x16x32_bf16(khf, ql[dc], sacc[fk], 0, 0, 0);
            }
        }

        // ---- mask + bias + online softmax (lane owns 16 scores of its q) ----
        float sv[4][4];
        float rmax = -INFINITY;
#pragma unroll
        for (int fk = 0; fk < 4; ++fk)
#pragma unroll
            for (int r = 0; r < 4; ++r) {
                float val = sacc[fk][r] + biasv;
                if (!same) {
                    const int k = fk * 16 + kg * 4 + r;
                    const bool hk = (hubmask >> k) & 1ull;
                    if (hq || hk) val = -INFINITY;
                }
                sv[fk][r] = val;
                rmax = fmaxf(rmax, val);
            }
        rmax = fmaxf(rmax, __shfl_xor(rmax, 16));
        rmax = fmaxf(rmax, __shfl_xor(rmax, 32));

        const float mn = fmaxf(m_i, rmax);
        const float alpha = (mn == -INFINITY) ? 1.f : __expf(m_i - mn);
        m_i = mn;

        float p[4][4];
        float psum = 0.f;
#pragma unroll
        for (int fk = 0; fk < 4; ++fk)
#pragma unroll
            for (int r = 0; r < 4; ++r) {
                const float pv = (sv[fk][r] == -INFINITY) ? 0.f : __expf(sv[fk][r] - mn);
                p[fk][r] = pv;
                psum += pv;
            }
        psum += __shfl_xor(psum, 16);
        psum += __shfl_xor(psum, 32);
        l_i = l_i * alpha + psum;
#pragma unroll
        for (int fd = 0; fd < 4; ++fd) {
            oacc[fd][0] *= alpha; oacc[fd][1] *= alpha;
            oacc[fd][2] *= alpha; oacc[fd][3] *= alpha;
        }

        // ---- pack P, O^T += V^T . P^T (k-slot permuted) ----
        unsigned int pc[4][2];
#pragma unroll
        for (int fk = 0; fk < 4; ++fk)
#pragma unroll
            for (int rp = 0; rp < 2; ++rp)
                pc[fk][rp] = (unsigned int)bf16_rn(p[fk][2 * rp]) |
                             ((unsigned int)bf16_rn(p[fk][2 * rp + 1]) << 16);
#pragma unroll
        for (int c = 0; c < 2; ++c) {
            u32x4 pw = {pc[2 * c][0], pc[2 * c][1], pc[2 * c + 1][0], pc[2 * c + 1][1]};
            bf16x8 pb = __builtin_bit_cast(bf16x8, pw);
#pragma unroll
            for (int fd = 0; fd < 4; ++fd) {
                const int vrow = fd * 16 + lr;
                const int Xv = (vrow & 7) << 3;
                const int vb = vrow * 64;
                bf16x4 v0 = *(const bf16x4*)&sVt[vb + ((c * 32 + kg * 4) ^ Xv)];
                bf16x4 v1 = *(const bf16x4*)&sVt[vb + ((c * 32 + 16 + kg * 4) ^ Xv)];
                bf16x8 va = __builtin_shufflevector(v0, v1, 0, 1, 2, 3, 4, 5, 6, 7);
                oacc[fd] = __builtin_amdgcn_mfma_f32_16x16x32_bf16(va, pb, oacc[fd], 0, 0, 0);
            }
        }
        asm volatile("" ::: "memory");
        __builtin_amdgcn_s_barrier();
    }

    // ---- epilogue: O^T -> att bf16 ----
    const float inv = 1.f / l_i;
#pragma unroll
    for (int fd = 0; fd < 4; ++fd) {
        ushort4 h4;
        h4.x = bf16_rn(oacc[fd][0] * inv);
        h4.y = bf16_rn(oacc[fd][1] * inv);
        h4.z = bf16_rn(oacc[fd][2] * inv);
        h4.w = bf16_rn(oacc[fd][3] * inv);
        const size_t idx = (size_t)qg * CDIM + h * 64 + fd * 16 + kg * 4;
        *(ushort4*)&ath[idx] = h4;
    }
}

// ---------------------------------------------------------------------------
extern "C" void kernel_launch(void* const* d_in, const int* in_sizes, int n_in,
                              void* d_out, int out_size, void* d_ws, size_t ws_size,
                              hipStream_t stream) {
    const float* x          = (const float*)d_in[0];
    const float* Wqkv       = (const float*)d_in[1];
    const float* bqkv       = (const float*)d_in[2];
    const float* Wproj      = (const float*)d_in[3];
    const float* bproj      = (const float*)d_in[4];
    const float* frame_bias = (const float*)d_in[5];
    const int*   adj        = (const int*)d_in[6];
    const int*   is_hub     = (const int*)d_in[8];
    float* out = (float*)d_out;

    char* ws = (char*)d_ws;
    size_t off = 0;
    auto alloc_us = [&](size_t n) { unsigned short* p = (unsigned short*)(ws + off); off += n * 2; return p; };
    unsigned short* qhg = alloc_us((size_t)NHEAD * NTOK * HDIM);
    unsigned short* qlg = alloc_us((size_t)NHEAD * NTOK * HDIM);
    unsigned short* khg = alloc_us((size_t)NHEAD * NTOK * HDIM);
    unsigned short* klg = alloc_us((size_t)NHEAD * NTOK * HDIM);
    unsigned short* vtg = alloc_us((size_t)NHEAD * HDIM * NTOK);
    unsigned short* xh  = alloc_us((size_t)NTOK * CDIM);
    unsigned short* xl  = alloc_us((size_t)NTOK * CDIM);
    unsigned short* wqh = alloc_us((size_t)3 * CDIM * CDIM);
    unsigned short* wph = alloc_us((size_t)CDIM * CDIM);
    unsigned short* ath = alloc_us((size_t)NTOK * CDIM);

    const int nb_x = (NTOK * CDIM / 4) / 256;
    const int nb_wq = (3 * CDIM * CDIM / 4) / 256;
    const int nb_wp = (CDIM * CDIM / 4) / 256;
    split3<<<nb_x + nb_wq + nb_wp, 256, 0, stream>>>(x, xh, xl, nb_x,
                                                     Wqkv, wqh, nb_wq,
                                                     Wproj, wph);

    // 1) QKV projection (2-term); epilogue emits attention-ready bf16 buffers
    gemm_mfma<64, 128, NTOK, 3 * CDIM, CDIM, 1>
        <<<dim3((3 * CDIM) / 128, NTOK / 64), 256, 0, stream>>>(
            xh, xl, wqh, bqkv, nullptr, qhg, qlg, khg, klg, vtg);
    // 2) sparse attention (QBLK=128, 8 waves), writes plain bf16 att
    attn_mfma<<<256, 512, 0, stream>>>(qhg, qlg, khg, klg, vtg,
                                       frame_bias, adj, is_hub, ath);
    // 3) output projection (1-term plain bf16)
    gemm_mfma<64, 128, NTOK, CDIM, CDIM, 2>
        <<<dim3(CDIM / 128, NTOK / 64), 256, 0, stream>>>(
            ath, nullptr, wph, bproj, out, nullptr, nullptr, nullptr, nullptr, nullptr);
}

// Round 8
// 98.072 us; speedup vs baseline: 4.3231x; 1.0283x over previous
//
#include <hip/hip_runtime.h>
#include <hip/hip_bf16.h>
#include <math.h>

// Problem constants
#define NTOK 2048
#define CDIM 1024
#define NHEAD 16
#define HDIM 64
// frame id = token >> 8 (8 frames of 256 tokens)

typedef __attribute__((ext_vector_type(8))) short bf16x8;
typedef __attribute__((ext_vector_type(4))) short bf16x4;
typedef __attribute__((ext_vector_type(4))) float f32x4;
typedef __attribute__((ext_vector_type(4))) unsigned int u32x4;

// ---------------------------------------------------------------------------
// helpers
// ---------------------------------------------------------------------------
__device__ inline unsigned short bf16_rn(float f) {
    unsigned int u = __float_as_uint(f);
    u += 0x7FFFu + ((u >> 16) & 1u);
    return (unsigned short)(u >> 16);
}

__device__ inline void split4(float4 v, ushort4& h, ushort4& l) {
    float a[4] = {v.x, v.y, v.z, v.w};
    unsigned short hs[4], ls[4];
#pragma unroll
    for (int j = 0; j < 4; ++j) {
        hs[j] = bf16_rn(a[j]);
        float hf = __uint_as_float((unsigned int)hs[j] << 16);
        ls[j] = bf16_rn(a[j] - hf);
    }
    h.x = hs[0]; h.y = hs[1]; h.z = hs[2]; h.w = hs[3];
    l.x = ls[0]; l.y = ls[1]; l.z = ls[2]; l.w = ls[3];
}

template <int N> __device__ inline void waitcnt_vm() {
    if constexpr (N == 0) asm volatile("s_waitcnt vmcnt(0)" ::: "memory");
    else if constexpr (N == 3) asm volatile("s_waitcnt vmcnt(3)" ::: "memory");
    else if constexpr (N == 4) asm volatile("s_waitcnt vmcnt(4)" ::: "memory");
    else if constexpr (N == 6) asm volatile("s_waitcnt vmcnt(6)" ::: "memory");
}

__device__ inline void gload16(const void* g, void* l) {
    __builtin_amdgcn_global_load_lds((const __attribute__((address_space(1))) void*)g,
                                     (__attribute__((address_space(3))) void*)l,
                                     16, 0, 0);
}

// One dispatch: x -> hi/lo split; Wqkv, Wproj -> plain bf16 (hi only).
__global__ __launch_bounds__(256) void split3(const float* __restrict__ s0, unsigned short* __restrict__ h0,
                                              unsigned short* __restrict__ l0, int nb0,
                                              const float* __restrict__ s1, unsigned short* __restrict__ h1,
                                              int nb1,
                                              const float* __restrict__ s2, unsigned short* __restrict__ h2) {
    int b = blockIdx.x;
    const float* s;
    unsigned short *hh, *ll = nullptr;
    if (b < nb0) { s = s0; hh = h0; ll = l0; }
    else if (b < nb0 + nb1) { s = s1; hh = h1; b -= nb0; }
    else { s = s2; hh = h2; b -= nb0 + nb1; }
    const int i = b * 256 + threadIdx.x;
    float4 v = ((const float4*)s)[i];
    ushort4 h, l;
    split4(v, h, l);
    ((ushort4*)hh)[i] = h;
    if (ll) ((ushort4*)ll)[i] = l;
}

// ---------------------------------------------------------------------------
// MFMA GEMM, counted-vmcnt double buffer. BM=64, BN=128, 4 waves (32x64 each).
// MODE 1 (QKV): (Ah+Al) @ Bh^T, 2 terms; epilogue writes attention-ready
//   bf16 buffers: q hi/lo swizzled (scaled 0.125), K plain bf16 swizzled,
//   V^T plain bf16 swizzled.
// MODE 2 (PROJ): Ah @ Bh^T, 1 term; f32 out + bias.
// ---------------------------------------------------------------------------
template <int BM, int BN, int M, int N, int K, int MODE>
__global__ __launch_bounds__(256) void gemm_mfma(const unsigned short* __restrict__ Ah,
                                                 const unsigned short* __restrict__ Al,
                                                 const unsigned short* __restrict__ Bh,
                                                 const float* __restrict__ bias,
                                                 float* __restrict__ C,
                                                 unsigned short* __restrict__ qhg,
                                                 unsigned short* __restrict__ qlg,
                                                 unsigned short* __restrict__ khg,
                                                 unsigned short* __restrict__ vtg) {
    constexpr bool ASPLIT = (MODE == 1);
    constexpr int NA = ASPLIT ? 2 : 1;
    constexpr int FM = BM / 32;
    constexpr int FN = BN / 32;
    constexpr int ASZ = BM * 32;
    constexpr int BSZ = BN * 32;
    constexpr int BUF = NA * ASZ + BSZ;
    __shared__ unsigned short lds[2 * BUF];

    const int tid = threadIdx.x;
    const int lane = tid & 63;
    const int w = tid >> 6;
    const int m0 = blockIdx.y * BM;
    const int n0 = blockIdx.x * BN;
    const int wave_m = (w >> 1) * (BM / 2);
    const int wave_n = (w & 1) * (BN / 2);
    const int lr = lane & 15;
    const int kg = lane >> 4;
    const int srow = tid >> 2;
    const int scol = (tid & 3) * 8;

    const size_t aRow = (size_t)(m0 + srow) * K + scol;
    const size_t bRow = (size_t)(n0 + srow) * K + scol;

    f32x4 acc[FM][FN];
#pragma unroll
    for (int i = 0; i < FM; ++i)
#pragma unroll
        for (int j = 0; j < FN; ++j) acc[i][j] = {0.f, 0.f, 0.f, 0.f};

    auto stage = [&](int buf, int k0) {
        unsigned short* bb = lds + buf * BUF;
#pragma unroll
        for (int j = 0; j < BM / 64; ++j) {
            const size_t ga = aRow + (size_t)j * 64 * K + k0;
            const int ldst = (srow + j * 64) * 32 + scol;
            gload16(Ah + ga, bb + ldst);
            if constexpr (ASPLIT) gload16(Al + ga, bb + ASZ + ldst);
        }
#pragma unroll
        for (int j = 0; j < BN / 64; ++j) {
            const size_t gb = bRow + (size_t)j * 64 * K + k0;
            const int ldst = (srow + j * 64) * 32 + scol;
            gload16(Bh + gb, bb + NA * ASZ + ldst);
        }
    };

    stage(0, 0);
    constexpr int NL = NA * (BM / 64) + (BN / 64);
    constexpr int NT = K / 32;
    for (int t = 0; t < NT; ++t) {
        const int cur = t & 1;
        if (t + 1 < NT) {
            stage(cur ^ 1, (t + 1) * 32);
            waitcnt_vm<NL>();   // current tile's loads done; next stays in flight
        } else {
            waitcnt_vm<0>();
        }
        __builtin_amdgcn_s_barrier();

        const unsigned short* bb = lds + cur * BUF;
        bf16x8 ah[FM], al[FM], bh[FN];
#pragma unroll
        for (int f = 0; f < FM; ++f) {
            const int ra = (wave_m + f * 16 + lr) * 32 + kg * 8;
            ah[f] = *(const bf16x8*)&bb[ra];
            if constexpr (ASPLIT) al[f] = *(const bf16x8*)&bb[ASZ + ra];
        }
#pragma unroll
        for (int f = 0; f < FN; ++f) {
            const int rb = (wave_n + f * 16 + lr) * 32 + kg * 8;
            bh[f] = *(const bf16x8*)&bb[NA * ASZ + rb];
        }
        __builtin_amdgcn_s_setprio(1);
#pragma unroll
        for (int fm = 0; fm < FM; ++fm)
#pragma unroll
            for (int fn = 0; fn < FN; ++fn) {
                acc[fm][fn] = __builtin_amdgcn_mfma_f32_16x16x32_bf16(ah[fm], bh[fn], acc[fm][fn], 0, 0, 0);
                if constexpr (ASPLIT)
                    acc[fm][fn] = __builtin_amdgcn_mfma_f32_16x16x32_bf16(al[fm], bh[fn], acc[fm][fn], 0, 0, 0);
            }
        __builtin_amdgcn_s_setprio(0);
        asm volatile("" ::: "memory");
        __builtin_amdgcn_s_barrier();
    }

    // epilogue: C/D layout col=lane&15, row=(lane>>4)*4+reg  [m89-verified]
    if constexpr (MODE == 2) {
        float bv[FN];
#pragma unroll
        for (int fn = 0; fn < FN; ++fn) bv[fn] = bias[n0 + wave_n + fn * 16 + lr];
#pragma unroll
        for (int fm = 0; fm < FM; ++fm) {
            const int row0 = m0 + wave_m + fm * 16 + kg * 4;
#pragma unroll
            for (int fn = 0; fn < FN; ++fn) {
                const int col = n0 + wave_n + fn * 16 + lr;
#pragma unroll
                for (int r = 0; r < 4; ++r)
                    C[(size_t)(row0 + r) * N + col] = acc[fm][fn][r] + bv[fn];
            }
        }
    } else {
        const int reg = n0 >> 10;  // 0=q, 1=k, 2=v (uniform per block)
#pragma unroll
        for (int fn = 0; fn < FN; ++fn) {
            const int col = n0 + wave_n + fn * 16 + lr;
            const int head = (col >> 6) & 15;
            const int d = col & 63;
            const float bv = bias[col];
#pragma unroll
            for (int fm = 0; fm < FM; ++fm) {
                const int row0 = m0 + wave_m + fm * 16 + kg * 4;
                if (reg == 2) {
                    // V^T [h][d][tok ^ ((d&7)<<3)]
                    ushort4 pk;
                    pk.x = bf16_rn(acc[fm][fn][0] + bv);
                    pk.y = bf16_rn(acc[fm][fn][1] + bv);
                    pk.z = bf16_rn(acc[fm][fn][2] + bv);
                    pk.w = bf16_rn(acc[fm][fn][3] + bv);
                    const size_t idx = (size_t)(head * 64 + d) * 2048 + (size_t)(row0 ^ ((d & 7) << 3));
                    *(ushort4*)&vtg[idx] = pk;
                } else if (reg == 1) {
                    // K plain bf16 [h][tok][d ^ ((tok&7)<<3)]
#pragma unroll
                    for (int r = 0; r < 4; ++r) {
                        const int tok = row0 + r;
                        const size_t idx = ((size_t)head * 2048 + tok) * 64 + (d ^ ((tok & 7) << 3));
                        khg[idx] = bf16_rn(acc[fm][fn][r] + bv);
                    }
                } else {
                    // Q hi/lo, pre-scaled by 0.125
#pragma unroll
                    for (int r = 0; r < 4; ++r) {
                        const int tok = row0 + r;
                        const float val = (acc[fm][fn][r] + bv) * 0.125f;
                        const unsigned short hb = bf16_rn(val);
                        const unsigned short lb = bf16_rn(val - __uint_as_float((unsigned int)hb << 16));
                        const size_t idx = ((size_t)head * 2048 + tok) * 64 + (d ^ ((tok & 7) << 3));
                        qhg[idx] = hb;
                        qlg[idx] = lb;
                    }
                }
            }
        }
    }
}

// ---------------------------------------------------------------------------
// MFMA sparse flash attention. QBLK=64 (4 waves x 16 q rows), 512 blocks
// (2 blocks/CU for latency hiding), XCD-decoded (2 heads per XCD).
// K plain bf16 (2-term QK^T: Kh*(Qh+Ql)), counted-vmcnt(4) double buffer,
// setprio around MFMA clusters. Output: plain bf16 att.
// ---------------------------------------------------------------------------
__global__ __launch_bounds__(256) void attn_mfma(const unsigned short* __restrict__ qhg,
                                                 const unsigned short* __restrict__ qlg,
                                                 const unsigned short* __restrict__ khg,
                                                 const unsigned short* __restrict__ vtg,
                                                 const float* __restrict__ frame_bias,
                                                 const int* __restrict__ adj,
                                                 const int* __restrict__ is_hub,
                                                 unsigned short* __restrict__ ath) {
    __shared__ unsigned short sBuf[2][2][64 * 64];  // [buf][{kh,vt}]
    __shared__ int sList[32];
    __shared__ float sFB[8];
    __shared__ unsigned long long sHub[32];
    __shared__ int sNT;

    // XCD decode: bid&7 = XCD, each XCD owns heads {2r, 2r+1}; 512 blocks
    const int bid = blockIdx.x;
    const int r8 = bid & 7, tt = bid >> 3;
    const int qb = tt & 31, hb = tt >> 5;
    const int h = r8 * 2 + hb;
    const int q0 = qb * 64;

    const int tid = threadIdx.x;
    const int lane = tid & 63;
    const int wq = tid >> 6;       // 0..3
    const int lr = lane & 15;
    const int kg = lane >> 4;
    const int fi = q0 >> 8;

    // ---- Q fragments straight from global (pre-swizzled layout) ----
    const int qrow = wq * 16 + lr;          // block-local q row (0..63)
    const int qg = q0 + qrow;               // global token
    const unsigned short* qbh = qhg + ((size_t)h * 2048 + qg) * 64;
    const unsigned short* qbl = qlg + ((size_t)h * 2048 + qg) * 64;
    const int Xq = (qg & 7) << 3;
    bf16x8 qh[2], ql[2];
#pragma unroll
    for (int dc = 0; dc < 2; ++dc) {
        const int off = (dc * 32 + kg * 8) ^ Xq;
        qh[dc] = *(const bf16x8*)&qbh[off];
        ql[dc] = *(const bf16x8*)&qbl[off];
    }
    const bool hq = is_hub[qg] != 0;

    // ---- prologue tables ----
#pragma unroll
    for (int i = 0; i < 8; ++i) {
        const int t2 = wq * 8 + i;
        unsigned long long mb = __ballot(is_hub[t2 * 64 + lane] != 0);
        if (lane == 0) sHub[t2] = mb;
    }
    if (tid < 8) sFB[tid] = frame_bias[fi * 8 + tid];
    if (wq == 0) {
        const bool ok = (lane < 32) && (adj[fi * 8 + ((lane & 31) >> 2)] != 0);
        const unsigned long long am = __ballot(ok);
        if (lane == 0) {
            int c = 0;
#pragma unroll 1
            for (int t2 = 0; t2 < 32; ++t2)
                if ((am >> t2) & 1ull) sList[c++] = t2;
            sNT = c;
        }
    }
    __syncthreads();
    const int nt = sNT;

    // staging: 256 threads, 2 x 16B chunks per 64x64 u16 tile per array
    const int crow = tid >> 3;          // 0..31
    const int ccol = (tid & 7) * 8;
    const unsigned short* kbase = khg + (size_t)h * 2048 * 64;
    const unsigned short* vbase = vtg + (size_t)h * 64 * 2048;

    auto stage = [&](int buf, int n0s) {
        const int dst = tid * 8;
        gload16(kbase + (size_t)(n0s + crow) * 64 + ccol, &sBuf[buf][0][dst]);
        gload16(kbase + (size_t)(n0s + crow + 32) * 64 + ccol, &sBuf[buf][0][dst + 2048]);
        gload16(vbase + (size_t)crow * 2048 + n0s + ccol, &sBuf[buf][1][dst]);
        gload16(vbase + (size_t)(crow + 32) * 2048 + n0s + ccol, &sBuf[buf][1][dst + 2048]);
    };

    float m_i = -INFINITY, l_i = 0.f;
    f32x4 oacc[4];
#pragma unroll
    for (int fd = 0; fd < 4; ++fd) oacc[fd] = {0.f, 0.f, 0.f, 0.f};

    stage(0, sList[0] * 64);
#pragma unroll 1
    for (int i = 0; i < nt; ++i) {
        const int cur = i & 1;
        const int tile = sList[i];
        if (i + 1 < nt) {
            stage(cur ^ 1, sList[i + 1] * 64);
            waitcnt_vm<4>();
        } else {
            waitcnt_vm<0>();
        }
        __builtin_amdgcn_s_barrier();

        const int fj = tile >> 2;
        const bool same = (fj == fi);
        const float biasv = sFB[fj];
        const unsigned long long hubmask = sHub[tile];
        const unsigned short* sKh = &sBuf[cur][0][0];
        const unsigned short* sVt = &sBuf[cur][1][0];

        // ---- S^T = Kh . (Qh+Ql)^T (2 terms) ----
        f32x4 sacc[4];
#pragma unroll
        for (int fk = 0; fk < 4; ++fk) sacc[fk] = {0.f, 0.f, 0.f, 0.f};
        __builtin_amdgcn_s_setprio(1);
#pragma unroll
        for (int fk = 0; fk < 4; ++fk) {
            const int r = fk * 16 + lr;
            const int Xk = (r & 7) << 3;
            const int rb = r * 64;
#pragma unroll
            for (int dc = 0; dc < 2; ++dc) {
                const int off = rb + ((dc * 32 + kg * 8) ^ Xk);
                bf16x8 khf = *(const bf16x8*)&sKh[off];
                sacc[fk] = __builtin_amdgcn_mfma_f32_16x16x32_bf16(khf, qh[dc], sacc[fk], 0, 0, 0);
                sacc[fk] = __builtin_amdgcn_mfma_f32_16x16x32_bf16(khf, ql[dc], sacc[fk], 0, 0, 0);
            }
        }
        __builtin_amdgcn_s_setprio(0);

        // ---- mask + bias + online softmax (lane owns 16 scores of its q) ----
        float sv[4][4];
        float rmax = -INFINITY;
#pragma unroll
        for (int fk = 0; fk < 4; ++fk)
#pragma unroll
            for (int r = 0; r < 4; ++r) {
                float val = sacc[fk][r] + biasv;
                if (!same) {
                    const int k = fk * 16 + kg * 4 + r;
                    const bool hk = (hubmask >> k) & 1ull;
                    if (hq || hk) val = -INFINITY;
                }
                sv[fk][r] = val;
                rmax = fmaxf(rmax, val);
            }
        rmax = fmaxf(rmax, __shfl_xor(rmax, 16));
        rmax = fmaxf(rmax, __shfl_xor(rmax, 32));

        const float mn = fmaxf(m_i, rmax);
        const float alpha = (mn == -INFINITY) ? 1.f : __expf(m_i - mn);
        m_i = mn;

        float p[4][4];
        float psum = 0.f;
#pragma unroll
        for (int fk = 0; fk < 4; ++fk)
#pragma unroll
            for (int r = 0; r < 4; ++r) {
                const float pv = (sv[fk][r] == -INFINITY) ? 0.f : __expf(sv[fk][r] - mn);
                p[fk][r] = pv;
                psum += pv;
            }
        psum += __shfl_xor(psum, 16);
        psum += __shfl_xor(psum, 32);
        l_i = l_i * alpha + psum;
#pragma unroll
        for (int fd = 0; fd < 4; ++fd) {
            oacc[fd][0] *= alpha; oacc[fd][1] *= alpha;
            oacc[fd][2] *= alpha; oacc[fd][3] *= alpha;
        }

        // ---- pack P, O^T += V^T . P^T (k-slot permuted) ----
        unsigned int pc[4][2];
#pragma unroll
        for (int fk = 0; fk < 4; ++fk)
#pragma unroll
            for (int rp = 0; rp < 2; ++rp)
                pc[fk][rp] = (unsigned int)bf16_rn(p[fk][2 * rp]) |
                             ((unsigned int)bf16_rn(p[fk][2 * rp + 1]) << 16);
        __builtin_amdgcn_s_setprio(1);
#pragma unroll
        for (int c = 0; c < 2; ++c) {
            u32x4 pw = {pc[2 * c][0], pc[2 * c][1], pc[2 * c + 1][0], pc[2 * c + 1][1]};
            bf16x8 pb = __builtin_bit_cast(bf16x8, pw);
#pragma unroll
            for (int fd = 0; fd < 4; ++fd) {
                const int vrow = fd * 16 + lr;
                const int Xv = (vrow & 7) << 3;
                const int vb = vrow * 64;
                bf16x4 v0 = *(const bf16x4*)&sVt[vb + ((c * 32 + kg * 4) ^ Xv)];
                bf16x4 v1 = *(const bf16x4*)&sVt[vb + ((c * 32 + 16 + kg * 4) ^ Xv)];
                bf16x8 va = __builtin_shufflevector(v0, v1, 0, 1, 2, 3, 4, 5, 6, 7);
                oacc[fd] = __builtin_amdgcn_mfma_f32_16x16x32_bf16(va, pb, oacc[fd], 0, 0, 0);
            }
        }
        __builtin_amdgcn_s_setprio(0);
        asm volatile("" ::: "memory");
        __builtin_amdgcn_s_barrier();
    }

    // ---- epilogue: O^T -> att bf16 ----
    const float inv = 1.f / l_i;
#pragma unroll
    for (int fd = 0; fd < 4; ++fd) {
        ushort4 h4;
        h4.x = bf16_rn(oacc[fd][0] * inv);
        h4.y = bf16_rn(oacc[fd][1] * inv);
        h4.z = bf16_rn(oacc[fd][2] * inv);
        h4.w = bf16_rn(oacc[fd][3] * inv);
        const size_t idx = (size_t)qg * CDIM + h * 64 + fd * 16 + kg * 4;
        *(ushort4*)&ath[idx] = h4;
    }
}

// ---------------------------------------------------------------------------
extern "C" void kernel_launch(void* const* d_in, const int* in_sizes, int n_in,
                              void* d_out, int out_size, void* d_ws, size_t ws_size,
                              hipStream_t stream) {
    const float* x          = (const float*)d_in[0];
    const float* Wqkv       = (const float*)d_in[1];
    const float* bqkv       = (const float*)d_in[2];
    const float* Wproj      = (const float*)d_in[3];
    const float* bproj      = (const float*)d_in[4];
    const float* frame_bias = (const float*)d_in[5];
    const int*   adj        = (const int*)d_in[6];
    const int*   is_hub     = (const int*)d_in[8];
    float* out = (float*)d_out;

    char* ws = (char*)d_ws;
    size_t off = 0;
    auto alloc_us = [&](size_t n) { unsigned short* p = (unsigned short*)(ws + off); off += n * 2; return p; };
    unsigned short* qhg = alloc_us((size_t)NHEAD * NTOK * HDIM);
    unsigned short* qlg = alloc_us((size_t)NHEAD * NTOK * HDIM);
    unsigned short* khg = alloc_us((size_t)NHEAD * NTOK * HDIM);
    unsigned short* vtg = alloc_us((size_t)NHEAD * HDIM * NTOK);
    unsigned short* xh  = alloc_us((size_t)NTOK * CDIM);
    unsigned short* xl  = alloc_us((size_t)NTOK * CDIM);
    unsigned short* wqh = alloc_us((size_t)3 * CDIM * CDIM);
    unsigned short* wph = alloc_us((size_t)CDIM * CDIM);
    unsigned short* ath = alloc_us((size_t)NTOK * CDIM);

    const int nb_x = (NTOK * CDIM / 4) / 256;
    const int nb_wq = (3 * CDIM * CDIM / 4) / 256;
    const int nb_wp = (CDIM * CDIM / 4) / 256;
    split3<<<nb_x + nb_wq + nb_wp, 256, 0, stream>>>(x, xh, xl, nb_x,
                                                     Wqkv, wqh, nb_wq,
                                                     Wproj, wph);

    // 1) QKV projection (2-term); epilogue emits attention-ready bf16 buffers
    gemm_mfma<64, 128, NTOK, 3 * CDIM, CDIM, 1>
        <<<dim3((3 * CDIM) / 128, NTOK / 64), 256, 0, stream>>>(
            xh, xl, wqh, bqkv, nullptr, qhg, qlg, khg, vtg);
    // 2) sparse attention (QBLK=64, 4 waves, 2 blocks/CU), writes bf16 att
    attn_mfma<<<512, 256, 0, stream>>>(qhg, qlg, khg, vtg,
                                       frame_bias, adj, is_hub, ath);
    // 3) output projection (1-term plain bf16)
    gemm_mfma<64, 128, NTOK, CDIM, CDIM, 2>
        <<<dim3(CDIM / 128, NTOK / 64), 256, 0, stream>>>(
            ath, nullptr, wph, bproj, out, nullptr, nullptr, nullptr, nullptr);
}

// Round 9
// 92.122 us; speedup vs baseline: 4.6024x; 1.0646x over previous
//
#include <hip/hip_runtime.h>
#include <hip/hip_bf16.h>
#include <math.h>

// Problem constants
#define NTOK 2048
#define CDIM 1024
#define NHEAD 16
#define HDIM 64
// frame id = token >> 8 (8 frames of 256 tokens)

typedef __attribute__((ext_vector_type(8))) short bf16x8;
typedef __attribute__((ext_vector_type(4))) short bf16x4;
typedef __attribute__((ext_vector_type(4))) float f32x4;
typedef __attribute__((ext_vector_type(4))) unsigned int u32x4;

// ---------------------------------------------------------------------------
// helpers
// ---------------------------------------------------------------------------
__device__ inline unsigned short bf16_rn(float f) {
    unsigned int u = __float_as_uint(f);
    u += 0x7FFFu + ((u >> 16) & 1u);
    return (unsigned short)(u >> 16);
}

__device__ inline void split4(float4 v, ushort4& h, ushort4& l) {
    float a[4] = {v.x, v.y, v.z, v.w};
    unsigned short hs[4], ls[4];
#pragma unroll
    for (int j = 0; j < 4; ++j) {
        hs[j] = bf16_rn(a[j]);
        float hf = __uint_as_float((unsigned int)hs[j] << 16);
        ls[j] = bf16_rn(a[j] - hf);
    }
    h.x = hs[0]; h.y = hs[1]; h.z = hs[2]; h.w = hs[3];
    l.x = ls[0]; l.y = ls[1]; l.z = ls[2]; l.w = ls[3];
}

template <int N> __device__ inline void waitcnt_vm() {
    if constexpr (N == 0) asm volatile("s_waitcnt vmcnt(0)" ::: "memory");
    else if constexpr (N == 3) asm volatile("s_waitcnt vmcnt(3)" ::: "memory");
    else if constexpr (N == 4) asm volatile("s_waitcnt vmcnt(4)" ::: "memory");
    else if constexpr (N == 8) asm volatile("s_waitcnt vmcnt(8)" ::: "memory");
}

__device__ inline void gload16(const void* g, void* l) {
    __builtin_amdgcn_global_load_lds((const __attribute__((address_space(1))) void*)g,
                                     (__attribute__((address_space(3))) void*)l,
                                     16, 0, 0);
}

// One dispatch: x -> hi/lo split; Wqkv, Wproj -> plain bf16 (hi only).
__global__ __launch_bounds__(256) void split3(const float* __restrict__ s0, unsigned short* __restrict__ h0,
                                              unsigned short* __restrict__ l0, int nb0,
                                              const float* __restrict__ s1, unsigned short* __restrict__ h1,
                                              int nb1,
                                              const float* __restrict__ s2, unsigned short* __restrict__ h2) {
    int b = blockIdx.x;
    const float* s;
    unsigned short *hh, *ll = nullptr;
    if (b < nb0) { s = s0; hh = h0; ll = l0; }
    else if (b < nb0 + nb1) { s = s1; hh = h1; b -= nb0; }
    else { s = s2; hh = h2; b -= nb0 + nb1; }
    const int i = b * 256 + threadIdx.x;
    float4 v = ((const float4*)s)[i];
    ushort4 h, l;
    split4(v, h, l);
    ((ushort4*)hh)[i] = h;
    if (ll) ((ushort4*)ll)[i] = l;
}

// ---------------------------------------------------------------------------
// MFMA GEMM, counted-vmcnt double buffer. BM=64, BN=128, 4 waves (32x64 each).
// MODE 1 (QKV): (Ah+Al) @ Bh^T for Q/K columns (n0 < 2048); Ah @ Bh^T for V
//   columns (V tolerates 1-term). Epilogue writes attention-ready bf16:
//   q hi/lo swizzled (scaled 0.125), K plain bf16 swizzled, V^T swizzled.
// MODE 2 (PROJ): Ah @ Bh^T, 1 term; f32 out + bias.
// ---------------------------------------------------------------------------
template <int BM, int BN, int M, int N, int K, int MODE>
__global__ __launch_bounds__(256) void gemm_mfma(const unsigned short* __restrict__ Ah,
                                                 const unsigned short* __restrict__ Al,
                                                 const unsigned short* __restrict__ Bh,
                                                 const float* __restrict__ bias,
                                                 float* __restrict__ C,
                                                 unsigned short* __restrict__ qhg,
                                                 unsigned short* __restrict__ qlg,
                                                 unsigned short* __restrict__ khg,
                                                 unsigned short* __restrict__ vtg) {
    constexpr bool ASPLIT = (MODE == 1);
    constexpr int FM = BM / 32;
    constexpr int FN = BN / 32;
    constexpr int ASZ = BM * 32;
    constexpr int BSZ = BN * 32;
    constexpr int BUF = 2 * ASZ + BSZ;   // room for Ah, Al, Bh (Al slot unused when !doAl)
    __shared__ unsigned short lds[2 * BUF];

    const int tid = threadIdx.x;
    const int lane = tid & 63;
    const int w = tid >> 6;
    const int m0 = blockIdx.y * BM;
    const int n0 = blockIdx.x * BN;
    const bool doAl = ASPLIT && (n0 < 2048);   // V columns: 1-term
    const int wave_m = (w >> 1) * (BM / 2);
    const int wave_n = (w & 1) * (BN / 2);
    const int lr = lane & 15;
    const int kg = lane >> 4;
    const int srow = tid >> 2;
    const int scol = (tid & 3) * 8;

    const size_t aRow = (size_t)(m0 + srow) * K + scol;
    const size_t bRow = (size_t)(n0 + srow) * K + scol;

    f32x4 acc[FM][FN];
#pragma unroll
    for (int i = 0; i < FM; ++i)
#pragma unroll
        for (int j = 0; j < FN; ++j) acc[i][j] = {0.f, 0.f, 0.f, 0.f};

    auto stage = [&](int buf, int k0) {
        unsigned short* bb = lds + buf * BUF;
#pragma unroll
        for (int j = 0; j < BM / 64; ++j) {
            const size_t ga = aRow + (size_t)j * 64 * K + k0;
            const int ldst = (srow + j * 64) * 32 + scol;
            gload16(Ah + ga, bb + ldst);
            if (doAl) gload16(Al + ga, bb + ASZ + ldst);
        }
#pragma unroll
        for (int j = 0; j < BN / 64; ++j) {
            const size_t gb = bRow + (size_t)j * 64 * K + k0;
            const int ldst = (srow + j * 64) * 32 + scol;
            gload16(Bh + gb, bb + 2 * ASZ + ldst);
        }
    };

    stage(0, 0);
    constexpr int NT = K / 32;
    for (int t = 0; t < NT; ++t) {
        const int cur = t & 1;
        if (t + 1 < NT) {
            stage(cur ^ 1, (t + 1) * 32);
            if (doAl) waitcnt_vm<4>(); else waitcnt_vm<3>();
        } else {
            waitcnt_vm<0>();
        }
        __builtin_amdgcn_s_barrier();

        const unsigned short* bb = lds + cur * BUF;
        bf16x8 ah[FM], al[FM], bh[FN];
#pragma unroll
        for (int f = 0; f < FM; ++f) {
            const int ra = (wave_m + f * 16 + lr) * 32 + kg * 8;
            ah[f] = *(const bf16x8*)&bb[ra];
            if (doAl) al[f] = *(const bf16x8*)&bb[ASZ + ra];
        }
#pragma unroll
        for (int f = 0; f < FN; ++f) {
            const int rb = (wave_n + f * 16 + lr) * 32 + kg * 8;
            bh[f] = *(const bf16x8*)&bb[2 * ASZ + rb];
        }
        __builtin_amdgcn_s_setprio(1);
#pragma unroll
        for (int fm = 0; fm < FM; ++fm)
#pragma unroll
            for (int fn = 0; fn < FN; ++fn) {
                acc[fm][fn] = __builtin_amdgcn_mfma_f32_16x16x32_bf16(ah[fm], bh[fn], acc[fm][fn], 0, 0, 0);
                if (doAl)
                    acc[fm][fn] = __builtin_amdgcn_mfma_f32_16x16x32_bf16(al[fm], bh[fn], acc[fm][fn], 0, 0, 0);
            }
        __builtin_amdgcn_s_setprio(0);
        asm volatile("" ::: "memory");
        __builtin_amdgcn_s_barrier();
    }

    // epilogue: C/D layout col=lane&15, row=(lane>>4)*4+reg  [m89-verified]
    if constexpr (MODE == 2) {
        float bv[FN];
#pragma unroll
        for (int fn = 0; fn < FN; ++fn) bv[fn] = bias[n0 + wave_n + fn * 16 + lr];
#pragma unroll
        for (int fm = 0; fm < FM; ++fm) {
            const int row0 = m0 + wave_m + fm * 16 + kg * 4;
#pragma unroll
            for (int fn = 0; fn < FN; ++fn) {
                const int col = n0 + wave_n + fn * 16 + lr;
#pragma unroll
                for (int r = 0; r < 4; ++r)
                    C[(size_t)(row0 + r) * N + col] = acc[fm][fn][r] + bv[fn];
            }
        }
    } else {
        const int reg = n0 >> 10;  // 0=q, 1=k, 2=v (uniform per block)
#pragma unroll
        for (int fn = 0; fn < FN; ++fn) {
            const int col = n0 + wave_n + fn * 16 + lr;
            const int head = (col >> 6) & 15;
            const int d = col & 63;
            const float bv = bias[col];
#pragma unroll
            for (int fm = 0; fm < FM; ++fm) {
                const int row0 = m0 + wave_m + fm * 16 + kg * 4;
                if (reg == 2) {
                    // V^T [h][d][tok ^ ((d&7)<<3)]
                    ushort4 pk;
                    pk.x = bf16_rn(acc[fm][fn][0] + bv);
                    pk.y = bf16_rn(acc[fm][fn][1] + bv);
                    pk.z = bf16_rn(acc[fm][fn][2] + bv);
                    pk.w = bf16_rn(acc[fm][fn][3] + bv);
                    const size_t idx = (size_t)(head * 64 + d) * 2048 + (size_t)(row0 ^ ((d & 7) << 3));
                    *(ushort4*)&vtg[idx] = pk;
                } else if (reg == 1) {
                    // K plain bf16 [h][tok][d ^ ((tok&7)<<3)]
#pragma unroll
                    for (int r = 0; r < 4; ++r) {
                        const int tok = row0 + r;
                        const size_t idx = ((size_t)head * 2048 + tok) * 64 + (d ^ ((tok & 7) << 3));
                        khg[idx] = bf16_rn(acc[fm][fn][r] + bv);
                    }
                } else {
                    // Q hi/lo, pre-scaled by 0.125
#pragma unroll
                    for (int r = 0; r < 4; ++r) {
                        const int tok = row0 + r;
                        const float val = (acc[fm][fn][r] + bv) * 0.125f;
                        const unsigned short hb = bf16_rn(val);
                        const unsigned short lb = bf16_rn(val - __uint_as_float((unsigned int)hb << 16));
                        const size_t idx = ((size_t)head * 2048 + tok) * 64 + (d ^ ((tok & 7) << 3));
                        qhg[idx] = hb;
                        qlg[idx] = lb;
                    }
                }
            }
        }
    }
}

// ---------------------------------------------------------------------------
// MFMA sparse flash attention, 2-tile-per-iteration (pair ILP).
// QBLK=64 (4 waves x 16 q rows), 512 blocks, XCD-decoded.
// Per pair: QK both tiles (8 indep MFMA chains), ONE combined online-softmax
// update, PV both tiles; barriers/vmcnt per-tile halved. Odd nt padded with
// a duplicate tile at bias=-inf (P==0, provably no contribution).
// ---------------------------------------------------------------------------
__global__ __launch_bounds__(256) void attn_mfma(const unsigned short* __restrict__ qhg,
                                                 const unsigned short* __restrict__ qlg,
                                                 const unsigned short* __restrict__ khg,
                                                 const unsigned short* __restrict__ vtg,
                                                 const float* __restrict__ frame_bias,
                                                 const int* __restrict__ adj,
                                                 const int* __restrict__ is_hub,
                                                 unsigned short* __restrict__ ath) {
    __shared__ unsigned short sBuf[2][4][64 * 64];  // [buf][{kA,vA,kB,vB}]
    __shared__ int sList[34];
    __shared__ float sFB[8];
    __shared__ unsigned long long sHub[32];
    __shared__ int sNT;

    // XCD decode: bid&7 = XCD, each XCD owns heads {2r, 2r+1}; 512 blocks
    const int bid = blockIdx.x;
    const int r8 = bid & 7, tt = bid >> 3;
    const int qb = tt & 31, hb = tt >> 5;
    const int h = r8 * 2 + hb;
    const int q0 = qb * 64;

    const int tid = threadIdx.x;
    const int lane = tid & 63;
    const int wq = tid >> 6;       // 0..3
    const int lr = lane & 15;
    const int kg = lane >> 4;
    const int fi = q0 >> 8;

    // ---- Q fragments straight from global (pre-swizzled layout) ----
    const int qrow = wq * 16 + lr;          // block-local q row (0..63)
    const int qg = q0 + qrow;               // global token
    const unsigned short* qbh = qhg + ((size_t)h * 2048 + qg) * 64;
    const unsigned short* qbl = qlg + ((size_t)h * 2048 + qg) * 64;
    const int Xq = (qg & 7) << 3;
    bf16x8 qh[2], ql[2];
#pragma unroll
    for (int dc = 0; dc < 2; ++dc) {
        const int off = (dc * 32 + kg * 8) ^ Xq;
        qh[dc] = *(const bf16x8*)&qbh[off];
        ql[dc] = *(const bf16x8*)&qbl[off];
    }
    const bool hq = is_hub[qg] != 0;

    // ---- prologue tables ----
#pragma unroll
    for (int i = 0; i < 8; ++i) {
        const int t2 = wq * 8 + i;
        unsigned long long mb = __ballot(is_hub[t2 * 64 + lane] != 0);
        if (lane == 0) sHub[t2] = mb;
    }
    if (tid < 8) sFB[tid] = frame_bias[fi * 8 + tid];
    if (wq == 0) {
        const bool ok = (lane < 32) && (adj[fi * 8 + ((lane & 31) >> 2)] != 0);
        const unsigned long long am = __ballot(ok);
        if (lane == 0) {
            int c = 0;
#pragma unroll 1
            for (int t2 = 0; t2 < 32; ++t2)
                if ((am >> t2) & 1ull) sList[c++] = t2;
            sNT = c;
            if (c & 1) sList[c] = sList[c - 1];  // pad duplicate (bias=-inf later)
        }
    }
    __syncthreads();
    const int nt = sNT;
    const int npair = (nt + 1) >> 1;

    // staging: 256 threads, 2 x 16B chunks per 64x64 u16 tile per array
    const int crow = tid >> 3;          // 0..31
    const int ccol = (tid & 7) * 8;
    const unsigned short* kbase = khg + (size_t)h * 2048 * 64;
    const unsigned short* vbase = vtg + (size_t)h * 64 * 2048;

    auto stageT = [&](int buf, int half, int n0s) {
        const int dst = tid * 8;
        gload16(kbase + (size_t)(n0s + crow) * 64 + ccol, &sBuf[buf][half * 2 + 0][dst]);
        gload16(kbase + (size_t)(n0s + crow + 32) * 64 + ccol, &sBuf[buf][half * 2 + 0][dst + 2048]);
        gload16(vbase + (size_t)crow * 2048 + n0s + ccol, &sBuf[buf][half * 2 + 1][dst]);
        gload16(vbase + (size_t)(crow + 32) * 2048 + n0s + ccol, &sBuf[buf][half * 2 + 1][dst + 2048]);
    };

    float m_i = -INFINITY, l_i = 0.f;
    f32x4 oacc[4];
#pragma unroll
    for (int fd = 0; fd < 4; ++fd) oacc[fd] = {0.f, 0.f, 0.f, 0.f};

    stageT(0, 0, sList[0] * 64);
    stageT(0, 1, sList[1] * 64);
#pragma unroll 1
    for (int p = 0; p < npair; ++p) {
        const int cur = p & 1;
        const int ta = sList[2 * p];
        const int tb = sList[2 * p + 1];
        if (p + 1 < npair) {
            stageT(cur ^ 1, 0, sList[2 * p + 2] * 64);
            stageT(cur ^ 1, 1, sList[2 * p + 3] * 64);
            waitcnt_vm<8>();
        } else {
            waitcnt_vm<0>();
        }
        __builtin_amdgcn_s_barrier();

        const int fja = ta >> 2, fjb = tb >> 2;
        const bool samea = (fja == fi), sameb = (fjb == fi);
        const float biasa = sFB[fja];
        const float biasb = (2 * p + 1 < nt) ? sFB[fjb] : -INFINITY;
        const unsigned long long hma = sHub[ta], hmb = sHub[tb];
        const unsigned short* sKa = &sBuf[cur][0][0];
        const unsigned short* sVa = &sBuf[cur][1][0];
        const unsigned short* sKb = &sBuf[cur][2][0];
        const unsigned short* sVb = &sBuf[cur][3][0];

        // ---- S^T for both tiles: 8 independent MFMA chains ----
        f32x4 sa[4], sb[4];
#pragma unroll
        for (int fk = 0; fk < 4; ++fk) { sa[fk] = {0.f, 0.f, 0.f, 0.f}; sb[fk] = {0.f, 0.f, 0.f, 0.f}; }
        __builtin_amdgcn_s_setprio(1);
#pragma unroll
        for (int fk = 0; fk < 4; ++fk) {
            const int r = fk * 16 + lr;
            const int Xk = (r & 7) << 3;
            const int rb = r * 64;
#pragma unroll
            for (int dc = 0; dc < 2; ++dc) {
                const int off = rb + ((dc * 32 + kg * 8) ^ Xk);
                bf16x8 ka = *(const bf16x8*)&sKa[off];
                bf16x8 kb = *(const bf16x8*)&sKb[off];
                sa[fk] = __builtin_amdgcn_mfma_f32_16x16x32_bf16(ka, qh[dc], sa[fk], 0, 0, 0);
                sb[fk] = __builtin_amdgcn_mfma_f32_16x16x32_bf16(kb, qh[dc], sb[fk], 0, 0, 0);
                sa[fk] = __builtin_amdgcn_mfma_f32_16x16x32_bf16(ka, ql[dc], sa[fk], 0, 0, 0);
                sb[fk] = __builtin_amdgcn_mfma_f32_16x16x32_bf16(kb, ql[dc], sb[fk], 0, 0, 0);
            }
        }
        __builtin_amdgcn_s_setprio(0);

        // ---- masks + combined online softmax over both tiles ----
        float pa[4][4], pb[4][4];
        float rmax = -INFINITY;
#pragma unroll
        for (int fk = 0; fk < 4; ++fk)
#pragma unroll
            for (int r = 0; r < 4; ++r) {
                const int k = fk * 16 + kg * 4 + r;
                float va = sa[fk][r] + biasa;
                if (!samea && (hq || ((hma >> k) & 1ull))) va = -INFINITY;
                float vb = sb[fk][r] + biasb;
                if (!sameb && (hq || ((hmb >> k) & 1ull))) vb = -INFINITY;
                pa[fk][r] = va;
                pb[fk][r] = vb;
                rmax = fmaxf(rmax, fmaxf(va, vb));
            }
        rmax = fmaxf(rmax, __shfl_xor(rmax, 16));
        rmax = fmaxf(rmax, __shfl_xor(rmax, 32));

        const float mn = fmaxf(m_i, rmax);
        const float alpha = (mn == -INFINITY) ? 1.f : __expf(m_i - mn);
        m_i = mn;

        float psum = 0.f;
#pragma unroll
        for (int fk = 0; fk < 4; ++fk)
#pragma unroll
            for (int r = 0; r < 4; ++r) {
                const float ea = (pa[fk][r] == -INFINITY) ? 0.f : __expf(pa[fk][r] - mn);
                const float eb = (pb[fk][r] == -INFINITY) ? 0.f : __expf(pb[fk][r] - mn);
                pa[fk][r] = ea;
                pb[fk][r] = eb;
                psum += ea + eb;
            }
        psum += __shfl_xor(psum, 16);
        psum += __shfl_xor(psum, 32);
        l_i = l_i * alpha + psum;
#pragma unroll
        for (int fd = 0; fd < 4; ++fd) {
            oacc[fd][0] *= alpha; oacc[fd][1] *= alpha;
            oacc[fd][2] *= alpha; oacc[fd][3] *= alpha;
        }

        // ---- pack P for both tiles, PV both tiles ----
        unsigned int pca[4][2], pcb[4][2];
#pragma unroll
        for (int fk = 0; fk < 4; ++fk)
#pragma unroll
            for (int rp = 0; rp < 2; ++rp) {
                pca[fk][rp] = (unsigned int)bf16_rn(pa[fk][2 * rp]) |
                              ((unsigned int)bf16_rn(pa[fk][2 * rp + 1]) << 16);
                pcb[fk][rp] = (unsigned int)bf16_rn(pb[fk][2 * rp]) |
                              ((unsigned int)bf16_rn(pb[fk][2 * rp + 1]) << 16);
            }
        __builtin_amdgcn_s_setprio(1);
#pragma unroll
        for (int half = 0; half < 2; ++half) {
            const unsigned int (*pc)[2] = half ? pcb : pca;
            const unsigned short* sV = half ? sVb : sVa;
#pragma unroll
            for (int c = 0; c < 2; ++c) {
                u32x4 pw = {pc[2 * c][0], pc[2 * c][1], pc[2 * c + 1][0], pc[2 * c + 1][1]};
                bf16x8 pbv = __builtin_bit_cast(bf16x8, pw);
#pragma unroll
                for (int fd = 0; fd < 4; ++fd) {
                    const int vrow = fd * 16 + lr;
                    const int Xv = (vrow & 7) << 3;
                    const int vb = vrow * 64;
                    bf16x4 v0 = *(const bf16x4*)&sV[vb + ((c * 32 + kg * 4) ^ Xv)];
                    bf16x4 v1 = *(const bf16x4*)&sV[vb + ((c * 32 + 16 + kg * 4) ^ Xv)];
                    bf16x8 va = __builtin_shufflevector(v0, v1, 0, 1, 2, 3, 4, 5, 6, 7);
                    oacc[fd] = __builtin_amdgcn_mfma_f32_16x16x32_bf16(va, pbv, oacc[fd], 0, 0, 0);
                }
            }
        }
        __builtin_amdgcn_s_setprio(0);
        asm volatile("" ::: "memory");
        __builtin_amdgcn_s_barrier();
    }

    // ---- epilogue: O^T -> att bf16 ----
    const float inv = 1.f / l_i;
#pragma unroll
    for (int fd = 0; fd < 4; ++fd) {
        ushort4 h4;
        h4.x = bf16_rn(oacc[fd][0] * inv);
        h4.y = bf16_rn(oacc[fd][1] * inv);
        h4.z = bf16_rn(oacc[fd][2] * inv);
        h4.w = bf16_rn(oacc[fd][3] * inv);
        const size_t idx = (size_t)qg * CDIM + h * 64 + fd * 16 + kg * 4;
        *(ushort4*)&ath[idx] = h4;
    }
}

// ---------------------------------------------------------------------------
extern "C" void kernel_launch(void* const* d_in, const int* in_sizes, int n_in,
                              void* d_out, int out_size, void* d_ws, size_t ws_size,
                              hipStream_t stream) {
    const float* x          = (const float*)d_in[0];
    const float* Wqkv       = (const float*)d_in[1];
    const float* bqkv       = (const float*)d_in[2];
    const float* Wproj      = (const float*)d_in[3];
    const float* bproj      = (const float*)d_in[4];
    const float* frame_bias = (const float*)d_in[5];
    const int*   adj        = (const int*)d_in[6];
    const int*   is_hub     = (const int*)d_in[8];
    float* out = (float*)d_out;

    char* ws = (char*)d_ws;
    size_t off = 0;
    auto alloc_us = [&](size_t n) { unsigned short* p = (unsigned short*)(ws + off); off += n * 2; return p; };
    unsigned short* qhg = alloc_us((size_t)NHEAD * NTOK * HDIM);
    unsigned short* qlg = alloc_us((size_t)NHEAD * NTOK * HDIM);
    unsigned short* khg = alloc_us((size_t)NHEAD * NTOK * HDIM);
    unsigned short* vtg = alloc_us((size_t)NHEAD * HDIM * NTOK);
    unsigned short* xh  = alloc_us((size_t)NTOK * CDIM);
    unsigned short* xl  = alloc_us((size_t)NTOK * CDIM);
    unsigned short* wqh = alloc_us((size_t)3 * CDIM * CDIM);
    unsigned short* wph = alloc_us((size_t)CDIM * CDIM);
    unsigned short* ath = alloc_us((size_t)NTOK * CDIM);

    const int nb_x = (NTOK * CDIM / 4) / 256;
    const int nb_wq = (3 * CDIM * CDIM / 4) / 256;
    const int nb_wp = (CDIM * CDIM / 4) / 256;
    split3<<<nb_x + nb_wq + nb_wp, 256, 0, stream>>>(x, xh, xl, nb_x,
                                                     Wqkv, wqh, nb_wq,
                                                     Wproj, wph);

    // 1) QKV projection (2-term Q/K, 1-term V); epilogue emits bf16 buffers
    gemm_mfma<64, 128, NTOK, 3 * CDIM, CDIM, 1>
        <<<dim3((3 * CDIM) / 128, NTOK / 64), 256, 0, stream>>>(
            xh, xl, wqh, bqkv, nullptr, qhg, qlg, khg, vtg);
    // 2) sparse attention (pair-ILP), writes bf16 att
    attn_mfma<<<512, 256, 0, stream>>>(qhg, qlg, khg, vtg,
                                       frame_bias, adj, is_hub, ath);
    // 3) output projection (1-term plain bf16)
    gemm_mfma<64, 128, NTOK, CDIM, CDIM, 2>
        <<<dim3(CDIM / 128, NTOK / 64), 256, 0, stream>>>(
            ath, nullptr, wph, bproj, out, nullptr, nullptr, nullptr, nullptr);
}

// Round 10
// 81.106 us; speedup vs baseline: 5.2274x; 1.1358x over previous
//
#include <hip/hip_runtime.h>
#include <hip/hip_bf16.h>
#include <math.h>

// Problem constants
#define NTOK 2048
#define CDIM 1024
#define NHEAD 16
#define HDIM 64
// frame id = token >> 8 (8 frames of 256 tokens)

typedef __attribute__((ext_vector_type(8))) short bf16x8;
typedef __attribute__((ext_vector_type(4))) short bf16x4;
typedef __attribute__((ext_vector_type(4))) float f32x4;
typedef __attribute__((ext_vector_type(4))) unsigned int u32x4;

// ---------------------------------------------------------------------------
// helpers
// ---------------------------------------------------------------------------
__device__ inline unsigned short bf16_rn(float f) {
    unsigned int u = __float_as_uint(f);
    u += 0x7FFFu + ((u >> 16) & 1u);
    return (unsigned short)(u >> 16);
}

template <int N> __device__ inline void waitcnt_vm() {
    if constexpr (N == 0) asm volatile("s_waitcnt vmcnt(0)" ::: "memory");
    else if constexpr (N == 3) asm volatile("s_waitcnt vmcnt(3)" ::: "memory");
    else if constexpr (N == 4) asm volatile("s_waitcnt vmcnt(4)" ::: "memory");
}

__device__ inline void gload16(const void* g, void* l) {
    __builtin_amdgcn_global_load_lds((const __attribute__((address_space(1))) void*)g,
                                     (__attribute__((address_space(3))) void*)l,
                                     16, 0, 0);
}

// One dispatch: convert x, Wqkv, Wproj to plain bf16.
__global__ __launch_bounds__(256) void conv3(const float* __restrict__ s0, unsigned short* __restrict__ h0, int nb0,
                                             const float* __restrict__ s1, unsigned short* __restrict__ h1, int nb1,
                                             const float* __restrict__ s2, unsigned short* __restrict__ h2) {
    int b = blockIdx.x;
    const float* s;
    unsigned short* hh;
    if (b < nb0) { s = s0; hh = h0; }
    else if (b < nb0 + nb1) { s = s1; hh = h1; b -= nb0; }
    else { s = s2; hh = h2; b -= nb0 + nb1; }
    const int i = b * 256 + threadIdx.x;
    float4 v = ((const float4*)s)[i];
    ushort4 h;
    h.x = bf16_rn(v.x); h.y = bf16_rn(v.y); h.z = bf16_rn(v.z); h.w = bf16_rn(v.w);
    ((ushort4*)hh)[i] = h;
}

// ---------------------------------------------------------------------------
// MFMA GEMM, 1-term bf16, counted-vmcnt double buffer.
// BM=64, BN=128, 4 waves (32x64 each).
// MODE 1 (QKV): epilogue writes attention-ready bf16: q (scaled 0.125,
//   swizzled), K (swizzled), V^T (swizzled).
// MODE 2 (PROJ): f32 out + bias.
// ---------------------------------------------------------------------------
template <int BM, int BN, int M, int N, int K, int MODE>
__global__ __launch_bounds__(256) void gemm_mfma(const unsigned short* __restrict__ Ah,
                                                 const unsigned short* __restrict__ Bh,
                                                 const float* __restrict__ bias,
                                                 float* __restrict__ C,
                                                 unsigned short* __restrict__ qg,
                                                 unsigned short* __restrict__ kg,
                                                 unsigned short* __restrict__ vtg) {
    constexpr int FM = BM / 32;
    constexpr int FN = BN / 32;
    constexpr int ASZ = BM * 32;
    constexpr int BSZ = BN * 32;
    constexpr int BUF = ASZ + BSZ;
    __shared__ unsigned short lds[2 * BUF];

    const int tid = threadIdx.x;
    const int lane = tid & 63;
    const int w = tid >> 6;
    const int m0 = blockIdx.y * BM;
    const int n0 = blockIdx.x * BN;
    const int wave_m = (w >> 1) * (BM / 2);
    const int wave_n = (w & 1) * (BN / 2);
    const int lr = lane & 15;
    const int kg_ = lane >> 4;
    const int srow = tid >> 2;
    const int scol = (tid & 3) * 8;

    const size_t aRow = (size_t)(m0 + srow) * K + scol;
    const size_t bRow = (size_t)(n0 + srow) * K + scol;

    f32x4 acc[FM][FN];
#pragma unroll
    for (int i = 0; i < FM; ++i)
#pragma unroll
        for (int j = 0; j < FN; ++j) acc[i][j] = {0.f, 0.f, 0.f, 0.f};

    auto stage = [&](int buf, int k0) {
        unsigned short* bb = lds + buf * BUF;
#pragma unroll
        for (int j = 0; j < BM / 64; ++j) {
            const size_t ga = aRow + (size_t)j * 64 * K + k0;
            gload16(Ah + ga, bb + (srow + j * 64) * 32 + scol);
        }
#pragma unroll
        for (int j = 0; j < BN / 64; ++j) {
            const size_t gb = bRow + (size_t)j * 64 * K + k0;
            gload16(Bh + gb, bb + ASZ + (srow + j * 64) * 32 + scol);
        }
    };

    stage(0, 0);
    constexpr int NL = BM / 64 + BN / 64;
    constexpr int NT = K / 32;
    for (int t = 0; t < NT; ++t) {
        const int cur = t & 1;
        if (t + 1 < NT) {
            stage(cur ^ 1, (t + 1) * 32);
            waitcnt_vm<NL>();
        } else {
            waitcnt_vm<0>();
        }
        __builtin_amdgcn_s_barrier();

        const unsigned short* bb = lds + cur * BUF;
        bf16x8 ah[FM], bh[FN];
#pragma unroll
        for (int f = 0; f < FM; ++f)
            ah[f] = *(const bf16x8*)&bb[(wave_m + f * 16 + lr) * 32 + kg_ * 8];
#pragma unroll
        for (int f = 0; f < FN; ++f)
            bh[f] = *(const bf16x8*)&bb[ASZ + (wave_n + f * 16 + lr) * 32 + kg_ * 8];
        __builtin_amdgcn_s_setprio(1);
#pragma unroll
        for (int fm = 0; fm < FM; ++fm)
#pragma unroll
            for (int fn = 0; fn < FN; ++fn)
                acc[fm][fn] = __builtin_amdgcn_mfma_f32_16x16x32_bf16(ah[fm], bh[fn], acc[fm][fn], 0, 0, 0);
        __builtin_amdgcn_s_setprio(0);
        asm volatile("" ::: "memory");
        __builtin_amdgcn_s_barrier();
    }

    // epilogue: C/D layout col=lane&15, row=(lane>>4)*4+reg  [m89-verified]
    if constexpr (MODE == 2) {
        float bv[FN];
#pragma unroll
        for (int fn = 0; fn < FN; ++fn) bv[fn] = bias[n0 + wave_n + fn * 16 + lr];
#pragma unroll
        for (int fm = 0; fm < FM; ++fm) {
            const int row0 = m0 + wave_m + fm * 16 + kg_ * 4;
#pragma unroll
            for (int fn = 0; fn < FN; ++fn) {
                const int col = n0 + wave_n + fn * 16 + lr;
#pragma unroll
                for (int r = 0; r < 4; ++r)
                    C[(size_t)(row0 + r) * N + col] = acc[fm][fn][r] + bv[fn];
            }
        }
    } else {
        const int reg = n0 >> 10;  // 0=q, 1=k, 2=v (uniform per block)
#pragma unroll
        for (int fn = 0; fn < FN; ++fn) {
            const int col = n0 + wave_n + fn * 16 + lr;
            const int head = (col >> 6) & 15;
            const int d = col & 63;
            const float bv = bias[col];
#pragma unroll
            for (int fm = 0; fm < FM; ++fm) {
                const int row0 = m0 + wave_m + fm * 16 + kg_ * 4;
                if (reg == 2) {
                    // V^T [h][d][tok ^ ((d&7)<<3)]
                    ushort4 pk;
                    pk.x = bf16_rn(acc[fm][fn][0] + bv);
                    pk.y = bf16_rn(acc[fm][fn][1] + bv);
                    pk.z = bf16_rn(acc[fm][fn][2] + bv);
                    pk.w = bf16_rn(acc[fm][fn][3] + bv);
                    const size_t idx = (size_t)(head * 64 + d) * 2048 + (size_t)(row0 ^ ((d & 7) << 3));
                    *(ushort4*)&vtg[idx] = pk;
                } else {
                    // q (scaled 0.125) / K plain bf16 [h][tok][d ^ ((tok&7)<<3)]
                    const float sc = (reg == 0) ? 0.125f : 1.0f;
                    unsigned short* dp = (reg == 0) ? qg : kg;
#pragma unroll
                    for (int r = 0; r < 4; ++r) {
                        const int tok = row0 + r;
                        const size_t idx = ((size_t)head * 2048 + tok) * 64 + (d ^ ((tok & 7) << 3));
                        dp[idx] = bf16_rn((acc[fm][fn][r] + bv) * sc);
                    }
                }
            }
        }
    }
}

// ---------------------------------------------------------------------------
// MFMA sparse flash attention, KV wave-split (flash-decoding within block).
// 512 blocks x 512 threads: 8 waves; waves 0-3 (half 0) process even tiles,
// waves 4-7 (half 1) odd tiles, private (m,l,O); merged via LDS at the end.
// 2 blocks/CU -> 4 waves/SIMD. Q plain bf16 (1-term QK^T).
// ---------------------------------------------------------------------------
__global__ __launch_bounds__(512) void attn_mfma(const unsigned short* __restrict__ qg,
                                                 const unsigned short* __restrict__ kgb,
                                                 const unsigned short* __restrict__ vtg,
                                                 const float* __restrict__ frame_bias,
                                                 const int* __restrict__ adj,
                                                 const int* __restrict__ is_hub,
                                                 unsigned short* __restrict__ ath) {
    __shared__ unsigned short sBuf[2][2][2][64 * 64];  // [buf][half][{k,v}] = 64KB
    __shared__ int sList[34];
    __shared__ float sFB[8];
    __shared__ unsigned long long sHub[32];
    __shared__ int sNT;

    // XCD decode: bid&7 = XCD, each XCD owns heads {2r, 2r+1}
    const int bid = blockIdx.x;
    const int r8 = bid & 7, tt = bid >> 3;
    const int qb = tt & 31, hb = tt >> 5;
    const int h = r8 * 2 + hb;
    const int q0 = qb * 64;

    const int tid = threadIdx.x;
    const int lane = tid & 63;
    const int wq = tid >> 6;        // 0..7
    const int half = wq >> 2;       // 0 or 1
    const int lr = lane & 15;
    const int kg = lane >> 4;
    const int fi = q0 >> 8;

    // ---- Q fragments (plain bf16, pre-swizzled global layout) ----
    const int qrow = (wq & 3) * 16 + lr;    // block-local q row (0..63)
    const int qgl = q0 + qrow;              // global token
    const unsigned short* qb_ = qg + ((size_t)h * 2048 + qgl) * 64;
    const int Xq = (qgl & 7) << 3;
    bf16x8 qh[2];
#pragma unroll
    for (int dc = 0; dc < 2; ++dc)
        qh[dc] = *(const bf16x8*)&qb_[(dc * 32 + kg * 8) ^ Xq];
    const bool hq = is_hub[qgl] != 0;

    // ---- prologue tables (8 waves x 4 masks) ----
#pragma unroll
    for (int i = 0; i < 4; ++i) {
        const int t2 = wq * 4 + i;
        unsigned long long mb = __ballot(is_hub[t2 * 64 + lane] != 0);
        if (lane == 0) sHub[t2] = mb;
    }
    if (tid < 8) sFB[tid] = frame_bias[fi * 8 + tid];
    if (wq == 0) {
        const bool ok = (lane < 32) && (adj[fi * 8 + ((lane & 31) >> 2)] != 0);
        const unsigned long long am = __ballot(ok);
        if (lane == 0) {
            int c = 0;
#pragma unroll 1
            for (int t2 = 0; t2 < 32; ++t2)
                if ((am >> t2) & 1ull) sList[c++] = t2;
            sNT = c;
            sList[c] = sList[c - 1];  // pad (odd nt / prefetch overrun)
        }
    }
    __syncthreads();
    const int nt = sNT;
    const int npair = (nt + 1) >> 1;

    // staging: each half's 256 threads stage that half's own K/V tile
    const int t256 = tid & 255;
    const int crow = t256 >> 3;          // 0..31
    const int ccol = (t256 & 7) * 8;
    const unsigned short* kbase = kgb + (size_t)h * 2048 * 64;
    const unsigned short* vbase = vtg + (size_t)h * 64 * 2048;

    auto stageOwn = [&](int buf, int n0s) {
        unsigned short* bk = &sBuf[buf][half][0][0];
        unsigned short* bv = &sBuf[buf][half][1][0];
        const int dst = t256 * 8;
        gload16(kbase + (size_t)(n0s + crow) * 64 + ccol, bk + dst);
        gload16(kbase + (size_t)(n0s + crow + 32) * 64 + ccol, bk + dst + 2048);
        gload16(vbase + (size_t)crow * 2048 + n0s + ccol, bv + dst);
        gload16(vbase + (size_t)(crow + 32) * 2048 + n0s + ccol, bv + dst + 2048);
    };

    float m_i = -INFINITY, l_i = 0.f;
    f32x4 oacc[4];
#pragma unroll
    for (int fd = 0; fd < 4; ++fd) oacc[fd] = {0.f, 0.f, 0.f, 0.f};

    stageOwn(0, sList[half] * 64);
#pragma unroll 1
    for (int p = 0; p < npair; ++p) {
        const int cur = p & 1;
        const int idx = 2 * p + half;
        if (p + 1 < npair) {
            stageOwn(cur ^ 1, sList[idx + 2] * 64);
            waitcnt_vm<4>();
        } else {
            waitcnt_vm<0>();
        }
        __builtin_amdgcn_s_barrier();

        const int tile = sList[idx];            // padded -> always valid data
        const bool live = idx < nt;
        const int fj = tile >> 2;
        const bool same = (fj == fi);
        const float biasv = sFB[fj];
        const unsigned long long hubmask = sHub[tile];
        const unsigned short* sKh = &sBuf[cur][half][0][0];
        const unsigned short* sVt = &sBuf[cur][half][1][0];

        // ---- S^T = K . Q^T (1 term) ----
        f32x4 sacc[4];
#pragma unroll
        for (int fk = 0; fk < 4; ++fk) sacc[fk] = {0.f, 0.f, 0.f, 0.f};
        __builtin_amdgcn_s_setprio(1);
#pragma unroll
        for (int fk = 0; fk < 4; ++fk) {
            const int r = fk * 16 + lr;
            const int Xk = (r & 7) << 3;
            const int rb = r * 64;
#pragma unroll
            for (int dc = 0; dc < 2; ++dc) {
                bf16x8 khf = *(const bf16x8*)&sKh[rb + ((dc * 32 + kg * 8) ^ Xk)];
                sacc[fk] = __builtin_amdgcn_mfma_f32_16x16x32_bf16(khf, qh[dc], sacc[fk], 0, 0, 0);
            }
        }
        __builtin_amdgcn_s_setprio(0);

        // ---- mask + bias + online softmax (lane owns 16 scores of its q) ----
        float sv[4][4];
        float rmax = -INFINITY;
#pragma unroll
        for (int fk = 0; fk < 4; ++fk)
#pragma unroll
            for (int r = 0; r < 4; ++r) {
                float val = sacc[fk][r] + biasv;
                if (!same) {
                    const int k = fk * 16 + kg * 4 + r;
                    if (hq || ((hubmask >> k) & 1ull)) val = -INFINITY;
                }
                if (!live) val = -INFINITY;
                sv[fk][r] = val;
                rmax = fmaxf(rmax, val);
            }
        rmax = fmaxf(rmax, __shfl_xor(rmax, 16));
        rmax = fmaxf(rmax, __shfl_xor(rmax, 32));

        const float mn = fmaxf(m_i, rmax);
        const float alpha = (mn == -INFINITY) ? 1.f : __expf(m_i - mn);
        m_i = mn;

        float p4[4][4];
        float psum = 0.f;
#pragma unroll
        for (int fk = 0; fk < 4; ++fk)
#pragma unroll
            for (int r = 0; r < 4; ++r) {
                const float pv = (sv[fk][r] == -INFINITY) ? 0.f : __expf(sv[fk][r] - mn);
                p4[fk][r] = pv;
                psum += pv;
            }
        psum += __shfl_xor(psum, 16);
        psum += __shfl_xor(psum, 32);
        l_i = l_i * alpha + psum;
#pragma unroll
        for (int fd = 0; fd < 4; ++fd) {
            oacc[fd][0] *= alpha; oacc[fd][1] *= alpha;
            oacc[fd][2] *= alpha; oacc[fd][3] *= alpha;
        }

        // ---- pack P, O^T += V^T . P^T (k-slot permuted) ----
        unsigned int pc[4][2];
#pragma unroll
        for (int fk = 0; fk < 4; ++fk)
#pragma unroll
            for (int rp = 0; rp < 2; ++rp)
                pc[fk][rp] = (unsigned int)bf16_rn(p4[fk][2 * rp]) |
                             ((unsigned int)bf16_rn(p4[fk][2 * rp + 1]) << 16);
        __builtin_amdgcn_s_setprio(1);
#pragma unroll
        for (int c = 0; c < 2; ++c) {
            u32x4 pw = {pc[2 * c][0], pc[2 * c][1], pc[2 * c + 1][0], pc[2 * c + 1][1]};
            bf16x8 pbv = __builtin_bit_cast(bf16x8, pw);
#pragma unroll
            for (int fd = 0; fd < 4; ++fd) {
                const int vrow = fd * 16 + lr;
                const int Xv = (vrow & 7) << 3;
                const int vb = vrow * 64;
                bf16x4 v0 = *(const bf16x4*)&sVt[vb + ((c * 32 + kg * 4) ^ Xv)];
                bf16x4 v1 = *(const bf16x4*)&sVt[vb + ((c * 32 + 16 + kg * 4) ^ Xv)];
                bf16x8 va = __builtin_shufflevector(v0, v1, 0, 1, 2, 3, 4, 5, 6, 7);
                oacc[fd] = __builtin_amdgcn_mfma_f32_16x16x32_bf16(va, pbv, oacc[fd], 0, 0, 0);
            }
        }
        __builtin_amdgcn_s_setprio(0);
        asm volatile("" ::: "memory");
        __builtin_amdgcn_s_barrier();
    }

    // ---- merge halves via LDS (sBuf reuse is safe: all reads barriered) ----
    float* mrg = (float*)&sBuf[0][0][0][0];
    const int mbase = ((wq & 3) * 64 + lane) * 18;
    if (half == 1) {
        mrg[mbase] = m_i;
        mrg[mbase + 1] = l_i;
#pragma unroll
        for (int fd = 0; fd < 4; ++fd)
#pragma unroll
            for (int r = 0; r < 4; ++r) mrg[mbase + 2 + fd * 4 + r] = oacc[fd][r];
    }
    __syncthreads();
    if (half == 0) {
        const float mb = mrg[mbase];
        const float lb = mrg[mbase + 1];
        const float m = fmaxf(m_i, mb);
        const float aa = (m_i == -INFINITY) ? 0.f : __expf(m_i - m);
        const float ab = (mb == -INFINITY) ? 0.f : __expf(mb - m);
        const float inv = 1.f / (l_i * aa + lb * ab);
#pragma unroll
        for (int fd = 0; fd < 4; ++fd) {
            ushort4 h4;
            unsigned short hs[4];
#pragma unroll
            for (int r = 0; r < 4; ++r) {
                const float o = (oacc[fd][r] * aa + mrg[mbase + 2 + fd * 4 + r] * ab) * inv;
                hs[r] = bf16_rn(o);
            }
            h4.x = hs[0]; h4.y = hs[1]; h4.z = hs[2]; h4.w = hs[3];
            const size_t idx = (size_t)qgl * CDIM + h * 64 + fd * 16 + kg * 4;
            *(ushort4*)&ath[idx] = h4;
        }
    }
}

// ---------------------------------------------------------------------------
extern "C" void kernel_launch(void* const* d_in, const int* in_sizes, int n_in,
                              void* d_out, int out_size, void* d_ws, size_t ws_size,
                              hipStream_t stream) {
    const float* x          = (const float*)d_in[0];
    const float* Wqkv       = (const float*)d_in[1];
    const float* bqkv       = (const float*)d_in[2];
    const float* Wproj      = (const float*)d_in[3];
    const float* bproj      = (const float*)d_in[4];
    const float* frame_bias = (const float*)d_in[5];
    const int*   adj        = (const int*)d_in[6];
    const int*   is_hub     = (const int*)d_in[8];
    float* out = (float*)d_out;

    char* ws = (char*)d_ws;
    size_t off = 0;
    auto alloc_us = [&](size_t n) { unsigned short* p = (unsigned short*)(ws + off); off += n * 2; return p; };
    unsigned short* qg  = alloc_us((size_t)NHEAD * NTOK * HDIM);
    unsigned short* kg  = alloc_us((size_t)NHEAD * NTOK * HDIM);
    unsigned short* vtg = alloc_us((size_t)NHEAD * HDIM * NTOK);
    unsigned short* xh  = alloc_us((size_t)NTOK * CDIM);
    unsigned short* wqh = alloc_us((size_t)3 * CDIM * CDIM);
    unsigned short* wph = alloc_us((size_t)CDIM * CDIM);
    unsigned short* ath = alloc_us((size_t)NTOK * CDIM);

    const int nb_x = (NTOK * CDIM / 4) / 256;
    const int nb_wq = (3 * CDIM * CDIM / 4) / 256;
    const int nb_wp = (CDIM * CDIM / 4) / 256;
    conv3<<<nb_x + nb_wq + nb_wp, 256, 0, stream>>>(x, xh, nb_x,
                                                    Wqkv, wqh, nb_wq,
                                                    Wproj, wph);

    // 1) QKV projection (1-term); epilogue emits attention-ready bf16 buffers
    gemm_mfma<64, 128, NTOK, 3 * CDIM, CDIM, 1>
        <<<dim3((3 * CDIM) / 128, NTOK / 64), 256, 0, stream>>>(
            xh, wqh, bqkv, nullptr, qg, kg, vtg);
    // 2) sparse attention (KV wave-split, 4 waves/SIMD), writes bf16 att
    attn_mfma<<<512, 512, 0, stream>>>(qg, kg, vtg,
                                       frame_bias, adj, is_hub, ath);
    // 3) output projection (1-term)
    gemm_mfma<64, 128, NTOK, CDIM, CDIM, 2>
        <<<dim3(CDIM / 128, NTOK / 64), 256, 0, stream>>>(
            ath, wph, bproj, out, nullptr, nullptr, nullptr);
}